// Round 5
// baseline (531.886 us; speedup 1.0000x reference)
//
#include <hip/hip_runtime.h>
#include <cmath>

#define BB 8
#define NN 4096
#define DD 64
#define KK 8
#define NCLS 2

constexpr float LNEPS = 1e-5f;
constexpr float BNRS = 0.9999950000374994f;      // 1/sqrt(1+1e-5)
constexpr float INVSQRT2 = 0.70710678118654752440f;

constexpr int QKV_GRID = 512;
constexpr int ATTN_GRID = 1024;
constexpr int FFN_GRID = 512;

// knn decomposition: 64 queries/block x 8 candidate-splits (one per wave)
#define QPB 64
#define SPLITS 8

__device__ __forceinline__ float wave_sum(float v) {
#pragma unroll
  for (int m = 32; m > 0; m >>= 1) v += __shfl_xor(v, m, 64);
  return v;
}

__device__ __forceinline__ float gelu_exact(float x) {
  return 0.5f * x * (1.0f + erff(x * INVSQRT2));
}

// identical in both knn passes -> bit-identical distances
__device__ __forceinline__ float dist2(float4 q, float4 p) {
  float dot = fmaf(q.x, p.x, fmaf(q.y, p.y, q.z * p.z));
  return fmaf(-2.0f, dot, q.w + p.w);
}

// ---------------------------------------------------------------- zero g
__global__ void zero_kernel(float* g) { g[threadIdx.x] = 0.0f; }

// ---------------------------------------------------------------- embed: h = relu(x@ew1+eb1)@ew2+eb2
__global__ __launch_bounds__(256) void embed_kernel(
    const float* __restrict__ x, const float* __restrict__ ew1, const float* __restrict__ eb1,
    const float* __restrict__ ew2, const float* __restrict__ eb2, float* __restrict__ h) {
  __shared__ float h1[4][DD];
  int w = threadIdx.x >> 6, c = threadIdx.x & 63;
  int pt = blockIdx.x * 4 + w;
  const float* xp = x + (size_t)pt * 3;
  float x0 = xp[0], x1 = xp[1], x2 = xp[2];
  float a = fmaf(x0, ew1[c], fmaf(x1, ew1[64 + c], fmaf(x2, ew1[128 + c], eb1[c])));
  h1[w][c] = fmaxf(a, 0.0f);
  __syncthreads();
  float s = eb2[c];
#pragma unroll 8
  for (int d = 0; d < DD; d++) s = fmaf(h1[w][d], ew2[d * 64 + c], s);
  h[(size_t)pt * 64 + c] = s;
}

// ---------------------------------------------------------------- knn prep: ppg[b*N+j] = (x,y,z,|p|^2)
__global__ __launch_bounds__(256) void knn_prep_kernel(const float* __restrict__ x,
                                                       float4* __restrict__ ppg) {
  int i = blockIdx.x * 256 + threadIdx.x;
  float a0 = x[3 * i + 0], a1 = x[3 * i + 1], a2 = x[3 * i + 2];
  ppg[i] = make_float4(a0, a1, a2, a0 * a0 + a1 * a1 + a2 * a2);
}

// ---------------------------------------------------------------- knn: exact top-8 (stable ties), 2-pass
// Pass 1: branchless f32 top-8-distance network (no divergence, 20 VALU ops/step).
// Threshold = exact 8th-smallest distance (merged across 8 splits).
// Pass 2: collect packed (d2,idx) keys <= thr (exactly 8 hits/query); stable merge.
__global__ __launch_bounds__(512) void knn_kernel(const float4* __restrict__ ppg,
                                                  int* __restrict__ idx) {
  __shared__ union {
    float v[SPLITS * 8][QPB];       // pass-1 value exchange
    double k[SPLITS * 8][QPB];      // pass-2 key exchange (32 KB)
  } mb;
  __shared__ float thrq[QPB];
  int b = blockIdx.x >> 6;          // 64 blocks per batch
  int qbase = (blockIdx.x & 63) * QPB;
  const float4* pb = ppg + (size_t)b * NN;
  int ql = threadIdx.x & 63;
  int sp = threadIdx.x >> 6;        // split id == wave id (wave-uniform candidate loads)
  float4 qp = pb[qbase + ql];
  int j0 = sp * (NN / SPLITS);

  // ---- pass 1: branchless top-8 distances
  float bd[8];
#pragma unroll
  for (int u = 0; u < 8; u++) bd[u] = INFINITY;
#pragma unroll 4
  for (int jj = 0; jj < NN / SPLITS; ++jj) {
    float d2 = dist2(qp, pb[j0 + jj]);
#pragma unroll
    for (int u = 7; u > 0; --u) bd[u] = fminf(bd[u], fmaxf(bd[u - 1], d2));
    bd[0] = fminf(bd[0], d2);
  }
#pragma unroll
  for (int u = 0; u < 8; u++) mb.v[sp * 8 + u][ql] = bd[u];
  __syncthreads();

  // ---- exact 8th-smallest across the 64-entry union (wave 0, branchless)
  if (threadIdx.x < QPB) {
    float cd[8];
#pragma unroll
    for (int u = 0; u < 8; u++) cd[u] = INFINITY;
    for (int e = 0; e < SPLITS * 8; e++) {
      float vv = mb.v[e][threadIdx.x];
#pragma unroll
      for (int u = 7; u > 0; --u) cd[u] = fminf(cd[u], fmaxf(cd[u - 1], vv));
      cd[0] = fminf(cd[0], vv);
    }
    thrq[threadIdx.x] = cd[7];
  }
  __syncthreads();
  float thr = thrq[ql];

  // ---- init key slots (each thread owns its 8 slots; no cross-thread hazard)
#pragma unroll
  for (int u = 0; u < 8; u++) mb.k[sp * 8 + u][ql] = INFINITY;

  // ---- pass 2: collect keys <= thr (expected exactly 8 hits per query)
  int cnt = 0;
#pragma unroll 4
  for (int jj = 0; jj < NN / SPLITS; ++jj) {
    int j = j0 + jj;
    float d2 = dist2(qp, pb[j]);
    if (d2 <= thr && cnt < 8) {
      mb.k[sp * 8 + cnt][ql] = __hiloint2double(__float_as_int(d2), j);
      cnt++;
    }
  }
  __syncthreads();

  // ---- stable merge of collected keys (index tie-break in low bits)
  if (threadIdx.x < QPB) {
    int qq = threadIdx.x;
    double cd[8];
#pragma unroll
    for (int u = 0; u < 8; u++) cd[u] = INFINITY;
    for (int e = 0; e < SPLITS * 8; e++) {
      double key = mb.k[e][qq];
      if (key < cd[7]) {
#pragma unroll
        for (int u = 7; u > 0; --u) cd[u] = fmin(cd[u], fmax(cd[u - 1], key));
        cd[0] = fmin(cd[0], key);
      }
    }
    int* op = idx + ((size_t)b * NN + qbase + qq) * 8;
#pragma unroll
    for (int u = 0; u < 8; u++) op[u] = __double2loint(cd[u]);
  }
}

// ---------------------------------------------------------------- qkv projection (4 points per wave)
__global__ __launch_bounds__(256) void qkv_kernel(
    const float* __restrict__ h, const float* __restrict__ wq, const float* __restrict__ bq,
    const float* __restrict__ wk, const float* __restrict__ bk,
    const float* __restrict__ wv, const float* __restrict__ bv,
    float* __restrict__ q, float* __restrict__ k, float* __restrict__ v) {
  __shared__ float lwq[DD * DD], lwk[DD * DD], lwv[DD * DD];
  __shared__ float lbq[DD], lbk[DD], lbv[DD];
  __shared__ __attribute__((aligned(16))) float hb[4][DD][4];
  int tid = threadIdx.x;
  for (int i = tid; i < DD * DD; i += 256) { lwq[i] = wq[i]; lwk[i] = wk[i]; lwv[i] = wv[i]; }
  if (tid < DD) { lbq[tid] = bq[tid]; lbk[tid] = bk[tid]; lbv[tid] = bv[tid]; }
  __syncthreads();
  int w = tid >> 6, c = tid & 63;
  constexpr int ITERS = (BB * NN) / (QKV_GRID * 16);
  for (int it = 0; it < ITERS; ++it) {
    int wid = it * (QKV_GRID * 4) + blockIdx.x * 4 + w;
    int p0 = wid * 4;
    __syncthreads();
#pragma unroll
    for (int i = 0; i < 4; i++) hb[w][c][i] = h[(size_t)(p0 + i) * 64 + c];
    __syncthreads();
    float aq[4], ak[4], av[4];
#pragma unroll
    for (int i = 0; i < 4; i++) { aq[i] = lbq[c]; ak[i] = lbk[c]; av[i] = lbv[c]; }
#pragma unroll 4
    for (int d = 0; d < DD; d++) {
      float wq_ = lwq[d * 64 + c], wk_ = lwk[d * 64 + c], wv_ = lwv[d * 64 + c];
      float4 hh = *(const float4*)&hb[w][d][0];
      aq[0] = fmaf(hh.x, wq_, aq[0]); aq[1] = fmaf(hh.y, wq_, aq[1]);
      aq[2] = fmaf(hh.z, wq_, aq[2]); aq[3] = fmaf(hh.w, wq_, aq[3]);
      ak[0] = fmaf(hh.x, wk_, ak[0]); ak[1] = fmaf(hh.y, wk_, ak[1]);
      ak[2] = fmaf(hh.z, wk_, ak[2]); ak[3] = fmaf(hh.w, wk_, ak[3]);
      av[0] = fmaf(hh.x, wv_, av[0]); av[1] = fmaf(hh.y, wv_, av[1]);
      av[2] = fmaf(hh.z, wv_, av[2]); av[3] = fmaf(hh.w, wv_, av[3]);
    }
#pragma unroll
    for (int i = 0; i < 4; i++) {
      q[(size_t)(p0 + i) * 64 + c] = aq[i];
      k[(size_t)(p0 + i) * 64 + c] = ak[i];
      v[(size_t)(p0 + i) * 64 + c] = av[i];
    }
  }
}

// ---------------------------------------------------------------- attention (1 point per wave) -> t = ln1(attn+x)
// NOTE: t may alias q (same-point read-then-write only) -> no __restrict__ on q/t.
__global__ __launch_bounds__(256) void attn_kernel(
    const float* __restrict__ x, const float* __restrict__ h,
    const float* q, const float* __restrict__ kk, const float* __restrict__ vv,
    const int* __restrict__ idx,
    const float* __restrict__ pw1, const float* __restrict__ pb1,
    const float* __restrict__ pw2, const float* __restrict__ pb2,
    const float* __restrict__ aw, const float* __restrict__ ab,
    const float* __restrict__ ow, const float* __restrict__ ob,
    const float* __restrict__ l1g, const float* __restrict__ l1b,
    float* t) {
  __shared__ float lpw2[DD * DD], low[DD * DD];
  __shared__ float lpw1[3 * DD], lpb1[DD], lpb2[DD], law[DD], lob[DD], ll1g[DD], ll1b[DD];
  __shared__ __attribute__((aligned(16))) float h1lo[4][DD][4], h1hi[4][DD][4];
  __shared__ __attribute__((aligned(16))) float outb[4][DD];
  int tid = threadIdx.x;
  for (int i = tid; i < DD * DD; i += 256) { lpw2[i] = pw2[i]; low[i] = ow[i]; }
  if (tid < 3 * DD) lpw1[tid] = pw1[tid];
  if (tid < DD) {
    lpb1[tid] = pb1[tid]; lpb2[tid] = pb2[tid]; law[tid] = aw[tid];
    lob[tid] = ob[tid]; ll1g[tid] = l1g[tid]; ll1b[tid] = l1b[tid];
  }
  float lab = ab[0];
  __syncthreads();
  int w = tid >> 6, c = tid & 63;
  constexpr int ITERS = (BB * NN) / (ATTN_GRID * 4);
  for (int it = 0; it < ITERS; ++it) {
    int p = (it * ATTN_GRID + blockIdx.x) * 4 + w;
    int b = p >> 12;
    int n = p & (NN - 1);
    const float* xb = x + (size_t)b * NN * 3;
    float hs = h[(size_t)p * 64 + c];
    float qs = q[(size_t)p * 64 + c];
    float px0 = xb[n * 3 + 0], px1 = xb[n * 3 + 1], px2 = xb[n * 3 + 2];
    int nb[8];
#pragma unroll
    for (int u = 0; u < 8; u++) nb[u] = idx[(size_t)p * 8 + u];
    __syncthreads();
#pragma unroll
    for (int u = 0; u < 8; u++) {
      int m = nb[u];
      float d0 = px0 - xb[m * 3 + 0], d1 = px1 - xb[m * 3 + 1], d2 = px2 - xb[m * 3 + 2];
      float h1 = fmaf(d0, lpw1[c], fmaf(d1, lpw1[64 + c], fmaf(d2, lpw1[128 + c], lpb1[c])));
      h1 = fmaxf(h1, 0.0f);
      if (u < 4) h1lo[w][c][u] = h1; else h1hi[w][c][u - 4] = h1;
    }
    __syncthreads();
    float acc[8];
#pragma unroll
    for (int u = 0; u < 8; u++) acc[u] = lpb2[c];
#pragma unroll 4
    for (int d = 0; d < DD; d++) {
      float wv_ = lpw2[d * 64 + c];
      float4 lo = *(const float4*)&h1lo[w][d][0];
      float4 hi = *(const float4*)&h1hi[w][d][0];
      acc[0] = fmaf(lo.x, wv_, acc[0]); acc[1] = fmaf(lo.y, wv_, acc[1]);
      acc[2] = fmaf(lo.z, wv_, acc[2]); acc[3] = fmaf(lo.w, wv_, acc[3]);
      acc[4] = fmaf(hi.x, wv_, acc[4]); acc[5] = fmaf(hi.y, wv_, acc[5]);
      acc[6] = fmaf(hi.z, wv_, acc[6]); acc[7] = fmaf(hi.w, wv_, acc[7]);
    }
    float lg[8];
#pragma unroll
    for (int u = 0; u < 8; u++) {
      float kv = kk[((size_t)(b << 12) + nb[u]) * 64 + c];
      float ai = qs - kv + acc[u];
      lg[u] = wave_sum(ai * law[c]) + lab;
    }
    float mx = lg[0];
#pragma unroll
    for (int u = 1; u < 8; u++) mx = fmaxf(mx, lg[u]);
    float ssum = 0.0f;
#pragma unroll
    for (int u = 0; u < 8; u++) { lg[u] = expf(lg[u] - mx); ssum += lg[u]; }
    float inv = 1.0f / ssum;
    float out = 0.0f;
#pragma unroll
    for (int u = 0; u < 8; u++) {
      float vg = vv[((size_t)(b << 12) + nb[u]) * 64 + c];
      out = fmaf(lg[u] * inv, vg + acc[u], out);
    }
    outb[w][c] = out;
    __syncthreads();
    float at = lob[c];
#pragma unroll 4
    for (int d = 0; d < DD; d += 4) {
      float4 ov = *(const float4*)&outb[w][d];
      at = fmaf(ov.x, low[(d + 0) * 64 + c], at);
      at = fmaf(ov.y, low[(d + 1) * 64 + c], at);
      at = fmaf(ov.z, low[(d + 2) * 64 + c], at);
      at = fmaf(ov.w, low[(d + 3) * 64 + c], at);
    }
    float res = at + hs;
    float mean = wave_sum(res) * (1.0f / 64.0f);
    float dv = res - mean;
    float var = wave_sum(dv * dv) * (1.0f / 64.0f);
    float ivr = 1.0f / sqrtf(var + LNEPS);
    t[(size_t)p * 64 + c] = fmaf(ll1g[c], dv * ivr, ll1b[c]);
  }
}

// ---------------------------------------------------------------- ffn (4 points per wave) -> h = ln2(t + ffn(t))
__global__ __launch_bounds__(256) void ffn_kernel(
    const float* __restrict__ t, const float* __restrict__ fw1, const float* __restrict__ fb1,
    const float* __restrict__ fw2, const float* __restrict__ fb2,
    const float* __restrict__ l2g, const float* __restrict__ l2b, float* __restrict__ h) {
  __shared__ float lf1[DD * 128];
  __shared__ float lf2[128 * DD];
  __shared__ float lb1[128], lb2[DD], lg2[DD], lbt2[DD];
  __shared__ __attribute__((aligned(16))) float yb[4][DD][4];
  __shared__ __attribute__((aligned(16))) float hb[4][128][4];
  int tid = threadIdx.x;
  for (int i = tid; i < DD * 128; i += 256) { lf1[i] = fw1[i]; lf2[i] = fw2[i]; }
  if (tid < 128) lb1[tid] = fb1[tid];
  if (tid < DD) { lb2[tid] = fb2[tid]; lg2[tid] = l2g[tid]; lbt2[tid] = l2b[tid]; }
  __syncthreads();
  int w = tid >> 6, c = tid & 63;
  constexpr int ITERS = (BB * NN) / (FFN_GRID * 16);
  for (int it = 0; it < ITERS; ++it) {
    int wid = it * (FFN_GRID * 4) + blockIdx.x * 4 + w;
    int p0 = wid * 4;
    float y[4];
    __syncthreads();
#pragma unroll
    for (int i = 0; i < 4; i++) { y[i] = t[(size_t)(p0 + i) * 64 + c]; yb[w][c][i] = y[i]; }
    __syncthreads();
    float hA[4], hB[4];
#pragma unroll
    for (int i = 0; i < 4; i++) { hA[i] = lb1[c]; hB[i] = lb1[64 + c]; }
#pragma unroll 4
    for (int d = 0; d < DD; d++) {
      float w0 = lf1[d * 128 + c], w1 = lf1[d * 128 + 64 + c];
      float4 yv = *(const float4*)&yb[w][d][0];
      hA[0] = fmaf(yv.x, w0, hA[0]); hA[1] = fmaf(yv.y, w0, hA[1]);
      hA[2] = fmaf(yv.z, w0, hA[2]); hA[3] = fmaf(yv.w, w0, hA[3]);
      hB[0] = fmaf(yv.x, w1, hB[0]); hB[1] = fmaf(yv.y, w1, hB[1]);
      hB[2] = fmaf(yv.z, w1, hB[2]); hB[3] = fmaf(yv.w, w1, hB[3]);
    }
#pragma unroll
    for (int i = 0; i < 4; i++) {
      hA[i] = gelu_exact(hA[i]); hB[i] = gelu_exact(hB[i]);
      hb[w][c][i] = hA[i]; hb[w][64 + c][i] = hB[i];
    }
    __syncthreads();
    float o[4];
#pragma unroll
    for (int i = 0; i < 4; i++) o[i] = lb2[c];
#pragma unroll 4
    for (int j = 0; j < 128; j++) {
      float wv_ = lf2[j * 64 + c];
      float4 hv = *(const float4*)&hb[w][j][0];
      o[0] = fmaf(hv.x, wv_, o[0]); o[1] = fmaf(hv.y, wv_, o[1]);
      o[2] = fmaf(hv.z, wv_, o[2]); o[3] = fmaf(hv.w, wv_, o[3]);
    }
#pragma unroll
    for (int i = 0; i < 4; i++) {
      float r = y[i] + o[i];
      float mean = wave_sum(r) * (1.0f / 64.0f);
      float dv = r - mean;
      float var = wave_sum(dv * dv) * (1.0f / 64.0f);
      float ivr = 1.0f / sqrtf(var + LNEPS);
      h[(size_t)(p0 + i) * 64 + c] = fmaf(lg2[c], dv * ivr, lbt2[c]);
    }
  }
}

// ---------------------------------------------------------------- classifier proj + blockwise max-pool
__global__ __launch_bounds__(256) void cls_kernel(
    const float* __restrict__ h, const float* __restrict__ cw, const float* __restrict__ cb,
    const float* __restrict__ cg, const float* __restrict__ cbeta, float* __restrict__ g) {
  __shared__ float lcw[DD * 128];
  __shared__ float lcb[128], lcg[128], lcbt[128];
  __shared__ __attribute__((aligned(16))) float hb[4][DD][4];
  __shared__ float wmax[4][128];
  int tid = threadIdx.x;
  for (int i = tid; i < DD * 128; i += 256) lcw[i] = cw[i];
  if (tid < 128) { lcb[tid] = cb[tid]; lcg[tid] = cg[tid]; lcbt[tid] = cbeta[tid]; }
  __syncthreads();
  int w = tid >> 6, c = tid & 63;
  int b = blockIdx.x >> 7;            // 128 blocks per batch
  int blk = blockIdx.x & 127;
  int base = b * NN + blk * 32;
  float m0 = 0.0f, m1 = 0.0f;
  for (int it = 0; it < 2; ++it) {
    int p0 = base + (w * 2 + it) * 4;
    __syncthreads();
#pragma unroll
    for (int i = 0; i < 4; i++) hb[w][c][i] = h[(size_t)(p0 + i) * 64 + c];
    __syncthreads();
    float a0[4], a1[4];
#pragma unroll
    for (int i = 0; i < 4; i++) { a0[i] = lcb[c]; a1[i] = lcb[64 + c]; }
#pragma unroll 4
    for (int d = 0; d < DD; d++) {
      float w0 = lcw[d * 128 + c], w1 = lcw[d * 128 + 64 + c];
      float4 hv = *(const float4*)&hb[w][d][0];
      a0[0] = fmaf(hv.x, w0, a0[0]); a0[1] = fmaf(hv.y, w0, a0[1]);
      a0[2] = fmaf(hv.z, w0, a0[2]); a0[3] = fmaf(hv.w, w0, a0[3]);
      a1[0] = fmaf(hv.x, w1, a1[0]); a1[1] = fmaf(hv.y, w1, a1[1]);
      a1[2] = fmaf(hv.z, w1, a1[2]); a1[3] = fmaf(hv.w, w1, a1[3]);
    }
#pragma unroll
    for (int i = 0; i < 4; i++) {
      m0 = fmaxf(m0, fmaxf(0.0f, fmaf(lcg[c] * a0[i], BNRS, lcbt[c])));
      m1 = fmaxf(m1, fmaxf(0.0f, fmaf(lcg[64 + c] * a1[i], BNRS, lcbt[64 + c])));
    }
  }
  wmax[w][c] = m0; wmax[w][64 + c] = m1;
  __syncthreads();
  if (tid < 128) {
    float mm = fmaxf(fmaxf(wmax[0][tid], wmax[1][tid]), fmaxf(wmax[2][tid], wmax[3][tid]));
    atomicMax((int*)&g[b * 128 + tid], __float_as_int(mm));  // values >= 0
  }
}

// ---------------------------------------------------------------- final head (per batch)
__global__ __launch_bounds__(128) void head_kernel(
    const float* __restrict__ g,
    const float* __restrict__ f1w, const float* __restrict__ f1b,
    const float* __restrict__ b1g, const float* __restrict__ b1b,
    const float* __restrict__ f2w, const float* __restrict__ f2b,
    const float* __restrict__ b2g, const float* __restrict__ b2b,
    const float* __restrict__ f3w, const float* __restrict__ f3b,
    float* __restrict__ out) {
  __shared__ float gb[128], g1[128], g2[64];
  int b = blockIdx.x, t = threadIdx.x;
  gb[t] = g[b * 128 + t];
  __syncthreads();
  float a = f1b[t];
#pragma unroll 4
  for (int d = 0; d < 128; d++) a = fmaf(gb[d], f1w[d * 128 + t], a);
  g1[t] = fmaxf(0.0f, fmaf(b1g[t] * a, BNRS, b1b[t]));
  __syncthreads();
  if (t < 64) {
    float a2 = f2b[t];
#pragma unroll 4
    for (int j = 0; j < 128; j++) a2 = fmaf(g1[j], f2w[j * 64 + t], a2);
    g2[t] = fmaxf(0.0f, fmaf(b2g[t] * a2, BNRS, b2b[t]));
  }
  __syncthreads();
  if (t < NCLS) {
    float a3 = f3b[t];
#pragma unroll
    for (int d = 0; d < 64; d++) a3 = fmaf(g2[d], f3w[d * NCLS + t], a3);
    out[b * NCLS + t] = a3;
  }
}

extern "C" void kernel_launch(void* const* d_in, const int* in_sizes, int n_in,
                              void* d_out, int out_size, void* d_ws, size_t ws_size,
                              hipStream_t stream) {
  const float* x    = (const float*)d_in[0];
  const float* ew1  = (const float*)d_in[1];
  const float* eb1  = (const float*)d_in[2];
  const float* ew2  = (const float*)d_in[3];
  const float* eb2  = (const float*)d_in[4];
  const float* wq   = (const float*)d_in[5];
  const float* bq   = (const float*)d_in[6];
  const float* wk   = (const float*)d_in[7];
  const float* bk   = (const float*)d_in[8];
  const float* wv   = (const float*)d_in[9];
  const float* bv   = (const float*)d_in[10];
  const float* pw1  = (const float*)d_in[11];
  const float* pb1  = (const float*)d_in[12];
  const float* pw2  = (const float*)d_in[13];
  const float* pb2  = (const float*)d_in[14];
  const float* aw   = (const float*)d_in[15];
  const float* ab   = (const float*)d_in[16];
  const float* ow   = (const float*)d_in[17];
  const float* ob   = (const float*)d_in[18];
  const float* l1g  = (const float*)d_in[19];
  const float* l1b  = (const float*)d_in[20];
  const float* l2g  = (const float*)d_in[21];
  const float* l2b  = (const float*)d_in[22];
  const float* fw1  = (const float*)d_in[23];
  const float* fb1  = (const float*)d_in[24];
  const float* fw2  = (const float*)d_in[25];
  const float* fb2  = (const float*)d_in[26];
  const float* cw   = (const float*)d_in[27];
  const float* cb   = (const float*)d_in[28];
  const float* cg   = (const float*)d_in[29];
  const float* cbeta= (const float*)d_in[30];
  const float* f1w  = (const float*)d_in[31];
  const float* f1b  = (const float*)d_in[32];
  const float* b1g  = (const float*)d_in[33];
  const float* b1b  = (const float*)d_in[34];
  const float* f2w  = (const float*)d_in[35];
  const float* f2b  = (const float*)d_in[36];
  const float* b2g  = (const float*)d_in[37];
  const float* b2b  = (const float*)d_in[38];
  const float* f3w  = (const float*)d_in[39];
  const float* f3b  = (const float*)d_in[40];

  const size_t P = (size_t)BB * NN;       // 32768 points
  float* ws = (float*)d_ws;
  float* h = ws;                          // P*64
  float* q = h + P * 64;
  float* k = q + P * 64;
  float* v = k + P * 64;
  int* idx = (int*)(v + P * 64);          // P*8 ints
  float* g = (float*)(idx + P * 8);       // B*128
  float4* ppg = (float4*)(g + BB * 128);  // P float4 (aligned: offset is 16B-multiple)
  float* t = q;                           // alias: safe (same-point read-then-write)

  zero_kernel<<<1, BB * 128, 0, stream>>>(g);
  embed_kernel<<<(int)(P / 4), 256, 0, stream>>>(x, ew1, eb1, ew2, eb2, h);
  knn_prep_kernel<<<(int)(P / 256), 256, 0, stream>>>(x, ppg);
  knn_kernel<<<BB * (NN / QPB), 512, 0, stream>>>(ppg, idx);
  for (int l = 0; l < 2; l++) {
    qkv_kernel<<<QKV_GRID, 256, 0, stream>>>(h, wq + l * DD * DD, bq + l * DD,
                                             wk + l * DD * DD, bk + l * DD,
                                             wv + l * DD * DD, bv + l * DD, q, k, v);
    attn_kernel<<<ATTN_GRID, 256, 0, stream>>>(x, h, q, k, v, idx,
                                               pw1 + l * 3 * DD, pb1 + l * DD,
                                               pw2 + l * DD * DD, pb2 + l * DD,
                                               aw + l * DD, ab + l,
                                               ow + l * DD * DD, ob + l * DD,
                                               l1g + l * DD, l1b + l * DD, t);
    ffn_kernel<<<FFN_GRID, 256, 0, stream>>>(t, fw1 + l * DD * 2 * DD, fb1 + l * 2 * DD,
                                             fw2 + l * 2 * DD * DD, fb2 + l * DD,
                                             l2g + l * DD, l2b + l * DD, h);
  }
  cls_kernel<<<BB * 128, 256, 0, stream>>>(h, cw, cb, cg, cbeta, g);
  head_kernel<<<BB, 128, 0, stream>>>(g, f1w, f1b, b1g, b1b, f2w, f2b, b2g, b2b, f3w, f3b,
                                      (float*)d_out);
}

// Round 6
// 490.918 us; speedup vs baseline: 1.0835x; 1.0835x over previous
//
#include <hip/hip_runtime.h>
#include <cmath>

#define BB 8
#define NN 4096
#define DD 64
#define KK 8
#define NCLS 2

constexpr float LNEPS = 1e-5f;
constexpr float BNRS = 0.9999950000374994f;      // 1/sqrt(1+1e-5)
constexpr float INVSQRT2 = 0.70710678118654752440f;

constexpr int QKV_GRID = 512;
constexpr int ATTN_GRID = 1024;
constexpr int FFN_GRID = 512;

// knn decomposition: 64 queries/block x 16 candidate-splits (one per wave)
#define QPB 64
#define SPLITS 16

__device__ __forceinline__ float wave_sum(float v) {
#pragma unroll
  for (int m = 32; m > 0; m >>= 1) v += __shfl_xor(v, m, 64);
  return v;
}

__device__ __forceinline__ float gelu_exact(float x) {
  return 0.5f * x * (1.0f + erff(x * INVSQRT2));
}

// identical in both knn passes -> bit-identical distances
__device__ __forceinline__ float dist2(float4 q, float4 p) {
  float dot = fmaf(q.x, p.x, fmaf(q.y, p.y, q.z * p.z));
  return fmaf(-2.0f, dot, q.w + p.w);
}

// ---------------------------------------------------------------- zero g
__global__ void zero_kernel(float* g) { g[threadIdx.x] = 0.0f; }

// ---------------------------------------------------------------- embed: h = relu(x@ew1+eb1)@ew2+eb2
__global__ __launch_bounds__(256) void embed_kernel(
    const float* __restrict__ x, const float* __restrict__ ew1, const float* __restrict__ eb1,
    const float* __restrict__ ew2, const float* __restrict__ eb2, float* __restrict__ h) {
  __shared__ float h1[4][DD];
  int w = threadIdx.x >> 6, c = threadIdx.x & 63;
  int pt = blockIdx.x * 4 + w;
  const float* xp = x + (size_t)pt * 3;
  float x0 = xp[0], x1 = xp[1], x2 = xp[2];
  float a = fmaf(x0, ew1[c], fmaf(x1, ew1[64 + c], fmaf(x2, ew1[128 + c], eb1[c])));
  h1[w][c] = fmaxf(a, 0.0f);
  __syncthreads();
  float s = eb2[c];
#pragma unroll 8
  for (int d = 0; d < DD; d++) s = fmaf(h1[w][d], ew2[d * 64 + c], s);
  h[(size_t)pt * 64 + c] = s;
}

// ---------------------------------------------------------------- knn prep: ppg[b*N+j] = (x,y,z,|p|^2)
__global__ __launch_bounds__(256) void knn_prep_kernel(const float* __restrict__ x,
                                                       float4* __restrict__ ppg) {
  int i = blockIdx.x * 256 + threadIdx.x;
  float a0 = x[3 * i + 0], a1 = x[3 * i + 1], a2 = x[3 * i + 2];
  ppg[i] = make_float4(a0, a1, a2, a0 * a0 + a1 * a1 + a2 * a2);
}

// ---------------------------------------------------------------- knn: exact top-8 (stable ties), 2-pass
// 512 blocks x 1024 thr (16 waves): lane=query (64/block), wave=candidate split.
// Pass 1: branchless f32 top-8-distance network; candidate loads are wave-uniform
//         (base via readfirstlane -> scalar loads on the scalar pipe).
// thr = exact 8th-smallest distance via 2-stage tree merge (8 waves || then wave 0).
// Pass 2: collect packed (d2,idx) f64 keys <= thr (cap 8/split is provably exact).
// Final: 2-stage tree merge of keys, index tie-break in low bits.
__global__ __launch_bounds__(1024) void knn_kernel(const float4* __restrict__ ppg,
                                                   int* __restrict__ idx) {
  __shared__ union {
    float v[SPLITS * 8][QPB];       // pass-1 value lists
    double k[SPLITS * 8][QPB];      // pass-2 key lists (64 KB)
  } mb;
  __shared__ float thrq[QPB];
  int b = blockIdx.x >> 6;          // 64 blocks per batch
  int qbase = (blockIdx.x & 63) * QPB;
  const float4* pb = ppg + (size_t)b * NN;
  int ql = threadIdx.x & 63;
  int sp = __builtin_amdgcn_readfirstlane(threadIdx.x >> 6);  // wave id = split id (SGPR)
  float4 qp = pb[qbase + ql];
  const float4* cp = pb + sp * (NN / SPLITS);                 // scalar base -> s_load

  // ---- pass 1: branchless top-8 distances (256 candidates per split)
  float bd[8];
#pragma unroll
  for (int u = 0; u < 8; u++) bd[u] = INFINITY;
#pragma unroll 4
  for (int jj = 0; jj < NN / SPLITS; ++jj) {
    float d2 = dist2(qp, cp[jj]);
#pragma unroll
    for (int u = 7; u > 0; --u) bd[u] = fminf(bd[u], fmaxf(bd[u - 1], d2));
    bd[0] = fminf(bd[0], d2);
  }
#pragma unroll
  for (int u = 0; u < 8; u++) mb.v[sp * 8 + u][ql] = bd[u];
  __syncthreads();

  // ---- thr merge stage 1: wave m (m<8) merges splits 2m,2m+1 -> rows 16m..16m+7
  if (sp < 8) {
    float cd[8];
#pragma unroll
    for (int u = 0; u < 8; u++) cd[u] = INFINITY;
    int base = sp * 16;
#pragma unroll
    for (int e = 0; e < 16; e++) {
      float vv = mb.v[base + e][ql];
#pragma unroll
      for (int u = 7; u > 0; --u) cd[u] = fminf(cd[u], fmaxf(cd[u - 1], vv));
      cd[0] = fminf(cd[0], vv);
    }
#pragma unroll
    for (int u = 0; u < 8; u++) mb.v[base + u][ql] = cd[u];
  }
  __syncthreads();

  // ---- thr merge stage 2: wave 0 merges 8 sorted lists with __all-break
  if (sp == 0) {
    float cd[8];
#pragma unroll
    for (int u = 0; u < 8; u++) cd[u] = INFINITY;
    for (int m = 0; m < 8; m++) {
      for (int e = 0; e < 8; e++) {
        float vv = mb.v[m * 16 + e][ql];
        if (__all(vv >= cd[7])) break;   // sorted list: rest can't contribute
        // network is idempotent for vv >= cd[7] -> no predication needed
#pragma unroll
        for (int u = 7; u > 0; --u) cd[u] = fminf(cd[u], fmaxf(cd[u - 1], vv));
        cd[0] = fminf(cd[0], vv);
      }
    }
    thrq[ql] = cd[7];
  }
  __syncthreads();
  float thr = thrq[ql];

  // ---- init key slots (each wave owns its 8 rows)
#pragma unroll
  for (int u = 0; u < 8; u++) mb.k[sp * 8 + u][ql] = INFINITY;

  // ---- pass 2: collect keys <= thr (global hit count is 8 + ties; cap is exact)
  int cnt = 0;
#pragma unroll 4
  for (int jj = 0; jj < NN / SPLITS; ++jj) {
    float d2 = dist2(qp, cp[jj]);
    if (d2 <= thr && cnt < 8) {
      mb.k[sp * 8 + cnt][ql] = __hiloint2double(__float_as_int(d2), sp * (NN / SPLITS) + jj);
      cnt++;
    }
  }
  __syncthreads();

  // ---- key merge stage 1: wave m (m<8) merges splits 2m,2m+1 (unsorted ok)
  if (sp < 8) {
    double cd[8];
#pragma unroll
    for (int u = 0; u < 8; u++) cd[u] = INFINITY;
    int base = sp * 16;
#pragma unroll
    for (int e = 0; e < 16; e++) {
      double key = mb.k[base + e][ql];
#pragma unroll
      for (int u = 7; u > 0; --u) cd[u] = fmin(cd[u], fmax(cd[u - 1], key));
      cd[0] = fmin(cd[0], key);
    }
#pragma unroll
    for (int u = 0; u < 8; u++) mb.k[base + u][ql] = cd[u];
  }
  __syncthreads();

  // ---- key merge stage 2: wave 0, sorted lists, __all-break; write indices
  if (sp == 0) {
    double cd[8];
#pragma unroll
    for (int u = 0; u < 8; u++) cd[u] = INFINITY;
    for (int m = 0; m < 8; m++) {
      for (int e = 0; e < 8; e++) {
        double key = mb.k[m * 16 + e][ql];
        if (__all(key >= cd[7])) break;
#pragma unroll
        for (int u = 7; u > 0; --u) cd[u] = fmin(cd[u], fmax(cd[u - 1], key));
        cd[0] = fmin(cd[0], key);
      }
    }
    int* op = idx + ((size_t)b * NN + qbase + ql) * 8;
#pragma unroll
    for (int u = 0; u < 8; u++) op[u] = __double2loint(cd[u]);
  }
}

// ---------------------------------------------------------------- qkv projection (4 points per wave)
__global__ __launch_bounds__(256) void qkv_kernel(
    const float* __restrict__ h, const float* __restrict__ wq, const float* __restrict__ bq,
    const float* __restrict__ wk, const float* __restrict__ bk,
    const float* __restrict__ wv, const float* __restrict__ bv,
    float* __restrict__ q, float* __restrict__ k, float* __restrict__ v) {
  __shared__ float lwq[DD * DD], lwk[DD * DD], lwv[DD * DD];
  __shared__ float lbq[DD], lbk[DD], lbv[DD];
  __shared__ __attribute__((aligned(16))) float hb[4][DD][4];
  int tid = threadIdx.x;
  for (int i = tid; i < DD * DD; i += 256) { lwq[i] = wq[i]; lwk[i] = wk[i]; lwv[i] = wv[i]; }
  if (tid < DD) { lbq[tid] = bq[tid]; lbk[tid] = bk[tid]; lbv[tid] = bv[tid]; }
  __syncthreads();
  int w = tid >> 6, c = tid & 63;
  constexpr int ITERS = (BB * NN) / (QKV_GRID * 16);
  for (int it = 0; it < ITERS; ++it) {
    int wid = it * (QKV_GRID * 4) + blockIdx.x * 4 + w;
    int p0 = wid * 4;
    __syncthreads();
#pragma unroll
    for (int i = 0; i < 4; i++) hb[w][c][i] = h[(size_t)(p0 + i) * 64 + c];
    __syncthreads();
    float aq[4], ak[4], av[4];
#pragma unroll
    for (int i = 0; i < 4; i++) { aq[i] = lbq[c]; ak[i] = lbk[c]; av[i] = lbv[c]; }
#pragma unroll 4
    for (int d = 0; d < DD; d++) {
      float wq_ = lwq[d * 64 + c], wk_ = lwk[d * 64 + c], wv_ = lwv[d * 64 + c];
      float4 hh = *(const float4*)&hb[w][d][0];
      aq[0] = fmaf(hh.x, wq_, aq[0]); aq[1] = fmaf(hh.y, wq_, aq[1]);
      aq[2] = fmaf(hh.z, wq_, aq[2]); aq[3] = fmaf(hh.w, wq_, aq[3]);
      ak[0] = fmaf(hh.x, wk_, ak[0]); ak[1] = fmaf(hh.y, wk_, ak[1]);
      ak[2] = fmaf(hh.z, wk_, ak[2]); ak[3] = fmaf(hh.w, wk_, ak[3]);
      av[0] = fmaf(hh.x, wv_, av[0]); av[1] = fmaf(hh.y, wv_, av[1]);
      av[2] = fmaf(hh.z, wv_, av[2]); av[3] = fmaf(hh.w, wv_, av[3]);
    }
#pragma unroll
    for (int i = 0; i < 4; i++) {
      q[(size_t)(p0 + i) * 64 + c] = aq[i];
      k[(size_t)(p0 + i) * 64 + c] = ak[i];
      v[(size_t)(p0 + i) * 64 + c] = av[i];
    }
  }
}

// ---------------------------------------------------------------- attention (1 point per wave) -> t = ln1(attn+x)
// NOTE: t may alias q (same-point read-then-write only) -> no __restrict__ on q/t.
__global__ __launch_bounds__(256) void attn_kernel(
    const float* __restrict__ x, const float* __restrict__ h,
    const float* q, const float* __restrict__ kk, const float* __restrict__ vv,
    const int* __restrict__ idx,
    const float* __restrict__ pw1, const float* __restrict__ pb1,
    const float* __restrict__ pw2, const float* __restrict__ pb2,
    const float* __restrict__ aw, const float* __restrict__ ab,
    const float* __restrict__ ow, const float* __restrict__ ob,
    const float* __restrict__ l1g, const float* __restrict__ l1b,
    float* t) {
  __shared__ float lpw2[DD * DD], low[DD * DD];
  __shared__ float lpw1[3 * DD], lpb1[DD], lpb2[DD], law[DD], lob[DD], ll1g[DD], ll1b[DD];
  __shared__ __attribute__((aligned(16))) float h1lo[4][DD][4], h1hi[4][DD][4];
  __shared__ __attribute__((aligned(16))) float outb[4][DD];
  int tid = threadIdx.x;
  for (int i = tid; i < DD * DD; i += 256) { lpw2[i] = pw2[i]; low[i] = ow[i]; }
  if (tid < 3 * DD) lpw1[tid] = pw1[tid];
  if (tid < DD) {
    lpb1[tid] = pb1[tid]; lpb2[tid] = pb2[tid]; law[tid] = aw[tid];
    lob[tid] = ob[tid]; ll1g[tid] = l1g[tid]; ll1b[tid] = l1b[tid];
  }
  float lab = ab[0];
  __syncthreads();
  int w = tid >> 6, c = tid & 63;
  constexpr int ITERS = (BB * NN) / (ATTN_GRID * 4);
  for (int it = 0; it < ITERS; ++it) {
    int p = (it * ATTN_GRID + blockIdx.x) * 4 + w;
    int b = p >> 12;
    int n = p & (NN - 1);
    const float* xb = x + (size_t)b * NN * 3;
    float hs = h[(size_t)p * 64 + c];
    float qs = q[(size_t)p * 64 + c];
    float px0 = xb[n * 3 + 0], px1 = xb[n * 3 + 1], px2 = xb[n * 3 + 2];
    int nb[8];
#pragma unroll
    for (int u = 0; u < 8; u++) nb[u] = idx[(size_t)p * 8 + u];
    __syncthreads();
#pragma unroll
    for (int u = 0; u < 8; u++) {
      int m = nb[u];
      float d0 = px0 - xb[m * 3 + 0], d1 = px1 - xb[m * 3 + 1], d2 = px2 - xb[m * 3 + 2];
      float h1 = fmaf(d0, lpw1[c], fmaf(d1, lpw1[64 + c], fmaf(d2, lpw1[128 + c], lpb1[c])));
      h1 = fmaxf(h1, 0.0f);
      if (u < 4) h1lo[w][c][u] = h1; else h1hi[w][c][u - 4] = h1;
    }
    __syncthreads();
    float acc[8];
#pragma unroll
    for (int u = 0; u < 8; u++) acc[u] = lpb2[c];
#pragma unroll 4
    for (int d = 0; d < DD; d++) {
      float wv_ = lpw2[d * 64 + c];
      float4 lo = *(const float4*)&h1lo[w][d][0];
      float4 hi = *(const float4*)&h1hi[w][d][0];
      acc[0] = fmaf(lo.x, wv_, acc[0]); acc[1] = fmaf(lo.y, wv_, acc[1]);
      acc[2] = fmaf(lo.z, wv_, acc[2]); acc[3] = fmaf(lo.w, wv_, acc[3]);
      acc[4] = fmaf(hi.x, wv_, acc[4]); acc[5] = fmaf(hi.y, wv_, acc[5]);
      acc[6] = fmaf(hi.z, wv_, acc[6]); acc[7] = fmaf(hi.w, wv_, acc[7]);
    }
    float lg[8];
#pragma unroll
    for (int u = 0; u < 8; u++) {
      float kv = kk[((size_t)(b << 12) + nb[u]) * 64 + c];
      float ai = qs - kv + acc[u];
      lg[u] = wave_sum(ai * law[c]) + lab;
    }
    float mx = lg[0];
#pragma unroll
    for (int u = 1; u < 8; u++) mx = fmaxf(mx, lg[u]);
    float ssum = 0.0f;
#pragma unroll
    for (int u = 0; u < 8; u++) { lg[u] = expf(lg[u] - mx); ssum += lg[u]; }
    float inv = 1.0f / ssum;
    float out = 0.0f;
#pragma unroll
    for (int u = 0; u < 8; u++) {
      float vg = vv[((size_t)(b << 12) + nb[u]) * 64 + c];
      out = fmaf(lg[u] * inv, vg + acc[u], out);
    }
    outb[w][c] = out;
    __syncthreads();
    float at = lob[c];
#pragma unroll 4
    for (int d = 0; d < DD; d += 4) {
      float4 ov = *(const float4*)&outb[w][d];
      at = fmaf(ov.x, low[(d + 0) * 64 + c], at);
      at = fmaf(ov.y, low[(d + 1) * 64 + c], at);
      at = fmaf(ov.z, low[(d + 2) * 64 + c], at);
      at = fmaf(ov.w, low[(d + 3) * 64 + c], at);
    }
    float res = at + hs;
    float mean = wave_sum(res) * (1.0f / 64.0f);
    float dv = res - mean;
    float var = wave_sum(dv * dv) * (1.0f / 64.0f);
    float ivr = 1.0f / sqrtf(var + LNEPS);
    t[(size_t)p * 64 + c] = fmaf(ll1g[c], dv * ivr, ll1b[c]);
  }
}

// ---------------------------------------------------------------- ffn (4 points per wave) -> h = ln2(t + ffn(t))
__global__ __launch_bounds__(256) void ffn_kernel(
    const float* __restrict__ t, const float* __restrict__ fw1, const float* __restrict__ fb1,
    const float* __restrict__ fw2, const float* __restrict__ fb2,
    const float* __restrict__ l2g, const float* __restrict__ l2b, float* __restrict__ h) {
  __shared__ float lf1[DD * 128];
  __shared__ float lf2[128 * DD];
  __shared__ float lb1[128], lb2[DD], lg2[DD], lbt2[DD];
  __shared__ __attribute__((aligned(16))) float yb[4][DD][4];
  __shared__ __attribute__((aligned(16))) float hb[4][128][4];
  int tid = threadIdx.x;
  for (int i = tid; i < DD * 128; i += 256) { lf1[i] = fw1[i]; lf2[i] = fw2[i]; }
  if (tid < 128) lb1[tid] = fb1[tid];
  if (tid < DD) { lb2[tid] = fb2[tid]; lg2[tid] = l2g[tid]; lbt2[tid] = l2b[tid]; }
  __syncthreads();
  int w = tid >> 6, c = tid & 63;
  constexpr int ITERS = (BB * NN) / (FFN_GRID * 16);
  for (int it = 0; it < ITERS; ++it) {
    int wid = it * (FFN_GRID * 4) + blockIdx.x * 4 + w;
    int p0 = wid * 4;
    float y[4];
    __syncthreads();
#pragma unroll
    for (int i = 0; i < 4; i++) { y[i] = t[(size_t)(p0 + i) * 64 + c]; yb[w][c][i] = y[i]; }
    __syncthreads();
    float hA[4], hB[4];
#pragma unroll
    for (int i = 0; i < 4; i++) { hA[i] = lb1[c]; hB[i] = lb1[64 + c]; }
#pragma unroll 4
    for (int d = 0; d < DD; d++) {
      float w0 = lf1[d * 128 + c], w1 = lf1[d * 128 + 64 + c];
      float4 yv = *(const float4*)&yb[w][d][0];
      hA[0] = fmaf(yv.x, w0, hA[0]); hA[1] = fmaf(yv.y, w0, hA[1]);
      hA[2] = fmaf(yv.z, w0, hA[2]); hA[3] = fmaf(yv.w, w0, hA[3]);
      hB[0] = fmaf(yv.x, w1, hB[0]); hB[1] = fmaf(yv.y, w1, hB[1]);
      hB[2] = fmaf(yv.z, w1, hB[2]); hB[3] = fmaf(yv.w, w1, hB[3]);
    }
#pragma unroll
    for (int i = 0; i < 4; i++) {
      hA[i] = gelu_exact(hA[i]); hB[i] = gelu_exact(hB[i]);
      hb[w][c][i] = hA[i]; hb[w][64 + c][i] = hB[i];
    }
    __syncthreads();
    float o[4];
#pragma unroll
    for (int i = 0; i < 4; i++) o[i] = lb2[c];
#pragma unroll 4
    for (int j = 0; j < 128; j++) {
      float wv_ = lf2[j * 64 + c];
      float4 hv = *(const float4*)&hb[w][j][0];
      o[0] = fmaf(hv.x, wv_, o[0]); o[1] = fmaf(hv.y, wv_, o[1]);
      o[2] = fmaf(hv.z, wv_, o[2]); o[3] = fmaf(hv.w, wv_, o[3]);
    }
#pragma unroll
    for (int i = 0; i < 4; i++) {
      float r = y[i] + o[i];
      float mean = wave_sum(r) * (1.0f / 64.0f);
      float dv = r - mean;
      float var = wave_sum(dv * dv) * (1.0f / 64.0f);
      float ivr = 1.0f / sqrtf(var + LNEPS);
      h[(size_t)(p0 + i) * 64 + c] = fmaf(lg2[c], dv * ivr, lbt2[c]);
    }
  }
}

// ---------------------------------------------------------------- classifier proj + blockwise max-pool
__global__ __launch_bounds__(256) void cls_kernel(
    const float* __restrict__ h, const float* __restrict__ cw, const float* __restrict__ cb,
    const float* __restrict__ cg, const float* __restrict__ cbeta, float* __restrict__ g) {
  __shared__ float lcw[DD * 128];
  __shared__ float lcb[128], lcg[128], lcbt[128];
  __shared__ __attribute__((aligned(16))) float hb[4][DD][4];
  __shared__ float wmax[4][128];
  int tid = threadIdx.x;
  for (int i = tid; i < DD * 128; i += 256) lcw[i] = cw[i];
  if (tid < 128) { lcb[tid] = cb[tid]; lcg[tid] = cg[tid]; lcbt[tid] = cbeta[tid]; }
  __syncthreads();
  int w = tid >> 6, c = tid & 63;
  int b = blockIdx.x >> 7;            // 128 blocks per batch
  int blk = blockIdx.x & 127;
  int base = b * NN + blk * 32;
  float m0 = 0.0f, m1 = 0.0f;
  for (int it = 0; it < 2; ++it) {
    int p0 = base + (w * 2 + it) * 4;
    __syncthreads();
#pragma unroll
    for (int i = 0; i < 4; i++) hb[w][c][i] = h[(size_t)(p0 + i) * 64 + c];
    __syncthreads();
    float a0[4], a1[4];
#pragma unroll
    for (int i = 0; i < 4; i++) { a0[i] = lcb[c]; a1[i] = lcb[64 + c]; }
#pragma unroll 4
    for (int d = 0; d < DD; d++) {
      float w0 = lcw[d * 128 + c], w1 = lcw[d * 128 + 64 + c];
      float4 hv = *(const float4*)&hb[w][d][0];
      a0[0] = fmaf(hv.x, w0, a0[0]); a0[1] = fmaf(hv.y, w0, a0[1]);
      a0[2] = fmaf(hv.z, w0, a0[2]); a0[3] = fmaf(hv.w, w0, a0[3]);
      a1[0] = fmaf(hv.x, w1, a1[0]); a1[1] = fmaf(hv.y, w1, a1[1]);
      a1[2] = fmaf(hv.z, w1, a1[2]); a1[3] = fmaf(hv.w, w1, a1[3]);
    }
#pragma unroll
    for (int i = 0; i < 4; i++) {
      m0 = fmaxf(m0, fmaxf(0.0f, fmaf(lcg[c] * a0[i], BNRS, lcbt[c])));
      m1 = fmaxf(m1, fmaxf(0.0f, fmaf(lcg[64 + c] * a1[i], BNRS, lcbt[64 + c])));
    }
  }
  wmax[w][c] = m0; wmax[w][64 + c] = m1;
  __syncthreads();
  if (tid < 128) {
    float mm = fmaxf(fmaxf(wmax[0][tid], wmax[1][tid]), fmaxf(wmax[2][tid], wmax[3][tid]));
    atomicMax((int*)&g[b * 128 + tid], __float_as_int(mm));  // values >= 0
  }
}

// ---------------------------------------------------------------- final head (per batch)
__global__ __launch_bounds__(128) void head_kernel(
    const float* __restrict__ g,
    const float* __restrict__ f1w, const float* __restrict__ f1b,
    const float* __restrict__ b1g, const float* __restrict__ b1b,
    const float* __restrict__ f2w, const float* __restrict__ f2b,
    const float* __restrict__ b2g, const float* __restrict__ b2b,
    const float* __restrict__ f3w, const float* __restrict__ f3b,
    float* __restrict__ out) {
  __shared__ float gb[128], g1[128], g2[64];
  int b = blockIdx.x, t = threadIdx.x;
  gb[t] = g[b * 128 + t];
  __syncthreads();
  float a = f1b[t];
#pragma unroll 4
  for (int d = 0; d < 128; d++) a = fmaf(gb[d], f1w[d * 128 + t], a);
  g1[t] = fmaxf(0.0f, fmaf(b1g[t] * a, BNRS, b1b[t]));
  __syncthreads();
  if (t < 64) {
    float a2 = f2b[t];
#pragma unroll 4
    for (int j = 0; j < 128; j++) a2 = fmaf(g1[j], f2w[j * 64 + t], a2);
    g2[t] = fmaxf(0.0f, fmaf(b2g[t] * a2, BNRS, b2b[t]));
  }
  __syncthreads();
  if (t < NCLS) {
    float a3 = f3b[t];
#pragma unroll
    for (int d = 0; d < 64; d++) a3 = fmaf(g2[d], f3w[d * NCLS + t], a3);
    out[b * NCLS + t] = a3;
  }
}

extern "C" void kernel_launch(void* const* d_in, const int* in_sizes, int n_in,
                              void* d_out, int out_size, void* d_ws, size_t ws_size,
                              hipStream_t stream) {
  const float* x    = (const float*)d_in[0];
  const float* ew1  = (const float*)d_in[1];
  const float* eb1  = (const float*)d_in[2];
  const float* ew2  = (const float*)d_in[3];
  const float* eb2  = (const float*)d_in[4];
  const float* wq   = (const float*)d_in[5];
  const float* bq   = (const float*)d_in[6];
  const float* wk   = (const float*)d_in[7];
  const float* bk   = (const float*)d_in[8];
  const float* wv   = (const float*)d_in[9];
  const float* bv   = (const float*)d_in[10];
  const float* pw1  = (const float*)d_in[11];
  const float* pb1  = (const float*)d_in[12];
  const float* pw2  = (const float*)d_in[13];
  const float* pb2  = (const float*)d_in[14];
  const float* aw   = (const float*)d_in[15];
  const float* ab   = (const float*)d_in[16];
  const float* ow   = (const float*)d_in[17];
  const float* ob   = (const float*)d_in[18];
  const float* l1g  = (const float*)d_in[19];
  const float* l1b  = (const float*)d_in[20];
  const float* l2g  = (const float*)d_in[21];
  const float* l2b  = (const float*)d_in[22];
  const float* fw1  = (const float*)d_in[23];
  const float* fb1  = (const float*)d_in[24];
  const float* fw2  = (const float*)d_in[25];
  const float* fb2  = (const float*)d_in[26];
  const float* cw   = (const float*)d_in[27];
  const float* cb   = (const float*)d_in[28];
  const float* cg   = (const float*)d_in[29];
  const float* cbeta= (const float*)d_in[30];
  const float* f1w  = (const float*)d_in[31];
  const float* f1b  = (const float*)d_in[32];
  const float* b1g  = (const float*)d_in[33];
  const float* b1b  = (const float*)d_in[34];
  const float* f2w  = (const float*)d_in[35];
  const float* f2b  = (const float*)d_in[36];
  const float* b2g  = (const float*)d_in[37];
  const float* b2b  = (const float*)d_in[38];
  const float* f3w  = (const float*)d_in[39];
  const float* f3b  = (const float*)d_in[40];

  const size_t P = (size_t)BB * NN;       // 32768 points
  float* ws = (float*)d_ws;
  float* h = ws;                          // P*64
  float* q = h + P * 64;
  float* k = q + P * 64;
  float* v = k + P * 64;
  int* idx = (int*)(v + P * 64);          // P*8 ints
  float* g = (float*)(idx + P * 8);       // B*128
  float4* ppg = (float4*)(g + BB * 128);  // P float4 (aligned: offset is 16B-multiple)
  float* t = q;                           // alias: safe (same-point read-then-write)

  zero_kernel<<<1, BB * 128, 0, stream>>>(g);
  embed_kernel<<<(int)(P / 4), 256, 0, stream>>>(x, ew1, eb1, ew2, eb2, h);
  knn_prep_kernel<<<(int)(P / 256), 256, 0, stream>>>(x, ppg);
  knn_kernel<<<BB * (NN / QPB), 1024, 0, stream>>>(ppg, idx);
  for (int l = 0; l < 2; l++) {
    qkv_kernel<<<QKV_GRID, 256, 0, stream>>>(h, wq + l * DD * DD, bq + l * DD,
                                             wk + l * DD * DD, bk + l * DD,
                                             wv + l * DD * DD, bv + l * DD, q, k, v);
    attn_kernel<<<ATTN_GRID, 256, 0, stream>>>(x, h, q, k, v, idx,
                                               pw1 + l * 3 * DD, pb1 + l * DD,
                                               pw2 + l * DD * DD, pb2 + l * DD,
                                               aw + l * DD, ab + l,
                                               ow + l * DD * DD, ob + l * DD,
                                               l1g + l * DD, l1b + l * DD, t);
    ffn_kernel<<<FFN_GRID, 256, 0, stream>>>(t, fw1 + l * DD * 2 * DD, fb1 + l * 2 * DD,
                                             fw2 + l * 2 * DD * DD, fb2 + l * DD,
                                             l2g + l * DD, l2b + l * DD, h);
  }
  cls_kernel<<<BB * 128, 256, 0, stream>>>(h, cw, cb, cg, cbeta, g);
  head_kernel<<<BB, 128, 0, stream>>>(g, f1w, f1b, b1g, b1b, f2w, f2b, b2g, b2b, f3w, f3b,
                                      (float*)d_out);
}

// Round 7
// 472.042 us; speedup vs baseline: 1.1268x; 1.0400x over previous
//
#include <hip/hip_runtime.h>
#include <cmath>

#define BB 8
#define NN 4096
#define DD 64
#define KK 8
#define NCLS 2

constexpr float LNEPS = 1e-5f;
constexpr float BNRS = 0.9999950000374994f;      // 1/sqrt(1+1e-5)
constexpr float INVSQRT2 = 0.70710678118654752440f;

constexpr int QKV_GRID = 512;
constexpr int ATTN_GRID = 1024;
constexpr int FFN_GRID = 512;

// knn decomposition: 64 queries/block x 16 candidate-splits (one per wave)
#define QPB 64
#define SPLITS 16
#define SUBSET 64     // pass-1 subset per split (16*64 = 1024-point bound set)

__device__ __forceinline__ float wave_sum(float v) {
#pragma unroll
  for (int m = 32; m > 0; m >>= 1) v += __shfl_xor(v, m, 64);
  return v;
}

__device__ __forceinline__ float gelu_exact(float x) {
  return 0.5f * x * (1.0f + erff(x * INVSQRT2));
}

// identical in both knn passes -> bit-identical distances
__device__ __forceinline__ float dist2(float4 q, float4 p) {
  float dot = fmaf(q.x, p.x, fmaf(q.y, p.y, q.z * p.z));
  return fmaf(-2.0f, dot, q.w + p.w);
}

// ---------------------------------------------------------------- zero g
__global__ void zero_kernel(float* g) { g[threadIdx.x] = 0.0f; }

// ---------------------------------------------------------------- embed: h = relu(x@ew1+eb1)@ew2+eb2
__global__ __launch_bounds__(256) void embed_kernel(
    const float* __restrict__ x, const float* __restrict__ ew1, const float* __restrict__ eb1,
    const float* __restrict__ ew2, const float* __restrict__ eb2, float* __restrict__ h) {
  __shared__ float h1[4][DD];
  int w = threadIdx.x >> 6, c = threadIdx.x & 63;
  int pt = blockIdx.x * 4 + w;
  const float* xp = x + (size_t)pt * 3;
  float x0 = xp[0], x1 = xp[1], x2 = xp[2];
  float a = fmaf(x0, ew1[c], fmaf(x1, ew1[64 + c], fmaf(x2, ew1[128 + c], eb1[c])));
  h1[w][c] = fmaxf(a, 0.0f);
  __syncthreads();
  float s = eb2[c];
#pragma unroll 8
  for (int d = 0; d < DD; d++) s = fmaf(h1[w][d], ew2[d * 64 + c], s);
  h[(size_t)pt * 64 + c] = s;
}

// ---------------------------------------------------------------- knn prep: ppg[b*N+j] = (x,y,z,|p|^2)
__global__ __launch_bounds__(256) void knn_prep_kernel(const float* __restrict__ x,
                                                       float4* __restrict__ ppg) {
  int i = blockIdx.x * 256 + threadIdx.x;
  float a0 = x[3 * i + 0], a1 = x[3 * i + 1], a2 = x[3 * i + 2];
  ppg[i] = make_float4(a0, a1, a2, a0 * a0 + a1 * a1 + a2 * a2);
}

// ---------------------------------------------------------------- knn: exact top-8 (stable ties), 2-pass
// 512 blocks x 1024 thr (16 waves): lane=query (64/block), wave=candidate split.
// Pass 1 (cheap): top-8 distance network over only SUBSET candidates per split;
//   tree-merged 8th-smallest of the 1024-subset = U, a PROVABLE upper bound on
//   the true 8th-smallest (k-th smallest of a subset >= k-th of the full set).
// Pass 2: scan all candidates; hits (d2<=U, ~32/query) enter an exact per-split
//   top-8-of-hits via a guarded f64 (d2,idx)-key network in REGISTERS. Every true
//   top-8 member is a hit and is among its split's 8 smallest hits -> exact.
// Final: 2-stage tree merge of keys, index tie-break in low bits.
__global__ __launch_bounds__(1024) void knn_kernel(const float4* __restrict__ ppg,
                                                   int* __restrict__ idx) {
  __shared__ union {
    float v[SPLITS * 8][QPB];       // pass-1 value lists
    double k[SPLITS * 8][QPB];      // pass-2 key lists (64 KB)
  } mb;
  __shared__ float thrq[QPB];
  int b = blockIdx.x >> 6;          // 64 blocks per batch
  int qbase = (blockIdx.x & 63) * QPB;
  const float4* pb = ppg + (size_t)b * NN;
  int ql = threadIdx.x & 63;
  int sp = __builtin_amdgcn_readfirstlane(threadIdx.x >> 6);  // wave id = split id (SGPR)
  float4 qp = pb[qbase + ql];
  const float4* cp = pb + sp * (NN / SPLITS);                 // scalar base

  // ---- pass 1: branchless top-8 distances over SUBSET candidates
  float bd[8];
#pragma unroll
  for (int u = 0; u < 8; u++) bd[u] = INFINITY;
#pragma unroll 4
  for (int jj = 0; jj < SUBSET; ++jj) {
    float d2 = dist2(qp, cp[jj]);
#pragma unroll
    for (int u = 7; u > 0; --u) bd[u] = fminf(bd[u], fmaxf(bd[u - 1], d2));
    bd[0] = fminf(bd[0], d2);
  }
#pragma unroll
  for (int u = 0; u < 8; u++) mb.v[sp * 8 + u][ql] = bd[u];
  __syncthreads();

  // ---- U merge stage 1: wave m (m<8) merges splits 2m,2m+1 -> rows 16m..16m+7
  if (sp < 8) {
    float cd[8];
#pragma unroll
    for (int u = 0; u < 8; u++) cd[u] = INFINITY;
    int base = sp * 16;
#pragma unroll
    for (int e = 0; e < 16; e++) {
      float vv = mb.v[base + e][ql];
#pragma unroll
      for (int u = 7; u > 0; --u) cd[u] = fminf(cd[u], fmaxf(cd[u - 1], vv));
      cd[0] = fminf(cd[0], vv);
    }
#pragma unroll
    for (int u = 0; u < 8; u++) mb.v[base + u][ql] = cd[u];
  }
  __syncthreads();

  // ---- U merge stage 2: wave 0 merges 8 sorted lists with __all-break
  if (sp == 0) {
    float cd[8];
#pragma unroll
    for (int u = 0; u < 8; u++) cd[u] = INFINITY;
    for (int m = 0; m < 8; m++) {
      for (int e = 0; e < 8; e++) {
        float vv = mb.v[m * 16 + e][ql];
        if (__all(vv >= cd[7])) break;   // sorted list: rest can't contribute
#pragma unroll
        for (int u = 7; u > 0; --u) cd[u] = fminf(cd[u], fmaxf(cd[u - 1], vv));
        cd[0] = fminf(cd[0], vv);
      }
    }
    thrq[ql] = cd[7];
  }
  __syncthreads();
  float U = thrq[ql];

  // ---- pass 2: exact per-split top-8 of hits (d2<=U), f64 keys in registers
  double kd[8];
#pragma unroll
  for (int u = 0; u < 8; u++) kd[u] = INFINITY;
#pragma unroll 4
  for (int jj = 0; jj < NN / SPLITS; ++jj) {
    float d2 = dist2(qp, cp[jj]);
    if (d2 <= U) {
      double key = __hiloint2double(__float_as_int(d2), sp * (NN / SPLITS) + jj);
      if (key < kd[7]) {
#pragma unroll
        for (int u = 7; u > 0; --u) kd[u] = fmin(kd[u], fmax(kd[u - 1], key));
        kd[0] = fmin(kd[0], key);
      }
    }
  }
#pragma unroll
  for (int u = 0; u < 8; u++) mb.k[sp * 8 + u][ql] = kd[u];
  __syncthreads();

  // ---- key merge stage 1: wave m (m<8) merges splits 2m,2m+1 (sorted lists)
  if (sp < 8) {
    double cd[8];
#pragma unroll
    for (int u = 0; u < 8; u++) cd[u] = INFINITY;
    int base = sp * 16;
#pragma unroll
    for (int e = 0; e < 16; e++) {
      double key = mb.k[base + e][ql];
#pragma unroll
      for (int u = 7; u > 0; --u) cd[u] = fmin(cd[u], fmax(cd[u - 1], key));
      cd[0] = fmin(cd[0], key);
    }
#pragma unroll
    for (int u = 0; u < 8; u++) mb.k[base + u][ql] = cd[u];
  }
  __syncthreads();

  // ---- key merge stage 2: wave 0, sorted lists, __all-break; write indices
  if (sp == 0) {
    double cd[8];
#pragma unroll
    for (int u = 0; u < 8; u++) cd[u] = INFINITY;
    for (int m = 0; m < 8; m++) {
      for (int e = 0; e < 8; e++) {
        double key = mb.k[m * 16 + e][ql];
        if (__all(key >= cd[7])) break;
#pragma unroll
        for (int u = 7; u > 0; --u) cd[u] = fmin(cd[u], fmax(cd[u - 1], key));
        cd[0] = fmin(cd[0], key);
      }
    }
    int* op = idx + ((size_t)b * NN + qbase + ql) * 8;
#pragma unroll
    for (int u = 0; u < 8; u++) op[u] = __double2loint(cd[u]);
  }
}

// ---------------------------------------------------------------- qkv projection (4 points per wave)
__global__ __launch_bounds__(256) void qkv_kernel(
    const float* __restrict__ h, const float* __restrict__ wq, const float* __restrict__ bq,
    const float* __restrict__ wk, const float* __restrict__ bk,
    const float* __restrict__ wv, const float* __restrict__ bv,
    float* __restrict__ q, float* __restrict__ k, float* __restrict__ v) {
  __shared__ float lwq[DD * DD], lwk[DD * DD], lwv[DD * DD];
  __shared__ float lbq[DD], lbk[DD], lbv[DD];
  __shared__ __attribute__((aligned(16))) float hb[4][DD][4];
  int tid = threadIdx.x;
  for (int i = tid; i < DD * DD; i += 256) { lwq[i] = wq[i]; lwk[i] = wk[i]; lwv[i] = wv[i]; }
  if (tid < DD) { lbq[tid] = bq[tid]; lbk[tid] = bk[tid]; lbv[tid] = bv[tid]; }
  __syncthreads();
  int w = tid >> 6, c = tid & 63;
  constexpr int ITERS = (BB * NN) / (QKV_GRID * 16);
  for (int it = 0; it < ITERS; ++it) {
    int wid = it * (QKV_GRID * 4) + blockIdx.x * 4 + w;
    int p0 = wid * 4;
    __syncthreads();
#pragma unroll
    for (int i = 0; i < 4; i++) hb[w][c][i] = h[(size_t)(p0 + i) * 64 + c];
    __syncthreads();
    float aq[4], ak[4], av[4];
#pragma unroll
    for (int i = 0; i < 4; i++) { aq[i] = lbq[c]; ak[i] = lbk[c]; av[i] = lbv[c]; }
#pragma unroll 4
    for (int d = 0; d < DD; d++) {
      float wq_ = lwq[d * 64 + c], wk_ = lwk[d * 64 + c], wv_ = lwv[d * 64 + c];
      float4 hh = *(const float4*)&hb[w][d][0];
      aq[0] = fmaf(hh.x, wq_, aq[0]); aq[1] = fmaf(hh.y, wq_, aq[1]);
      aq[2] = fmaf(hh.z, wq_, aq[2]); aq[3] = fmaf(hh.w, wq_, aq[3]);
      ak[0] = fmaf(hh.x, wk_, ak[0]); ak[1] = fmaf(hh.y, wk_, ak[1]);
      ak[2] = fmaf(hh.z, wk_, ak[2]); ak[3] = fmaf(hh.w, wk_, ak[3]);
      av[0] = fmaf(hh.x, wv_, av[0]); av[1] = fmaf(hh.y, wv_, av[1]);
      av[2] = fmaf(hh.z, wv_, av[2]); av[3] = fmaf(hh.w, wv_, av[3]);
    }
#pragma unroll
    for (int i = 0; i < 4; i++) {
      q[(size_t)(p0 + i) * 64 + c] = aq[i];
      k[(size_t)(p0 + i) * 64 + c] = ak[i];
      v[(size_t)(p0 + i) * 64 + c] = av[i];
    }
  }
}

// ---------------------------------------------------------------- attention (1 point per wave) -> t = ln1(attn+x)
// NOTE: t may alias q (same-point read-then-write only) -> no __restrict__ on q/t.
__global__ __launch_bounds__(256) void attn_kernel(
    const float* __restrict__ x, const float* __restrict__ h,
    const float* q, const float* __restrict__ kk, const float* __restrict__ vv,
    const int* __restrict__ idx,
    const float* __restrict__ pw1, const float* __restrict__ pb1,
    const float* __restrict__ pw2, const float* __restrict__ pb2,
    const float* __restrict__ aw, const float* __restrict__ ab,
    const float* __restrict__ ow, const float* __restrict__ ob,
    const float* __restrict__ l1g, const float* __restrict__ l1b,
    float* t) {
  __shared__ float lpw2[DD * DD], low[DD * DD];
  __shared__ float lpw1[3 * DD], lpb1[DD], lpb2[DD], law[DD], lob[DD], ll1g[DD], ll1b[DD];
  __shared__ __attribute__((aligned(16))) float h1lo[4][DD][4], h1hi[4][DD][4];
  __shared__ __attribute__((aligned(16))) float outb[4][DD];
  int tid = threadIdx.x;
  for (int i = tid; i < DD * DD; i += 256) { lpw2[i] = pw2[i]; low[i] = ow[i]; }
  if (tid < 3 * DD) lpw1[tid] = pw1[tid];
  if (tid < DD) {
    lpb1[tid] = pb1[tid]; lpb2[tid] = pb2[tid]; law[tid] = aw[tid];
    lob[tid] = ob[tid]; ll1g[tid] = l1g[tid]; ll1b[tid] = l1b[tid];
  }
  float lab = ab[0];
  __syncthreads();
  int w = tid >> 6, c = tid & 63;
  constexpr int ITERS = (BB * NN) / (ATTN_GRID * 4);
  for (int it = 0; it < ITERS; ++it) {
    int p = (it * ATTN_GRID + blockIdx.x) * 4 + w;
    int b = p >> 12;
    int n = p & (NN - 1);
    const float* xb = x + (size_t)b * NN * 3;
    float hs = h[(size_t)p * 64 + c];
    float qs = q[(size_t)p * 64 + c];
    float px0 = xb[n * 3 + 0], px1 = xb[n * 3 + 1], px2 = xb[n * 3 + 2];
    int nb[8];
#pragma unroll
    for (int u = 0; u < 8; u++) nb[u] = idx[(size_t)p * 8 + u];
    __syncthreads();
#pragma unroll
    for (int u = 0; u < 8; u++) {
      int m = nb[u];
      float d0 = px0 - xb[m * 3 + 0], d1 = px1 - xb[m * 3 + 1], d2 = px2 - xb[m * 3 + 2];
      float h1 = fmaf(d0, lpw1[c], fmaf(d1, lpw1[64 + c], fmaf(d2, lpw1[128 + c], lpb1[c])));
      h1 = fmaxf(h1, 0.0f);
      if (u < 4) h1lo[w][c][u] = h1; else h1hi[w][c][u - 4] = h1;
    }
    __syncthreads();
    float acc[8];
#pragma unroll
    for (int u = 0; u < 8; u++) acc[u] = lpb2[c];
#pragma unroll 4
    for (int d = 0; d < DD; d++) {
      float wv_ = lpw2[d * 64 + c];
      float4 lo = *(const float4*)&h1lo[w][d][0];
      float4 hi = *(const float4*)&h1hi[w][d][0];
      acc[0] = fmaf(lo.x, wv_, acc[0]); acc[1] = fmaf(lo.y, wv_, acc[1]);
      acc[2] = fmaf(lo.z, wv_, acc[2]); acc[3] = fmaf(lo.w, wv_, acc[3]);
      acc[4] = fmaf(hi.x, wv_, acc[4]); acc[5] = fmaf(hi.y, wv_, acc[5]);
      acc[6] = fmaf(hi.z, wv_, acc[6]); acc[7] = fmaf(hi.w, wv_, acc[7]);
    }
    float lg[8];
#pragma unroll
    for (int u = 0; u < 8; u++) {
      float kv = kk[((size_t)(b << 12) + nb[u]) * 64 + c];
      float ai = qs - kv + acc[u];
      lg[u] = wave_sum(ai * law[c]) + lab;
    }
    float mx = lg[0];
#pragma unroll
    for (int u = 1; u < 8; u++) mx = fmaxf(mx, lg[u]);
    float ssum = 0.0f;
#pragma unroll
    for (int u = 0; u < 8; u++) { lg[u] = expf(lg[u] - mx); ssum += lg[u]; }
    float inv = 1.0f / ssum;
    float out = 0.0f;
#pragma unroll
    for (int u = 0; u < 8; u++) {
      float vg = vv[((size_t)(b << 12) + nb[u]) * 64 + c];
      out = fmaf(lg[u] * inv, vg + acc[u], out);
    }
    outb[w][c] = out;
    __syncthreads();
    float at = lob[c];
#pragma unroll 4
    for (int d = 0; d < DD; d += 4) {
      float4 ov = *(const float4*)&outb[w][d];
      at = fmaf(ov.x, low[(d + 0) * 64 + c], at);
      at = fmaf(ov.y, low[(d + 1) * 64 + c], at);
      at = fmaf(ov.z, low[(d + 2) * 64 + c], at);
      at = fmaf(ov.w, low[(d + 3) * 64 + c], at);
    }
    float res = at + hs;
    float mean = wave_sum(res) * (1.0f / 64.0f);
    float dv = res - mean;
    float var = wave_sum(dv * dv) * (1.0f / 64.0f);
    float ivr = 1.0f / sqrtf(var + LNEPS);
    t[(size_t)p * 64 + c] = fmaf(ll1g[c], dv * ivr, ll1b[c]);
  }
}

// ---------------------------------------------------------------- ffn (4 points per wave) -> h = ln2(t + ffn(t))
__global__ __launch_bounds__(256) void ffn_kernel(
    const float* __restrict__ t, const float* __restrict__ fw1, const float* __restrict__ fb1,
    const float* __restrict__ fw2, const float* __restrict__ fb2,
    const float* __restrict__ l2g, const float* __restrict__ l2b, float* __restrict__ h) {
  __shared__ float lf1[DD * 128];
  __shared__ float lf2[128 * DD];
  __shared__ float lb1[128], lb2[DD], lg2[DD], lbt2[DD];
  __shared__ __attribute__((aligned(16))) float yb[4][DD][4];
  __shared__ __attribute__((aligned(16))) float hb[4][128][4];
  int tid = threadIdx.x;
  for (int i = tid; i < DD * 128; i += 256) { lf1[i] = fw1[i]; lf2[i] = fw2[i]; }
  if (tid < 128) lb1[tid] = fb1[tid];
  if (tid < DD) { lb2[tid] = fb2[tid]; lg2[tid] = l2g[tid]; lbt2[tid] = l2b[tid]; }
  __syncthreads();
  int w = tid >> 6, c = tid & 63;
  constexpr int ITERS = (BB * NN) / (FFN_GRID * 16);
  for (int it = 0; it < ITERS; ++it) {
    int wid = it * (FFN_GRID * 4) + blockIdx.x * 4 + w;
    int p0 = wid * 4;
    float y[4];
    __syncthreads();
#pragma unroll
    for (int i = 0; i < 4; i++) { y[i] = t[(size_t)(p0 + i) * 64 + c]; yb[w][c][i] = y[i]; }
    __syncthreads();
    float hA[4], hB[4];
#pragma unroll
    for (int i = 0; i < 4; i++) { hA[i] = lb1[c]; hB[i] = lb1[64 + c]; }
#pragma unroll 4
    for (int d = 0; d < DD; d++) {
      float w0 = lf1[d * 128 + c], w1 = lf1[d * 128 + 64 + c];
      float4 yv = *(const float4*)&yb[w][d][0];
      hA[0] = fmaf(yv.x, w0, hA[0]); hA[1] = fmaf(yv.y, w0, hA[1]);
      hA[2] = fmaf(yv.z, w0, hA[2]); hA[3] = fmaf(yv.w, w0, hA[3]);
      hB[0] = fmaf(yv.x, w1, hB[0]); hB[1] = fmaf(yv.y, w1, hB[1]);
      hB[2] = fmaf(yv.z, w1, hB[2]); hB[3] = fmaf(yv.w, w1, hB[3]);
    }
#pragma unroll
    for (int i = 0; i < 4; i++) {
      hA[i] = gelu_exact(hA[i]); hB[i] = gelu_exact(hB[i]);
      hb[w][c][i] = hA[i]; hb[w][64 + c][i] = hB[i];
    }
    __syncthreads();
    float o[4];
#pragma unroll
    for (int i = 0; i < 4; i++) o[i] = lb2[c];
#pragma unroll 4
    for (int j = 0; j < 128; j++) {
      float wv_ = lf2[j * 64 + c];
      float4 hv = *(const float4*)&hb[w][j][0];
      o[0] = fmaf(hv.x, wv_, o[0]); o[1] = fmaf(hv.y, wv_, o[1]);
      o[2] = fmaf(hv.z, wv_, o[2]); o[3] = fmaf(hv.w, wv_, o[3]);
    }
#pragma unroll
    for (int i = 0; i < 4; i++) {
      float r = y[i] + o[i];
      float mean = wave_sum(r) * (1.0f / 64.0f);
      float dv = r - mean;
      float var = wave_sum(dv * dv) * (1.0f / 64.0f);
      float ivr = 1.0f / sqrtf(var + LNEPS);
      h[(size_t)(p0 + i) * 64 + c] = fmaf(lg2[c], dv * ivr, lbt2[c]);
    }
  }
}

// ---------------------------------------------------------------- classifier proj + blockwise max-pool
__global__ __launch_bounds__(256) void cls_kernel(
    const float* __restrict__ h, const float* __restrict__ cw, const float* __restrict__ cb,
    const float* __restrict__ cg, const float* __restrict__ cbeta, float* __restrict__ g) {
  __shared__ float lcw[DD * 128];
  __shared__ float lcb[128], lcg[128], lcbt[128];
  __shared__ __attribute__((aligned(16))) float hb[4][DD][4];
  __shared__ float wmax[4][128];
  int tid = threadIdx.x;
  for (int i = tid; i < DD * 128; i += 256) lcw[i] = cw[i];
  if (tid < 128) { lcb[tid] = cb[tid]; lcg[tid] = cg[tid]; lcbt[tid] = cbeta[tid]; }
  __syncthreads();
  int w = tid >> 6, c = tid & 63;
  int b = blockIdx.x >> 7;            // 128 blocks per batch
  int blk = blockIdx.x & 127;
  int base = b * NN + blk * 32;
  float m0 = 0.0f, m1 = 0.0f;
  for (int it = 0; it < 2; ++it) {
    int p0 = base + (w * 2 + it) * 4;
    __syncthreads();
#pragma unroll
    for (int i = 0; i < 4; i++) hb[w][c][i] = h[(size_t)(p0 + i) * 64 + c];
    __syncthreads();
    float a0[4], a1[4];
#pragma unroll
    for (int i = 0; i < 4; i++) { a0[i] = lcb[c]; a1[i] = lcb[64 + c]; }
#pragma unroll 4
    for (int d = 0; d < DD; d++) {
      float w0 = lcw[d * 128 + c], w1 = lcw[d * 128 + 64 + c];
      float4 hv = *(const float4*)&hb[w][d][0];
      a0[0] = fmaf(hv.x, w0, a0[0]); a0[1] = fmaf(hv.y, w0, a0[1]);
      a0[2] = fmaf(hv.z, w0, a0[2]); a0[3] = fmaf(hv.w, w0, a0[3]);
      a1[0] = fmaf(hv.x, w1, a1[0]); a1[1] = fmaf(hv.y, w1, a1[1]);
      a1[2] = fmaf(hv.z, w1, a1[2]); a1[3] = fmaf(hv.w, w1, a1[3]);
    }
#pragma unroll
    for (int i = 0; i < 4; i++) {
      m0 = fmaxf(m0, fmaxf(0.0f, fmaf(lcg[c] * a0[i], BNRS, lcbt[c])));
      m1 = fmaxf(m1, fmaxf(0.0f, fmaf(lcg[64 + c] * a1[i], BNRS, lcbt[64 + c])));
    }
  }
  wmax[w][c] = m0; wmax[w][64 + c] = m1;
  __syncthreads();
  if (tid < 128) {
    float mm = fmaxf(fmaxf(wmax[0][tid], wmax[1][tid]), fmaxf(wmax[2][tid], wmax[3][tid]));
    atomicMax((int*)&g[b * 128 + tid], __float_as_int(mm));  // values >= 0
  }
}

// ---------------------------------------------------------------- final head (per batch)
__global__ __launch_bounds__(128) void head_kernel(
    const float* __restrict__ g,
    const float* __restrict__ f1w, const float* __restrict__ f1b,
    const float* __restrict__ b1g, const float* __restrict__ b1b,
    const float* __restrict__ f2w, const float* __restrict__ f2b,
    const float* __restrict__ b2g, const float* __restrict__ b2b,
    const float* __restrict__ f3w, const float* __restrict__ f3b,
    float* __restrict__ out) {
  __shared__ float gb[128], g1[128], g2[64];
  int b = blockIdx.x, t = threadIdx.x;
  gb[t] = g[b * 128 + t];
  __syncthreads();
  float a = f1b[t];
#pragma unroll 4
  for (int d = 0; d < 128; d++) a = fmaf(gb[d], f1w[d * 128 + t], a);
  g1[t] = fmaxf(0.0f, fmaf(b1g[t] * a, BNRS, b1b[t]));
  __syncthreads();
  if (t < 64) {
    float a2 = f2b[t];
#pragma unroll 4
    for (int j = 0; j < 128; j++) a2 = fmaf(g1[j], f2w[j * 64 + t], a2);
    g2[t] = fmaxf(0.0f, fmaf(b2g[t] * a2, BNRS, b2b[t]));
  }
  __syncthreads();
  if (t < NCLS) {
    float a3 = f3b[t];
#pragma unroll
    for (int d = 0; d < 64; d++) a3 = fmaf(g2[d], f3w[d * NCLS + t], a3);
    out[b * NCLS + t] = a3;
  }
}

extern "C" void kernel_launch(void* const* d_in, const int* in_sizes, int n_in,
                              void* d_out, int out_size, void* d_ws, size_t ws_size,
                              hipStream_t stream) {
  const float* x    = (const float*)d_in[0];
  const float* ew1  = (const float*)d_in[1];
  const float* eb1  = (const float*)d_in[2];
  const float* ew2  = (const float*)d_in[3];
  const float* eb2  = (const float*)d_in[4];
  const float* wq   = (const float*)d_in[5];
  const float* bq   = (const float*)d_in[6];
  const float* wk   = (const float*)d_in[7];
  const float* bk   = (const float*)d_in[8];
  const float* wv   = (const float*)d_in[9];
  const float* bv   = (const float*)d_in[10];
  const float* pw1  = (const float*)d_in[11];
  const float* pb1  = (const float*)d_in[12];
  const float* pw2  = (const float*)d_in[13];
  const float* pb2  = (const float*)d_in[14];
  const float* aw   = (const float*)d_in[15];
  const float* ab   = (const float*)d_in[16];
  const float* ow   = (const float*)d_in[17];
  const float* ob   = (const float*)d_in[18];
  const float* l1g  = (const float*)d_in[19];
  const float* l1b  = (const float*)d_in[20];
  const float* l2g  = (const float*)d_in[21];
  const float* l2b  = (const float*)d_in[22];
  const float* fw1  = (const float*)d_in[23];
  const float* fb1  = (const float*)d_in[24];
  const float* fw2  = (const float*)d_in[25];
  const float* fb2  = (const float*)d_in[26];
  const float* cw   = (const float*)d_in[27];
  const float* cb   = (const float*)d_in[28];
  const float* cg   = (const float*)d_in[29];
  const float* cbeta= (const float*)d_in[30];
  const float* f1w  = (const float*)d_in[31];
  const float* f1b  = (const float*)d_in[32];
  const float* b1g  = (const float*)d_in[33];
  const float* b1b  = (const float*)d_in[34];
  const float* f2w  = (const float*)d_in[35];
  const float* f2b  = (const float*)d_in[36];
  const float* b2g  = (const float*)d_in[37];
  const float* b2b  = (const float*)d_in[38];
  const float* f3w  = (const float*)d_in[39];
  const float* f3b  = (const float*)d_in[40];

  const size_t P = (size_t)BB * NN;       // 32768 points
  float* ws = (float*)d_ws;
  float* h = ws;                          // P*64
  float* q = h + P * 64;
  float* k = q + P * 64;
  float* v = k + P * 64;
  int* idx = (int*)(v + P * 64);          // P*8 ints
  float* g = (float*)(idx + P * 8);       // B*128
  float4* ppg = (float4*)(g + BB * 128);  // P float4 (aligned: offset is 16B-multiple)
  float* t = q;                           // alias: safe (same-point read-then-write)

  zero_kernel<<<1, BB * 128, 0, stream>>>(g);
  embed_kernel<<<(int)(P / 4), 256, 0, stream>>>(x, ew1, eb1, ew2, eb2, h);
  knn_prep_kernel<<<(int)(P / 256), 256, 0, stream>>>(x, ppg);
  knn_kernel<<<BB * (NN / QPB), 1024, 0, stream>>>(ppg, idx);
  for (int l = 0; l < 2; l++) {
    qkv_kernel<<<QKV_GRID, 256, 0, stream>>>(h, wq + l * DD * DD, bq + l * DD,
                                             wk + l * DD * DD, bk + l * DD,
                                             wv + l * DD * DD, bv + l * DD, q, k, v);
    attn_kernel<<<ATTN_GRID, 256, 0, stream>>>(x, h, q, k, v, idx,
                                               pw1 + l * 3 * DD, pb1 + l * DD,
                                               pw2 + l * DD * DD, pb2 + l * DD,
                                               aw + l * DD, ab + l,
                                               ow + l * DD * DD, ob + l * DD,
                                               l1g + l * DD, l1b + l * DD, t);
    ffn_kernel<<<FFN_GRID, 256, 0, stream>>>(t, fw1 + l * DD * 2 * DD, fb1 + l * 2 * DD,
                                             fw2 + l * 2 * DD * DD, fb2 + l * DD,
                                             l2g + l * DD, l2b + l * DD, h);
  }
  cls_kernel<<<BB * 128, 256, 0, stream>>>(h, cw, cb, cg, cbeta, g);
  head_kernel<<<BB, 128, 0, stream>>>(g, f1w, f1b, b1g, b1b, f2w, f2b, b2g, b2b, f3w, f3b,
                                      (float*)d_out);
}

// Round 8
// 426.046 us; speedup vs baseline: 1.2484x; 1.1080x over previous
//
#include <hip/hip_runtime.h>
#include <cmath>

#define BB 8
#define NN 4096
#define DD 64
#define KK 8
#define NCLS 2

constexpr float LNEPS = 1e-5f;
constexpr float BNRS = 0.9999950000374994f;      // 1/sqrt(1+1e-5)
constexpr float INVSQRT2 = 0.70710678118654752440f;

constexpr int QKV_GRID = 512;
constexpr int ATTN_GRID = 1024;
constexpr int FFN_GRID = 512;

// knn decomposition: 64 queries/block x 16 candidate-splits (one per wave)
#define QPB 64
#define SPLITS 16
#define SUBSET 64     // pass-1 subset per split (16*64 = 1024-point bound set)

__device__ __forceinline__ float wave_sum(float v) {
#pragma unroll
  for (int m = 32; m > 0; m >>= 1) v += __shfl_xor(v, m, 64);
  return v;
}

__device__ __forceinline__ float gelu_exact(float x) {
  return 0.5f * x * (1.0f + erff(x * INVSQRT2));
}

// identical in both knn passes -> bit-identical distances
__device__ __forceinline__ float dist2(float4 q, float4 p) {
  float dot = fmaf(q.x, p.x, fmaf(q.y, p.y, q.z * p.z));
  return fmaf(-2.0f, dot, q.w + p.w);
}

// ---------------------------------------------------------------- zero g
__global__ void zero_kernel(float* g) { g[threadIdx.x] = 0.0f; }

// ---------------------------------------------------------------- embed: h = relu(x@ew1+eb1)@ew2+eb2
// h1 is wave-private -> no barrier needed (lockstep lanes, in-order DS ops)
__global__ __launch_bounds__(256) void embed_kernel(
    const float* __restrict__ x, const float* __restrict__ ew1, const float* __restrict__ eb1,
    const float* __restrict__ ew2, const float* __restrict__ eb2, float* __restrict__ h) {
  __shared__ float h1[4][DD];
  int w = threadIdx.x >> 6, c = threadIdx.x & 63;
  int pt = blockIdx.x * 4 + w;
  const float* xp = x + (size_t)pt * 3;
  float x0 = xp[0], x1 = xp[1], x2 = xp[2];
  float a = fmaf(x0, ew1[c], fmaf(x1, ew1[64 + c], fmaf(x2, ew1[128 + c], eb1[c])));
  h1[w][c] = fmaxf(a, 0.0f);
  float s = eb2[c];
#pragma unroll 8
  for (int d = 0; d < DD; d++) s = fmaf(h1[w][d], ew2[d * 64 + c], s);
  h[(size_t)pt * 64 + c] = s;
}

// ---------------------------------------------------------------- knn prep: ppg[b*N+j] = (x,y,z,|p|^2)
__global__ __launch_bounds__(256) void knn_prep_kernel(const float* __restrict__ x,
                                                       float4* __restrict__ ppg) {
  int i = blockIdx.x * 256 + threadIdx.x;
  float a0 = x[3 * i + 0], a1 = x[3 * i + 1], a2 = x[3 * i + 2];
  ppg[i] = make_float4(a0, a1, a2, a0 * a0 + a1 * a1 + a2 * a2);
}

// ---------------------------------------------------------------- knn: exact top-8 (stable ties), 2-pass
__global__ __launch_bounds__(1024) void knn_kernel(const float4* __restrict__ ppg,
                                                   int* __restrict__ idx) {
  __shared__ union {
    float v[SPLITS * 8][QPB];       // pass-1 value lists
    double k[SPLITS * 8][QPB];      // pass-2 key lists (64 KB)
  } mb;
  __shared__ float thrq[QPB];
  int b = blockIdx.x >> 6;          // 64 blocks per batch
  int qbase = (blockIdx.x & 63) * QPB;
  const float4* pb = ppg + (size_t)b * NN;
  int ql = threadIdx.x & 63;
  int sp = __builtin_amdgcn_readfirstlane(threadIdx.x >> 6);  // wave id = split id (SGPR)
  float4 qp = pb[qbase + ql];
  const float4* cp = pb + sp * (NN / SPLITS);                 // scalar base

  // ---- pass 1: branchless top-8 distances over SUBSET candidates
  float bd[8];
#pragma unroll
  for (int u = 0; u < 8; u++) bd[u] = INFINITY;
#pragma unroll 4
  for (int jj = 0; jj < SUBSET; ++jj) {
    float d2 = dist2(qp, cp[jj]);
#pragma unroll
    for (int u = 7; u > 0; --u) bd[u] = fminf(bd[u], fmaxf(bd[u - 1], d2));
    bd[0] = fminf(bd[0], d2);
  }
#pragma unroll
  for (int u = 0; u < 8; u++) mb.v[sp * 8 + u][ql] = bd[u];
  __syncthreads();

  // ---- U merge stage 1
  if (sp < 8) {
    float cd[8];
#pragma unroll
    for (int u = 0; u < 8; u++) cd[u] = INFINITY;
    int base = sp * 16;
#pragma unroll
    for (int e = 0; e < 16; e++) {
      float vv = mb.v[base + e][ql];
#pragma unroll
      for (int u = 7; u > 0; --u) cd[u] = fminf(cd[u], fmaxf(cd[u - 1], vv));
      cd[0] = fminf(cd[0], vv);
    }
#pragma unroll
    for (int u = 0; u < 8; u++) mb.v[base + u][ql] = cd[u];
  }
  __syncthreads();

  // ---- U merge stage 2
  if (sp == 0) {
    float cd[8];
#pragma unroll
    for (int u = 0; u < 8; u++) cd[u] = INFINITY;
    for (int m = 0; m < 8; m++) {
      for (int e = 0; e < 8; e++) {
        float vv = mb.v[m * 16 + e][ql];
        if (__all(vv >= cd[7])) break;
#pragma unroll
        for (int u = 7; u > 0; --u) cd[u] = fminf(cd[u], fmaxf(cd[u - 1], vv));
        cd[0] = fminf(cd[0], vv);
      }
    }
    thrq[ql] = cd[7];
  }
  __syncthreads();
  float U = thrq[ql];

  // ---- pass 2: exact per-split top-8 of hits (d2<=U), f64 keys in registers
  double kd[8];
#pragma unroll
  for (int u = 0; u < 8; u++) kd[u] = INFINITY;
#pragma unroll 4
  for (int jj = 0; jj < NN / SPLITS; ++jj) {
    float d2 = dist2(qp, cp[jj]);
    if (d2 <= U) {
      double key = __hiloint2double(__float_as_int(d2), sp * (NN / SPLITS) + jj);
      if (key < kd[7]) {
#pragma unroll
        for (int u = 7; u > 0; --u) kd[u] = fmin(kd[u], fmax(kd[u - 1], key));
        kd[0] = fmin(kd[0], key);
      }
    }
  }
#pragma unroll
  for (int u = 0; u < 8; u++) mb.k[sp * 8 + u][ql] = kd[u];
  __syncthreads();

  // ---- key merge stage 1
  if (sp < 8) {
    double cd[8];
#pragma unroll
    for (int u = 0; u < 8; u++) cd[u] = INFINITY;
    int base = sp * 16;
#pragma unroll
    for (int e = 0; e < 16; e++) {
      double key = mb.k[base + e][ql];
#pragma unroll
      for (int u = 7; u > 0; --u) cd[u] = fmin(cd[u], fmax(cd[u - 1], key));
      cd[0] = fmin(cd[0], key);
    }
#pragma unroll
    for (int u = 0; u < 8; u++) mb.k[base + u][ql] = cd[u];
  }
  __syncthreads();

  // ---- key merge stage 2 + write
  if (sp == 0) {
    double cd[8];
#pragma unroll
    for (int u = 0; u < 8; u++) cd[u] = INFINITY;
    for (int m = 0; m < 8; m++) {
      for (int e = 0; e < 8; e++) {
        double key = mb.k[m * 16 + e][ql];
        if (__all(key >= cd[7])) break;
#pragma unroll
        for (int u = 7; u > 0; --u) cd[u] = fmin(cd[u], fmax(cd[u - 1], key));
        cd[0] = fmin(cd[0], key);
      }
    }
    int* op = idx + ((size_t)b * NN + qbase + ql) * 8;
#pragma unroll
    for (int u = 0; u < 8; u++) op[u] = __double2loint(cd[u]);
  }
}

// ---------------------------------------------------------------- qkv projection (4 points per wave)
// hb is wave-private -> in-loop barriers removed
__global__ __launch_bounds__(256) void qkv_kernel(
    const float* __restrict__ h, const float* __restrict__ wq, const float* __restrict__ bq,
    const float* __restrict__ wk, const float* __restrict__ bk,
    const float* __restrict__ wv, const float* __restrict__ bv,
    float* __restrict__ q, float* __restrict__ k, float* __restrict__ v) {
  __shared__ float lwq[DD * DD], lwk[DD * DD], lwv[DD * DD];
  __shared__ float lbq[DD], lbk[DD], lbv[DD];
  __shared__ __attribute__((aligned(16))) float hb[4][DD][4];
  int tid = threadIdx.x;
  for (int i = tid; i < DD * DD; i += 256) { lwq[i] = wq[i]; lwk[i] = wk[i]; lwv[i] = wv[i]; }
  if (tid < DD) { lbq[tid] = bq[tid]; lbk[tid] = bk[tid]; lbv[tid] = bv[tid]; }
  __syncthreads();
  int w = tid >> 6, c = tid & 63;
  constexpr int ITERS = (BB * NN) / (QKV_GRID * 16);
  for (int it = 0; it < ITERS; ++it) {
    int wid = it * (QKV_GRID * 4) + blockIdx.x * 4 + w;
    int p0 = wid * 4;
#pragma unroll
    for (int i = 0; i < 4; i++) hb[w][c][i] = h[(size_t)(p0 + i) * 64 + c];
    float aq[4], ak[4], av[4];
#pragma unroll
    for (int i = 0; i < 4; i++) { aq[i] = lbq[c]; ak[i] = lbk[c]; av[i] = lbv[c]; }
#pragma unroll 4
    for (int d = 0; d < DD; d++) {
      float wq_ = lwq[d * 64 + c], wk_ = lwk[d * 64 + c], wv_ = lwv[d * 64 + c];
      float4 hh = *(const float4*)&hb[w][d][0];
      aq[0] = fmaf(hh.x, wq_, aq[0]); aq[1] = fmaf(hh.y, wq_, aq[1]);
      aq[2] = fmaf(hh.z, wq_, aq[2]); aq[3] = fmaf(hh.w, wq_, aq[3]);
      ak[0] = fmaf(hh.x, wk_, ak[0]); ak[1] = fmaf(hh.y, wk_, ak[1]);
      ak[2] = fmaf(hh.z, wk_, ak[2]); ak[3] = fmaf(hh.w, wk_, ak[3]);
      av[0] = fmaf(hh.x, wv_, av[0]); av[1] = fmaf(hh.y, wv_, av[1]);
      av[2] = fmaf(hh.z, wv_, av[2]); av[3] = fmaf(hh.w, wv_, av[3]);
    }
#pragma unroll
    for (int i = 0; i < 4; i++) {
      q[(size_t)(p0 + i) * 64 + c] = aq[i];
      k[(size_t)(p0 + i) * 64 + c] = ak[i];
      v[(size_t)(p0 + i) * 64 + c] = av[i];
    }
  }
}

// ---------------------------------------------------------------- attention (2 points per wave) -> t = ln1(attn+x)
// h1b/outb are wave-private -> no in-loop barriers. ow read from global (L1/L2-hot).
// NOTE: t may alias q (same-point read-then-write only) -> no __restrict__ on q/t.
__global__ __launch_bounds__(256) void attn_kernel(
    const float* __restrict__ x, const float* __restrict__ h,
    const float* q, const float* __restrict__ kk, const float* __restrict__ vv,
    const int* __restrict__ idx,
    const float* __restrict__ pw1, const float* __restrict__ pb1,
    const float* __restrict__ pw2, const float* __restrict__ pb2,
    const float* __restrict__ aw, const float* __restrict__ ab,
    const float* __restrict__ ow, const float* __restrict__ ob,
    const float* __restrict__ l1g, const float* __restrict__ l1b,
    float* t) {
  __shared__ float lpw2[DD * DD];
  __shared__ float lpw1[3 * DD], lpb1[DD], lpb2[DD], law[DD], lob_[DD], ll1g[DD], ll1b[DD];
  __shared__ __attribute__((aligned(16))) float h1b[4][2][DD][8];   // [wave][pt][d][u] 16KB
  __shared__ __attribute__((aligned(16))) float outb[4][2][DD];     // 2KB
  int tid = threadIdx.x;
  for (int i = tid; i < DD * DD; i += 256) lpw2[i] = pw2[i];
  if (tid < 3 * DD) lpw1[tid] = pw1[tid];
  if (tid < DD) {
    lpb1[tid] = pb1[tid]; lpb2[tid] = pb2[tid]; law[tid] = aw[tid];
    lob_[tid] = ob[tid]; ll1g[tid] = l1g[tid]; ll1b[tid] = l1b[tid];
  }
  float lab = ab[0];
  __syncthreads();
  int w = tid >> 6, c = tid & 63;
  constexpr int ITERS = (BB * NN) / (ATTN_GRID * 8);
  for (int it = 0; it < ITERS; ++it) {
    int p0 = (it * ATTN_GRID + blockIdx.x) * 8 + w * 2;   // p0 even -> p0,p0+1 same batch
    int b = p0 >> 12;
    int n0 = p0 & (NN - 1);
    const float* xb = x + (size_t)b * NN * 3;
    float hs0 = h[(size_t)p0 * 64 + c], hs1 = h[(size_t)(p0 + 1) * 64 + c];
    float qs0 = q[(size_t)p0 * 64 + c], qs1 = q[(size_t)(p0 + 1) * 64 + c];
    int nb[2][8];
#pragma unroll
    for (int u = 0; u < 8; u++) {
      nb[0][u] = idx[(size_t)p0 * 8 + u];
      nb[1][u] = idx[(size_t)(p0 + 1) * 8 + u];
    }
    float w1c0 = lpw1[c], w1c1 = lpw1[64 + c], w1c2 = lpw1[128 + c], b1c = lpb1[c];
#pragma unroll
    for (int pt = 0; pt < 2; ++pt) {
      int n = n0 + pt;
      float px0 = xb[n * 3 + 0], px1 = xb[n * 3 + 1], px2 = xb[n * 3 + 2];
      float h1v[8];
#pragma unroll
      for (int u = 0; u < 8; u++) {
        int m = nb[pt][u];
        float d0 = px0 - xb[m * 3 + 0], d1 = px1 - xb[m * 3 + 1], d2 = px2 - xb[m * 3 + 2];
        h1v[u] = fmaxf(fmaf(d0, w1c0, fmaf(d1, w1c1, fmaf(d2, w1c2, b1c))), 0.0f);
      }
      *(float4*)&h1b[w][pt][c][0] = make_float4(h1v[0], h1v[1], h1v[2], h1v[3]);
      *(float4*)&h1b[w][pt][c][4] = make_float4(h1v[4], h1v[5], h1v[6], h1v[7]);
    }
    float acc0[8], acc1[8];
    float pb2c = lpb2[c];
#pragma unroll
    for (int u = 0; u < 8; u++) { acc0[u] = pb2c; acc1[u] = pb2c; }
#pragma unroll 2
    for (int d = 0; d < DD; d++) {
      float wv_ = lpw2[d * 64 + c];
      float4 a0 = *(const float4*)&h1b[w][0][d][0];
      float4 b0 = *(const float4*)&h1b[w][0][d][4];
      float4 a1 = *(const float4*)&h1b[w][1][d][0];
      float4 b1 = *(const float4*)&h1b[w][1][d][4];
      acc0[0] = fmaf(a0.x, wv_, acc0[0]); acc0[1] = fmaf(a0.y, wv_, acc0[1]);
      acc0[2] = fmaf(a0.z, wv_, acc0[2]); acc0[3] = fmaf(a0.w, wv_, acc0[3]);
      acc0[4] = fmaf(b0.x, wv_, acc0[4]); acc0[5] = fmaf(b0.y, wv_, acc0[5]);
      acc0[6] = fmaf(b0.z, wv_, acc0[6]); acc0[7] = fmaf(b0.w, wv_, acc0[7]);
      acc1[0] = fmaf(a1.x, wv_, acc1[0]); acc1[1] = fmaf(a1.y, wv_, acc1[1]);
      acc1[2] = fmaf(a1.z, wv_, acc1[2]); acc1[3] = fmaf(a1.w, wv_, acc1[3]);
      acc1[4] = fmaf(b1.x, wv_, acc1[4]); acc1[5] = fmaf(b1.y, wv_, acc1[5]);
      acc1[6] = fmaf(b1.z, wv_, acc1[6]); acc1[7] = fmaf(b1.w, wv_, acc1[7]);
    }
    float lawc = law[c];
    float lg0[8], lg1[8];
#pragma unroll
    for (int u = 0; u < 8; u++) {
      float kv0 = kk[((size_t)(b << 12) + nb[0][u]) * 64 + c];
      float kv1 = kk[((size_t)(b << 12) + nb[1][u]) * 64 + c];
      lg0[u] = wave_sum((qs0 - kv0 + acc0[u]) * lawc) + lab;
      lg1[u] = wave_sum((qs1 - kv1 + acc1[u]) * lawc) + lab;
    }
    float mx0 = lg0[0], mx1 = lg1[0];
#pragma unroll
    for (int u = 1; u < 8; u++) { mx0 = fmaxf(mx0, lg0[u]); mx1 = fmaxf(mx1, lg1[u]); }
    float s0 = 0.0f, s1 = 0.0f;
#pragma unroll
    for (int u = 0; u < 8; u++) {
      lg0[u] = expf(lg0[u] - mx0); s0 += lg0[u];
      lg1[u] = expf(lg1[u] - mx1); s1 += lg1[u];
    }
    float i0 = 1.0f / s0, i1 = 1.0f / s1;
    float out0 = 0.0f, out1 = 0.0f;
#pragma unroll
    for (int u = 0; u < 8; u++) {
      float vg0 = vv[((size_t)(b << 12) + nb[0][u]) * 64 + c];
      float vg1 = vv[((size_t)(b << 12) + nb[1][u]) * 64 + c];
      out0 = fmaf(lg0[u] * i0, vg0 + acc0[u], out0);
      out1 = fmaf(lg1[u] * i1, vg1 + acc1[u], out1);
    }
    outb[w][0][c] = out0; outb[w][1][c] = out1;
    float at0 = lob_[c], at1 = at0;
#pragma unroll 4
    for (int d = 0; d < DD; d += 4) {
      float4 o0 = *(const float4*)&outb[w][0][d];
      float4 o1 = *(const float4*)&outb[w][1][d];
      float wa = ow[(d + 0) * 64 + c], wb = ow[(d + 1) * 64 + c];
      float wc = ow[(d + 2) * 64 + c], wd = ow[(d + 3) * 64 + c];
      at0 = fmaf(o0.x, wa, at0); at0 = fmaf(o0.y, wb, at0);
      at0 = fmaf(o0.z, wc, at0); at0 = fmaf(o0.w, wd, at0);
      at1 = fmaf(o1.x, wa, at1); at1 = fmaf(o1.y, wb, at1);
      at1 = fmaf(o1.z, wc, at1); at1 = fmaf(o1.w, wd, at1);
    }
    float g1c = ll1g[c], bt1c = ll1b[c];
    {
      float res = at0 + hs0;
      float mean = wave_sum(res) * (1.0f / 64.0f);
      float dv = res - mean;
      float var = wave_sum(dv * dv) * (1.0f / 64.0f);
      float ivr = 1.0f / sqrtf(var + LNEPS);
      t[(size_t)p0 * 64 + c] = fmaf(g1c, dv * ivr, bt1c);
    }
    {
      float res = at1 + hs1;
      float mean = wave_sum(res) * (1.0f / 64.0f);
      float dv = res - mean;
      float var = wave_sum(dv * dv) * (1.0f / 64.0f);
      float ivr = 1.0f / sqrtf(var + LNEPS);
      t[(size_t)(p0 + 1) * 64 + c] = fmaf(g1c, dv * ivr, bt1c);
    }
  }
}

// ---------------------------------------------------------------- ffn (4 points per wave) -> h = ln2(t + ffn(t))
// yb/hb are wave-private -> in-loop barriers removed
__global__ __launch_bounds__(256) void ffn_kernel(
    const float* __restrict__ t, const float* __restrict__ fw1, const float* __restrict__ fb1,
    const float* __restrict__ fw2, const float* __restrict__ fb2,
    const float* __restrict__ l2g, const float* __restrict__ l2b, float* __restrict__ h) {
  __shared__ float lf1[DD * 128];
  __shared__ float lf2[128 * DD];
  __shared__ float lb1[128], lb2[DD], lg2[DD], lbt2[DD];
  __shared__ __attribute__((aligned(16))) float yb[4][DD][4];
  __shared__ __attribute__((aligned(16))) float hb[4][128][4];
  int tid = threadIdx.x;
  for (int i = tid; i < DD * 128; i += 256) { lf1[i] = fw1[i]; lf2[i] = fw2[i]; }
  if (tid < 128) lb1[tid] = fb1[tid];
  if (tid < DD) { lb2[tid] = fb2[tid]; lg2[tid] = l2g[tid]; lbt2[tid] = l2b[tid]; }
  __syncthreads();
  int w = tid >> 6, c = tid & 63;
  constexpr int ITERS = (BB * NN) / (FFN_GRID * 16);
  for (int it = 0; it < ITERS; ++it) {
    int wid = it * (FFN_GRID * 4) + blockIdx.x * 4 + w;
    int p0 = wid * 4;
    float y[4];
#pragma unroll
    for (int i = 0; i < 4; i++) { y[i] = t[(size_t)(p0 + i) * 64 + c]; yb[w][c][i] = y[i]; }
    float hA[4], hB[4];
#pragma unroll
    for (int i = 0; i < 4; i++) { hA[i] = lb1[c]; hB[i] = lb1[64 + c]; }
#pragma unroll 4
    for (int d = 0; d < DD; d++) {
      float w0 = lf1[d * 128 + c], w1 = lf1[d * 128 + 64 + c];
      float4 yv = *(const float4*)&yb[w][d][0];
      hA[0] = fmaf(yv.x, w0, hA[0]); hA[1] = fmaf(yv.y, w0, hA[1]);
      hA[2] = fmaf(yv.z, w0, hA[2]); hA[3] = fmaf(yv.w, w0, hA[3]);
      hB[0] = fmaf(yv.x, w1, hB[0]); hB[1] = fmaf(yv.y, w1, hB[1]);
      hB[2] = fmaf(yv.z, w1, hB[2]); hB[3] = fmaf(yv.w, w1, hB[3]);
    }
#pragma unroll
    for (int i = 0; i < 4; i++) {
      hA[i] = gelu_exact(hA[i]); hB[i] = gelu_exact(hB[i]);
      hb[w][c][i] = hA[i]; hb[w][64 + c][i] = hB[i];
    }
    float o[4];
#pragma unroll
    for (int i = 0; i < 4; i++) o[i] = lb2[c];
#pragma unroll 4
    for (int j = 0; j < 128; j++) {
      float wv_ = lf2[j * 64 + c];
      float4 hv = *(const float4*)&hb[w][j][0];
      o[0] = fmaf(hv.x, wv_, o[0]); o[1] = fmaf(hv.y, wv_, o[1]);
      o[2] = fmaf(hv.z, wv_, o[2]); o[3] = fmaf(hv.w, wv_, o[3]);
    }
#pragma unroll
    for (int i = 0; i < 4; i++) {
      float r = y[i] + o[i];
      float mean = wave_sum(r) * (1.0f / 64.0f);
      float dv = r - mean;
      float var = wave_sum(dv * dv) * (1.0f / 64.0f);
      float ivr = 1.0f / sqrtf(var + LNEPS);
      h[(size_t)(p0 + i) * 64 + c] = fmaf(lg2[c], dv * ivr, lbt2[c]);
    }
  }
}

// ---------------------------------------------------------------- classifier proj + blockwise max-pool
// hb wave-private -> in-loop barriers removed; wmax reduction keeps its barrier
__global__ __launch_bounds__(256) void cls_kernel(
    const float* __restrict__ h, const float* __restrict__ cw, const float* __restrict__ cb,
    const float* __restrict__ cg, const float* __restrict__ cbeta, float* __restrict__ g) {
  __shared__ float lcw[DD * 128];
  __shared__ float lcb[128], lcg[128], lcbt[128];
  __shared__ __attribute__((aligned(16))) float hb[4][DD][4];
  __shared__ float wmax[4][128];
  int tid = threadIdx.x;
  for (int i = tid; i < DD * 128; i += 256) lcw[i] = cw[i];
  if (tid < 128) { lcb[tid] = cb[tid]; lcg[tid] = cg[tid]; lcbt[tid] = cbeta[tid]; }
  __syncthreads();
  int w = tid >> 6, c = tid & 63;
  int b = blockIdx.x >> 7;            // 128 blocks per batch
  int blk = blockIdx.x & 127;
  int base = b * NN + blk * 32;
  float m0 = 0.0f, m1 = 0.0f;
  for (int it = 0; it < 2; ++it) {
    int p0 = base + (w * 2 + it) * 4;
#pragma unroll
    for (int i = 0; i < 4; i++) hb[w][c][i] = h[(size_t)(p0 + i) * 64 + c];
    float a0[4], a1[4];
#pragma unroll
    for (int i = 0; i < 4; i++) { a0[i] = lcb[c]; a1[i] = lcb[64 + c]; }
#pragma unroll 4
    for (int d = 0; d < DD; d++) {
      float w0 = lcw[d * 128 + c], w1 = lcw[d * 128 + 64 + c];
      float4 hv = *(const float4*)&hb[w][d][0];
      a0[0] = fmaf(hv.x, w0, a0[0]); a0[1] = fmaf(hv.y, w0, a0[1]);
      a0[2] = fmaf(hv.z, w0, a0[2]); a0[3] = fmaf(hv.w, w0, a0[3]);
      a1[0] = fmaf(hv.x, w1, a1[0]); a1[1] = fmaf(hv.y, w1, a1[1]);
      a1[2] = fmaf(hv.z, w1, a1[2]); a1[3] = fmaf(hv.w, w1, a1[3]);
    }
#pragma unroll
    for (int i = 0; i < 4; i++) {
      m0 = fmaxf(m0, fmaxf(0.0f, fmaf(lcg[c] * a0[i], BNRS, lcbt[c])));
      m1 = fmaxf(m1, fmaxf(0.0f, fmaf(lcg[64 + c] * a1[i], BNRS, lcbt[64 + c])));
    }
  }
  wmax[w][c] = m0; wmax[w][64 + c] = m1;
  __syncthreads();
  if (tid < 128) {
    float mm = fmaxf(fmaxf(wmax[0][tid], wmax[1][tid]), fmaxf(wmax[2][tid], wmax[3][tid]));
    atomicMax((int*)&g[b * 128 + tid], __float_as_int(mm));  // values >= 0
  }
}

// ---------------------------------------------------------------- final head (per batch)
__global__ __launch_bounds__(128) void head_kernel(
    const float* __restrict__ g,
    const float* __restrict__ f1w, const float* __restrict__ f1b,
    const float* __restrict__ b1g, const float* __restrict__ b1b,
    const float* __restrict__ f2w, const float* __restrict__ f2b,
    const float* __restrict__ b2g, const float* __restrict__ b2b,
    const float* __restrict__ f3w, const float* __restrict__ f3b,
    float* __restrict__ out) {
  __shared__ float gb[128], g1[128], g2[64];
  int b = blockIdx.x, t = threadIdx.x;
  gb[t] = g[b * 128 + t];
  __syncthreads();
  float a = f1b[t];
#pragma unroll 4
  for (int d = 0; d < 128; d++) a = fmaf(gb[d], f1w[d * 128 + t], a);
  g1[t] = fmaxf(0.0f, fmaf(b1g[t] * a, BNRS, b1b[t]));
  __syncthreads();
  if (t < 64) {
    float a2 = f2b[t];
#pragma unroll 4
    for (int j = 0; j < 128; j++) a2 = fmaf(g1[j], f2w[j * 64 + t], a2);
    g2[t] = fmaxf(0.0f, fmaf(b2g[t] * a2, BNRS, b2b[t]));
  }
  __syncthreads();
  if (t < NCLS) {
    float a3 = f3b[t];
#pragma unroll
    for (int d = 0; d < 64; d++) a3 = fmaf(g2[d], f3w[d * NCLS + t], a3);
    out[b * NCLS + t] = a3;
  }
}

extern "C" void kernel_launch(void* const* d_in, const int* in_sizes, int n_in,
                              void* d_out, int out_size, void* d_ws, size_t ws_size,
                              hipStream_t stream) {
  const float* x    = (const float*)d_in[0];
  const float* ew1  = (const float*)d_in[1];
  const float* eb1  = (const float*)d_in[2];
  const float* ew2  = (const float*)d_in[3];
  const float* eb2  = (const float*)d_in[4];
  const float* wq   = (const float*)d_in[5];
  const float* bq   = (const float*)d_in[6];
  const float* wk   = (const float*)d_in[7];
  const float* bk   = (const float*)d_in[8];
  const float* wv   = (const float*)d_in[9];
  const float* bv   = (const float*)d_in[10];
  const float* pw1  = (const float*)d_in[11];
  const float* pb1  = (const float*)d_in[12];
  const float* pw2  = (const float*)d_in[13];
  const float* pb2  = (const float*)d_in[14];
  const float* aw   = (const float*)d_in[15];
  const float* ab   = (const float*)d_in[16];
  const float* ow   = (const float*)d_in[17];
  const float* ob   = (const float*)d_in[18];
  const float* l1g  = (const float*)d_in[19];
  const float* l1b  = (const float*)d_in[20];
  const float* l2g  = (const float*)d_in[21];
  const float* l2b  = (const float*)d_in[22];
  const float* fw1  = (const float*)d_in[23];
  const float* fb1  = (const float*)d_in[24];
  const float* fw2  = (const float*)d_in[25];
  const float* fb2  = (const float*)d_in[26];
  const float* cw   = (const float*)d_in[27];
  const float* cb   = (const float*)d_in[28];
  const float* cg   = (const float*)d_in[29];
  const float* cbeta= (const float*)d_in[30];
  const float* f1w  = (const float*)d_in[31];
  const float* f1b  = (const float*)d_in[32];
  const float* b1g  = (const float*)d_in[33];
  const float* b1b  = (const float*)d_in[34];
  const float* f2w  = (const float*)d_in[35];
  const float* f2b  = (const float*)d_in[36];
  const float* b2g  = (const float*)d_in[37];
  const float* b2b  = (const float*)d_in[38];
  const float* f3w  = (const float*)d_in[39];
  const float* f3b  = (const float*)d_in[40];

  const size_t P = (size_t)BB * NN;       // 32768 points
  float* ws = (float*)d_ws;
  float* h = ws;                          // P*64
  float* q = h + P * 64;
  float* k = q + P * 64;
  float* v = k + P * 64;
  int* idx = (int*)(v + P * 64);          // P*8 ints
  float* g = (float*)(idx + P * 8);       // B*128
  float4* ppg = (float4*)(g + BB * 128);  // P float4 (aligned: offset is 16B-multiple)
  float* t = q;                           // alias: safe (same-point read-then-write)

  zero_kernel<<<1, BB * 128, 0, stream>>>(g);
  embed_kernel<<<(int)(P / 4), 256, 0, stream>>>(x, ew1, eb1, ew2, eb2, h);
  knn_prep_kernel<<<(int)(P / 256), 256, 0, stream>>>(x, ppg);
  knn_kernel<<<BB * (NN / QPB), 1024, 0, stream>>>(ppg, idx);
  for (int l = 0; l < 2; l++) {
    qkv_kernel<<<QKV_GRID, 256, 0, stream>>>(h, wq + l * DD * DD, bq + l * DD,
                                             wk + l * DD * DD, bk + l * DD,
                                             wv + l * DD * DD, bv + l * DD, q, k, v);
    attn_kernel<<<ATTN_GRID, 256, 0, stream>>>(x, h, q, k, v, idx,
                                               pw1 + l * 3 * DD, pb1 + l * DD,
                                               pw2 + l * DD * DD, pb2 + l * DD,
                                               aw + l * DD, ab + l,
                                               ow + l * DD * DD, ob + l * DD,
                                               l1g + l * DD, l1b + l * DD, t);
    ffn_kernel<<<FFN_GRID, 256, 0, stream>>>(t, fw1 + l * DD * 2 * DD, fb1 + l * 2 * DD,
                                             fw2 + l * 2 * DD * DD, fb2 + l * DD,
                                             l2g + l * DD, l2b + l * DD, h);
  }
  cls_kernel<<<BB * 128, 256, 0, stream>>>(h, cw, cb, cg, cbeta, g);
  head_kernel<<<BB, 128, 0, stream>>>(g, f1w, f1b, b1g, b1b, f2w, f2b, b2g, b2b, f3w, f3b,
                                      (float*)d_out);
}

// Round 9
// 415.475 us; speedup vs baseline: 1.2802x; 1.0254x over previous
//
#include <hip/hip_runtime.h>
#include <cmath>

#define BB 8
#define NN 4096
#define DD 64
#define KK 8
#define NCLS 2

constexpr float LNEPS = 1e-5f;
constexpr float BNRS = 0.9999950000374994f;      // 1/sqrt(1+1e-5)
constexpr float INVSQRT2 = 0.70710678118654752440f;

constexpr int QKV_GRID = 512;
constexpr int ATTN_GRID = 1024;
constexpr int FFN_GRID = 512;

// knn decomposition: 64 queries/block x 16 candidate-splits (one per wave)
#define QPB 64
#define SPLITS 16
#define SUBSET 64     // pass-1 subset per split (16*64 = 1024-point bound set)

__device__ __forceinline__ float wave_sum(float v) {
#pragma unroll
  for (int m = 32; m > 0; m >>= 1) v += __shfl_xor(v, m, 64);
  return v;
}

__device__ __forceinline__ float gelu_exact(float x) {
  return 0.5f * x * (1.0f + erff(x * INVSQRT2));
}

// identical in both knn passes -> bit-identical distances
__device__ __forceinline__ float dist2(float4 q, float4 p) {
  float dot = fmaf(q.x, p.x, fmaf(q.y, p.y, q.z * p.z));
  return fmaf(-2.0f, dot, q.w + p.w);
}

// ---------------------------------------------------------------- zero g
__global__ void zero_kernel(float* g) { g[threadIdx.x] = 0.0f; }

// ---------------------------------------------------------------- embed: h = relu(x@ew1+eb1)@ew2+eb2
// XCD-pinned: batch = blockIdx & 7 (all blocks of a batch on one XCD's L2)
__global__ __launch_bounds__(256) void embed_kernel(
    const float* __restrict__ x, const float* __restrict__ ew1, const float* __restrict__ eb1,
    const float* __restrict__ ew2, const float* __restrict__ eb2, float* __restrict__ h) {
  __shared__ float h1[4][DD];
  int w = threadIdx.x >> 6, c = threadIdx.x & 63;
  int pt = ((blockIdx.x & 7) << 12) + (blockIdx.x >> 3) * 4 + w;
  const float* xp = x + (size_t)pt * 3;
  float x0 = xp[0], x1 = xp[1], x2 = xp[2];
  float a = fmaf(x0, ew1[c], fmaf(x1, ew1[64 + c], fmaf(x2, ew1[128 + c], eb1[c])));
  h1[w][c] = fmaxf(a, 0.0f);
  float s = eb2[c];
#pragma unroll 8
  for (int d = 0; d < DD; d++) s = fmaf(h1[w][d], ew2[d * 64 + c], s);
  h[(size_t)pt * 64 + c] = s;
}

// ---------------------------------------------------------------- knn prep: ppg[b*N+j] = (x,y,z,|p|^2)
__global__ __launch_bounds__(256) void knn_prep_kernel(const float* __restrict__ x,
                                                       float4* __restrict__ ppg) {
  int i = ((blockIdx.x & 7) << 12) + (blockIdx.x >> 3) * 256 + threadIdx.x;
  float a0 = x[3 * i + 0], a1 = x[3 * i + 1], a2 = x[3 * i + 2];
  ppg[i] = make_float4(a0, a1, a2, a0 * a0 + a1 * a1 + a2 * a2);
}

// ---------------------------------------------------------------- knn: exact top-8 (stable ties), 2-pass
__global__ __launch_bounds__(1024) void knn_kernel(const float4* __restrict__ ppg,
                                                   int* __restrict__ idx) {
  __shared__ union {
    float v[SPLITS * 8][QPB];       // pass-1 value lists
    double k[SPLITS * 8][QPB];      // pass-2 key lists (64 KB)
  } mb;
  __shared__ float thrq[QPB];
  int b = blockIdx.x & 7;           // XCD-pinned batch
  int qbase = (blockIdx.x >> 3) * QPB;
  const float4* pb = ppg + (size_t)b * NN;
  int ql = threadIdx.x & 63;
  int sp = __builtin_amdgcn_readfirstlane(threadIdx.x >> 6);  // wave id = split id (SGPR)
  float4 qp = pb[qbase + ql];
  const float4* cp = pb + sp * (NN / SPLITS);                 // scalar base

  // ---- pass 1: branchless top-8 distances over SUBSET candidates
  float bd[8];
#pragma unroll
  for (int u = 0; u < 8; u++) bd[u] = INFINITY;
#pragma unroll 4
  for (int jj = 0; jj < SUBSET; ++jj) {
    float d2 = dist2(qp, cp[jj]);
#pragma unroll
    for (int u = 7; u > 0; --u) bd[u] = fminf(bd[u], fmaxf(bd[u - 1], d2));
    bd[0] = fminf(bd[0], d2);
  }
#pragma unroll
  for (int u = 0; u < 8; u++) mb.v[sp * 8 + u][ql] = bd[u];
  __syncthreads();

  // ---- U merge stage 1
  if (sp < 8) {
    float cd[8];
#pragma unroll
    for (int u = 0; u < 8; u++) cd[u] = INFINITY;
    int base = sp * 16;
#pragma unroll
    for (int e = 0; e < 16; e++) {
      float vv = mb.v[base + e][ql];
#pragma unroll
      for (int u = 7; u > 0; --u) cd[u] = fminf(cd[u], fmaxf(cd[u - 1], vv));
      cd[0] = fminf(cd[0], vv);
    }
#pragma unroll
    for (int u = 0; u < 8; u++) mb.v[base + u][ql] = cd[u];
  }
  __syncthreads();

  // ---- U merge stage 2
  if (sp == 0) {
    float cd[8];
#pragma unroll
    for (int u = 0; u < 8; u++) cd[u] = INFINITY;
    for (int m = 0; m < 8; m++) {
      for (int e = 0; e < 8; e++) {
        float vv = mb.v[m * 16 + e][ql];
        if (__all(vv >= cd[7])) break;
#pragma unroll
        for (int u = 7; u > 0; --u) cd[u] = fminf(cd[u], fmaxf(cd[u - 1], vv));
        cd[0] = fminf(cd[0], vv);
      }
    }
    thrq[ql] = cd[7];
  }
  __syncthreads();
  float U = thrq[ql];

  // ---- pass 2: exact per-split top-8 of hits (d2<=U), f64 keys in registers
  double kd[8];
#pragma unroll
  for (int u = 0; u < 8; u++) kd[u] = INFINITY;
#pragma unroll 4
  for (int jj = 0; jj < NN / SPLITS; ++jj) {
    float d2 = dist2(qp, cp[jj]);
    if (d2 <= U) {
      double key = __hiloint2double(__float_as_int(d2), sp * (NN / SPLITS) + jj);
      if (key < kd[7]) {
#pragma unroll
        for (int u = 7; u > 0; --u) kd[u] = fmin(kd[u], fmax(kd[u - 1], key));
        kd[0] = fmin(kd[0], key);
      }
    }
  }
#pragma unroll
  for (int u = 0; u < 8; u++) mb.k[sp * 8 + u][ql] = kd[u];
  __syncthreads();

  // ---- key merge stage 1
  if (sp < 8) {
    double cd[8];
#pragma unroll
    for (int u = 0; u < 8; u++) cd[u] = INFINITY;
    int base = sp * 16;
#pragma unroll
    for (int e = 0; e < 16; e++) {
      double key = mb.k[base + e][ql];
#pragma unroll
      for (int u = 7; u > 0; --u) cd[u] = fmin(cd[u], fmax(cd[u - 1], key));
      cd[0] = fmin(cd[0], key);
    }
#pragma unroll
    for (int u = 0; u < 8; u++) mb.k[base + u][ql] = cd[u];
  }
  __syncthreads();

  // ---- key merge stage 2 + write
  if (sp == 0) {
    double cd[8];
#pragma unroll
    for (int u = 0; u < 8; u++) cd[u] = INFINITY;
    for (int m = 0; m < 8; m++) {
      for (int e = 0; e < 8; e++) {
        double key = mb.k[m * 16 + e][ql];
        if (__all(key >= cd[7])) break;
#pragma unroll
        for (int u = 7; u > 0; --u) cd[u] = fmin(cd[u], fmax(cd[u - 1], key));
        cd[0] = fmin(cd[0], key);
      }
    }
    int* op = idx + ((size_t)b * NN + qbase + ql) * 8;
#pragma unroll
    for (int u = 0; u < 8; u++) op[u] = __double2loint(cd[u]);
  }
}

// ---------------------------------------------------------------- qkv projection (4 points per wave, XCD-pinned)
__global__ __launch_bounds__(256) void qkv_kernel(
    const float* __restrict__ h, const float* __restrict__ wq, const float* __restrict__ bq,
    const float* __restrict__ wk, const float* __restrict__ bk,
    const float* __restrict__ wv, const float* __restrict__ bv,
    float* __restrict__ q, float* __restrict__ k, float* __restrict__ v) {
  __shared__ float lwq[DD * DD], lwk[DD * DD], lwv[DD * DD];
  __shared__ float lbq[DD], lbk[DD], lbv[DD];
  __shared__ __attribute__((aligned(16))) float hb[4][DD][4];
  int tid = threadIdx.x;
  for (int i = tid; i < DD * DD; i += 256) { lwq[i] = wq[i]; lwk[i] = wk[i]; lwv[i] = wv[i]; }
  if (tid < DD) { lbq[tid] = bq[tid]; lbk[tid] = bk[tid]; lbv[tid] = bv[tid]; }
  __syncthreads();
  int w = tid >> 6, c = tid & 63;
  int batch = blockIdx.x & 7, pos = blockIdx.x >> 3;   // 64 block-positions per batch
  constexpr int ITERS = NN / ((QKV_GRID / 8) * 16);    // 4
  for (int it = 0; it < ITERS; ++it) {
    int p0 = (batch << 12) + ((it * 64 + pos) * 4 + w) * 4;
#pragma unroll
    for (int i = 0; i < 4; i++) hb[w][c][i] = h[(size_t)(p0 + i) * 64 + c];
    float aq[4], ak[4], av[4];
#pragma unroll
    for (int i = 0; i < 4; i++) { aq[i] = lbq[c]; ak[i] = lbk[c]; av[i] = lbv[c]; }
#pragma unroll 4
    for (int d = 0; d < DD; d++) {
      float wq_ = lwq[d * 64 + c], wk_ = lwk[d * 64 + c], wv_ = lwv[d * 64 + c];
      float4 hh = *(const float4*)&hb[w][d][0];
      aq[0] = fmaf(hh.x, wq_, aq[0]); aq[1] = fmaf(hh.y, wq_, aq[1]);
      aq[2] = fmaf(hh.z, wq_, aq[2]); aq[3] = fmaf(hh.w, wq_, aq[3]);
      ak[0] = fmaf(hh.x, wk_, ak[0]); ak[1] = fmaf(hh.y, wk_, ak[1]);
      ak[2] = fmaf(hh.z, wk_, ak[2]); ak[3] = fmaf(hh.w, wk_, ak[3]);
      av[0] = fmaf(hh.x, wv_, av[0]); av[1] = fmaf(hh.y, wv_, av[1]);
      av[2] = fmaf(hh.z, wv_, av[2]); av[3] = fmaf(hh.w, wv_, av[3]);
    }
#pragma unroll
    for (int i = 0; i < 4; i++) {
      q[(size_t)(p0 + i) * 64 + c] = aq[i];
      k[(size_t)(p0 + i) * 64 + c] = ak[i];
      v[(size_t)(p0 + i) * 64 + c] = av[i];
    }
  }
}

// ---------------------------------------------------------------- attention (2 points per wave, XCD-pinned) -> t = ln1(attn+x)
// k/v gathers prefetched BEFORE the pe compute (latency hidden under ~2K cycles of FMA).
// NOTE: t may alias q (same-point read-then-write only) -> no __restrict__ on q/t.
__global__ __launch_bounds__(256) void attn_kernel(
    const float* __restrict__ x, const float* __restrict__ h,
    const float* q, const float* __restrict__ kk, const float* __restrict__ vv,
    const int* __restrict__ idx,
    const float* __restrict__ pw1, const float* __restrict__ pb1,
    const float* __restrict__ pw2, const float* __restrict__ pb2,
    const float* __restrict__ aw, const float* __restrict__ ab,
    const float* __restrict__ ow, const float* __restrict__ ob,
    const float* __restrict__ l1g, const float* __restrict__ l1b,
    float* t) {
  __shared__ float lpw2[DD * DD];
  __shared__ float lpw1[3 * DD], lpb1[DD], lpb2[DD], law[DD], lob_[DD], ll1g[DD], ll1b[DD];
  __shared__ __attribute__((aligned(16))) float h1b[4][2][DD][8];   // [wave][pt][d][u] 16KB
  __shared__ __attribute__((aligned(16))) float outb[4][2][DD];     // 2KB
  int tid = threadIdx.x;
  for (int i = tid; i < DD * DD; i += 256) lpw2[i] = pw2[i];
  if (tid < 3 * DD) lpw1[tid] = pw1[tid];
  if (tid < DD) {
    lpb1[tid] = pb1[tid]; lpb2[tid] = pb2[tid]; law[tid] = aw[tid];
    lob_[tid] = ob[tid]; ll1g[tid] = l1g[tid]; ll1b[tid] = l1b[tid];
  }
  float lab = ab[0];
  __syncthreads();
  int w = tid >> 6, c = tid & 63;
  int b = blockIdx.x & 7, pos = blockIdx.x >> 3;   // 128 block-positions per batch
  const float* xb = x + (size_t)b * NN * 3;
  constexpr int ITERS = NN / ((ATTN_GRID / 8) * 8);   // 4
  for (int it = 0; it < ITERS; ++it) {
    int n0 = ((it * 128 + pos) * 8) + w * 2;
    int p0 = (b << 12) + n0;
    float hs0 = h[(size_t)p0 * 64 + c], hs1 = h[(size_t)(p0 + 1) * 64 + c];
    float qs0 = q[(size_t)p0 * 64 + c], qs1 = q[(size_t)(p0 + 1) * 64 + c];
    int nb[2][8];
#pragma unroll
    for (int u = 0; u < 8; u++) {
      nb[0][u] = idx[(size_t)p0 * 8 + u];
      nb[1][u] = idx[(size_t)(p0 + 1) * 8 + u];
    }
    // ---- prefetch all k/v gather rows NOW; latency hides under pe1+pe2 compute
    float kv0[8], kv1[8], vg0[8], vg1[8];
#pragma unroll
    for (int u = 0; u < 8; u++) {
      kv0[u] = kk[((size_t)(b << 12) + nb[0][u]) * 64 + c];
      kv1[u] = kk[((size_t)(b << 12) + nb[1][u]) * 64 + c];
      vg0[u] = vv[((size_t)(b << 12) + nb[0][u]) * 64 + c];
      vg1[u] = vv[((size_t)(b << 12) + nb[1][u]) * 64 + c];
    }
    float w1c0 = lpw1[c], w1c1 = lpw1[64 + c], w1c2 = lpw1[128 + c], b1c = lpb1[c];
#pragma unroll
    for (int pt = 0; pt < 2; ++pt) {
      int n = n0 + pt;
      float px0 = xb[n * 3 + 0], px1 = xb[n * 3 + 1], px2 = xb[n * 3 + 2];
      float h1v[8];
#pragma unroll
      for (int u = 0; u < 8; u++) {
        int m = nb[pt][u];
        float d0 = px0 - xb[m * 3 + 0], d1 = px1 - xb[m * 3 + 1], d2 = px2 - xb[m * 3 + 2];
        h1v[u] = fmaxf(fmaf(d0, w1c0, fmaf(d1, w1c1, fmaf(d2, w1c2, b1c))), 0.0f);
      }
      *(float4*)&h1b[w][pt][c][0] = make_float4(h1v[0], h1v[1], h1v[2], h1v[3]);
      *(float4*)&h1b[w][pt][c][4] = make_float4(h1v[4], h1v[5], h1v[6], h1v[7]);
    }
    float acc0[8], acc1[8];
    float pb2c = lpb2[c];
#pragma unroll
    for (int u = 0; u < 8; u++) { acc0[u] = pb2c; acc1[u] = pb2c; }
#pragma unroll 2
    for (int d = 0; d < DD; d++) {
      float wv_ = lpw2[d * 64 + c];
      float4 a0 = *(const float4*)&h1b[w][0][d][0];
      float4 b0 = *(const float4*)&h1b[w][0][d][4];
      float4 a1 = *(const float4*)&h1b[w][1][d][0];
      float4 b1 = *(const float4*)&h1b[w][1][d][4];
      acc0[0] = fmaf(a0.x, wv_, acc0[0]); acc0[1] = fmaf(a0.y, wv_, acc0[1]);
      acc0[2] = fmaf(a0.z, wv_, acc0[2]); acc0[3] = fmaf(a0.w, wv_, acc0[3]);
      acc0[4] = fmaf(b0.x, wv_, acc0[4]); acc0[5] = fmaf(b0.y, wv_, acc0[5]);
      acc0[6] = fmaf(b0.z, wv_, acc0[6]); acc0[7] = fmaf(b0.w, wv_, acc0[7]);
      acc1[0] = fmaf(a1.x, wv_, acc1[0]); acc1[1] = fmaf(a1.y, wv_, acc1[1]);
      acc1[2] = fmaf(a1.z, wv_, acc1[2]); acc1[3] = fmaf(a1.w, wv_, acc1[3]);
      acc1[4] = fmaf(b1.x, wv_, acc1[4]); acc1[5] = fmaf(b1.y, wv_, acc1[5]);
      acc1[6] = fmaf(b1.z, wv_, acc1[6]); acc1[7] = fmaf(b1.w, wv_, acc1[7]);
    }
    float lawc = law[c];
    float lg0[8], lg1[8];
#pragma unroll
    for (int u = 0; u < 8; u++) {
      lg0[u] = wave_sum((qs0 - kv0[u] + acc0[u]) * lawc) + lab;
      lg1[u] = wave_sum((qs1 - kv1[u] + acc1[u]) * lawc) + lab;
    }
    float mx0 = lg0[0], mx1 = lg1[0];
#pragma unroll
    for (int u = 1; u < 8; u++) { mx0 = fmaxf(mx0, lg0[u]); mx1 = fmaxf(mx1, lg1[u]); }
    float s0 = 0.0f, s1 = 0.0f;
#pragma unroll
    for (int u = 0; u < 8; u++) {
      lg0[u] = expf(lg0[u] - mx0); s0 += lg0[u];
      lg1[u] = expf(lg1[u] - mx1); s1 += lg1[u];
    }
    float i0 = 1.0f / s0, i1 = 1.0f / s1;
    float out0 = 0.0f, out1 = 0.0f;
#pragma unroll
    for (int u = 0; u < 8; u++) {
      out0 = fmaf(lg0[u] * i0, vg0[u] + acc0[u], out0);
      out1 = fmaf(lg1[u] * i1, vg1[u] + acc1[u], out1);
    }
    outb[w][0][c] = out0; outb[w][1][c] = out1;
    float at0 = lob_[c], at1 = at0;
#pragma unroll 4
    for (int d = 0; d < DD; d += 4) {
      float4 o0 = *(const float4*)&outb[w][0][d];
      float4 o1 = *(const float4*)&outb[w][1][d];
      float wa = ow[(d + 0) * 64 + c], wb = ow[(d + 1) * 64 + c];
      float wc = ow[(d + 2) * 64 + c], wd = ow[(d + 3) * 64 + c];
      at0 = fmaf(o0.x, wa, at0); at0 = fmaf(o0.y, wb, at0);
      at0 = fmaf(o0.z, wc, at0); at0 = fmaf(o0.w, wd, at0);
      at1 = fmaf(o1.x, wa, at1); at1 = fmaf(o1.y, wb, at1);
      at1 = fmaf(o1.z, wc, at1); at1 = fmaf(o1.w, wd, at1);
    }
    float g1c = ll1g[c], bt1c = ll1b[c];
    {
      float res = at0 + hs0;
      float mean = wave_sum(res) * (1.0f / 64.0f);
      float dv = res - mean;
      float var = wave_sum(dv * dv) * (1.0f / 64.0f);
      float ivr = 1.0f / sqrtf(var + LNEPS);
      t[(size_t)p0 * 64 + c] = fmaf(g1c, dv * ivr, bt1c);
    }
    {
      float res = at1 + hs1;
      float mean = wave_sum(res) * (1.0f / 64.0f);
      float dv = res - mean;
      float var = wave_sum(dv * dv) * (1.0f / 64.0f);
      float ivr = 1.0f / sqrtf(var + LNEPS);
      t[(size_t)(p0 + 1) * 64 + c] = fmaf(g1c, dv * ivr, bt1c);
    }
  }
}

// ---------------------------------------------------------------- ffn (4 points per wave, XCD-pinned) -> h = ln2(t + ffn(t))
__global__ __launch_bounds__(256) void ffn_kernel(
    const float* __restrict__ t, const float* __restrict__ fw1, const float* __restrict__ fb1,
    const float* __restrict__ fw2, const float* __restrict__ fb2,
    const float* __restrict__ l2g, const float* __restrict__ l2b, float* __restrict__ h) {
  __shared__ float lf1[DD * 128];
  __shared__ float lf2[128 * DD];
  __shared__ float lb1[128], lb2[DD], lg2[DD], lbt2[DD];
  __shared__ __attribute__((aligned(16))) float yb[4][DD][4];
  __shared__ __attribute__((aligned(16))) float hb[4][128][4];
  int tid = threadIdx.x;
  for (int i = tid; i < DD * 128; i += 256) { lf1[i] = fw1[i]; lf2[i] = fw2[i]; }
  if (tid < 128) lb1[tid] = fb1[tid];
  if (tid < DD) { lb2[tid] = fb2[tid]; lg2[tid] = l2g[tid]; lbt2[tid] = l2b[tid]; }
  __syncthreads();
  int w = tid >> 6, c = tid & 63;
  int batch = blockIdx.x & 7, pos = blockIdx.x >> 3;
  constexpr int ITERS = NN / ((FFN_GRID / 8) * 16);   // 4
  for (int it = 0; it < ITERS; ++it) {
    int p0 = (batch << 12) + ((it * 64 + pos) * 4 + w) * 4;
    float y[4];
#pragma unroll
    for (int i = 0; i < 4; i++) { y[i] = t[(size_t)(p0 + i) * 64 + c]; yb[w][c][i] = y[i]; }
    float hA[4], hB[4];
#pragma unroll
    for (int i = 0; i < 4; i++) { hA[i] = lb1[c]; hB[i] = lb1[64 + c]; }
#pragma unroll 4
    for (int d = 0; d < DD; d++) {
      float w0 = lf1[d * 128 + c], w1 = lf1[d * 128 + 64 + c];
      float4 yv = *(const float4*)&yb[w][d][0];
      hA[0] = fmaf(yv.x, w0, hA[0]); hA[1] = fmaf(yv.y, w0, hA[1]);
      hA[2] = fmaf(yv.z, w0, hA[2]); hA[3] = fmaf(yv.w, w0, hA[3]);
      hB[0] = fmaf(yv.x, w1, hB[0]); hB[1] = fmaf(yv.y, w1, hB[1]);
      hB[2] = fmaf(yv.z, w1, hB[2]); hB[3] = fmaf(yv.w, w1, hB[3]);
    }
#pragma unroll
    for (int i = 0; i < 4; i++) {
      hA[i] = gelu_exact(hA[i]); hB[i] = gelu_exact(hB[i]);
      hb[w][c][i] = hA[i]; hb[w][64 + c][i] = hB[i];
    }
    float o[4];
#pragma unroll
    for (int i = 0; i < 4; i++) o[i] = lb2[c];
#pragma unroll 4
    for (int j = 0; j < 128; j++) {
      float wv_ = lf2[j * 64 + c];
      float4 hv = *(const float4*)&hb[w][j][0];
      o[0] = fmaf(hv.x, wv_, o[0]); o[1] = fmaf(hv.y, wv_, o[1]);
      o[2] = fmaf(hv.z, wv_, o[2]); o[3] = fmaf(hv.w, wv_, o[3]);
    }
#pragma unroll
    for (int i = 0; i < 4; i++) {
      float r = y[i] + o[i];
      float mean = wave_sum(r) * (1.0f / 64.0f);
      float dv = r - mean;
      float var = wave_sum(dv * dv) * (1.0f / 64.0f);
      float ivr = 1.0f / sqrtf(var + LNEPS);
      h[(size_t)(p0 + i) * 64 + c] = fmaf(lg2[c], dv * ivr, lbt2[c]);
    }
  }
}

// ---------------------------------------------------------------- classifier proj + blockwise max-pool (XCD-pinned)
__global__ __launch_bounds__(256) void cls_kernel(
    const float* __restrict__ h, const float* __restrict__ cw, const float* __restrict__ cb,
    const float* __restrict__ cg, const float* __restrict__ cbeta, float* __restrict__ g) {
  __shared__ float lcw[DD * 128];
  __shared__ float lcb[128], lcg[128], lcbt[128];
  __shared__ __attribute__((aligned(16))) float hb[4][DD][4];
  __shared__ float wmax[4][128];
  int tid = threadIdx.x;
  for (int i = tid; i < DD * 128; i += 256) lcw[i] = cw[i];
  if (tid < 128) { lcb[tid] = cb[tid]; lcg[tid] = cg[tid]; lcbt[tid] = cbeta[tid]; }
  __syncthreads();
  int w = tid >> 6, c = tid & 63;
  int b = blockIdx.x & 7;             // XCD-pinned batch
  int blk = blockIdx.x >> 3;          // 128 block-positions per batch
  int base = b * NN + blk * 32;
  float m0 = 0.0f, m1 = 0.0f;
  for (int it = 0; it < 2; ++it) {
    int p0 = base + (w * 2 + it) * 4;
#pragma unroll
    for (int i = 0; i < 4; i++) hb[w][c][i] = h[(size_t)(p0 + i) * 64 + c];
    float a0[4], a1[4];
#pragma unroll
    for (int i = 0; i < 4; i++) { a0[i] = lcb[c]; a1[i] = lcb[64 + c]; }
#pragma unroll 4
    for (int d = 0; d < DD; d++) {
      float w0 = lcw[d * 128 + c], w1 = lcw[d * 128 + 64 + c];
      float4 hv = *(const float4*)&hb[w][d][0];
      a0[0] = fmaf(hv.x, w0, a0[0]); a0[1] = fmaf(hv.y, w0, a0[1]);
      a0[2] = fmaf(hv.z, w0, a0[2]); a0[3] = fmaf(hv.w, w0, a0[3]);
      a1[0] = fmaf(hv.x, w1, a1[0]); a1[1] = fmaf(hv.y, w1, a1[1]);
      a1[2] = fmaf(hv.z, w1, a1[2]); a1[3] = fmaf(hv.w, w1, a1[3]);
    }
#pragma unroll
    for (int i = 0; i < 4; i++) {
      m0 = fmaxf(m0, fmaxf(0.0f, fmaf(lcg[c] * a0[i], BNRS, lcbt[c])));
      m1 = fmaxf(m1, fmaxf(0.0f, fmaf(lcg[64 + c] * a1[i], BNRS, lcbt[64 + c])));
    }
  }
  wmax[w][c] = m0; wmax[w][64 + c] = m1;
  __syncthreads();
  if (tid < 128) {
    float mm = fmaxf(fmaxf(wmax[0][tid], wmax[1][tid]), fmaxf(wmax[2][tid], wmax[3][tid]));
    atomicMax((int*)&g[b * 128 + tid], __float_as_int(mm));  // values >= 0
  }
}

// ---------------------------------------------------------------- final head (per batch)
__global__ __launch_bounds__(128) void head_kernel(
    const float* __restrict__ g,
    const float* __restrict__ f1w, const float* __restrict__ f1b,
    const float* __restrict__ b1g, const float* __restrict__ b1b,
    const float* __restrict__ f2w, const float* __restrict__ f2b,
    const float* __restrict__ b2g, const float* __restrict__ b2b,
    const float* __restrict__ f3w, const float* __restrict__ f3b,
    float* __restrict__ out) {
  __shared__ float gb[128], g1[128], g2[64];
  int b = blockIdx.x, t = threadIdx.x;
  gb[t] = g[b * 128 + t];
  __syncthreads();
  float a = f1b[t];
#pragma unroll 4
  for (int d = 0; d < 128; d++) a = fmaf(gb[d], f1w[d * 128 + t], a);
  g1[t] = fmaxf(0.0f, fmaf(b1g[t] * a, BNRS, b1b[t]));
  __syncthreads();
  if (t < 64) {
    float a2 = f2b[t];
#pragma unroll 4
    for (int j = 0; j < 128; j++) a2 = fmaf(g1[j], f2w[j * 64 + t], a2);
    g2[t] = fmaxf(0.0f, fmaf(b2g[t] * a2, BNRS, b2b[t]));
  }
  __syncthreads();
  if (t < NCLS) {
    float a3 = f3b[t];
#pragma unroll
    for (int d = 0; d < 64; d++) a3 = fmaf(g2[d], f3w[d * NCLS + t], a3);
    out[b * NCLS + t] = a3;
  }
}

extern "C" void kernel_launch(void* const* d_in, const int* in_sizes, int n_in,
                              void* d_out, int out_size, void* d_ws, size_t ws_size,
                              hipStream_t stream) {
  const float* x    = (const float*)d_in[0];
  const float* ew1  = (const float*)d_in[1];
  const float* eb1  = (const float*)d_in[2];
  const float* ew2  = (const float*)d_in[3];
  const float* eb2  = (const float*)d_in[4];
  const float* wq   = (const float*)d_in[5];
  const float* bq   = (const float*)d_in[6];
  const float* wk   = (const float*)d_in[7];
  const float* bk   = (const float*)d_in[8];
  const float* wv   = (const float*)d_in[9];
  const float* bv   = (const float*)d_in[10];
  const float* pw1  = (const float*)d_in[11];
  const float* pb1  = (const float*)d_in[12];
  const float* pw2  = (const float*)d_in[13];
  const float* pb2  = (const float*)d_in[14];
  const float* aw   = (const float*)d_in[15];
  const float* ab   = (const float*)d_in[16];
  const float* ow   = (const float*)d_in[17];
  const float* ob   = (const float*)d_in[18];
  const float* l1g  = (const float*)d_in[19];
  const float* l1b  = (const float*)d_in[20];
  const float* l2g  = (const float*)d_in[21];
  const float* l2b  = (const float*)d_in[22];
  const float* fw1  = (const float*)d_in[23];
  const float* fb1  = (const float*)d_in[24];
  const float* fw2  = (const float*)d_in[25];
  const float* fb2  = (const float*)d_in[26];
  const float* cw   = (const float*)d_in[27];
  const float* cb   = (const float*)d_in[28];
  const float* cg   = (const float*)d_in[29];
  const float* cbeta= (const float*)d_in[30];
  const float* f1w  = (const float*)d_in[31];
  const float* f1b  = (const float*)d_in[32];
  const float* b1g  = (const float*)d_in[33];
  const float* b1b  = (const float*)d_in[34];
  const float* f2w  = (const float*)d_in[35];
  const float* f2b  = (const float*)d_in[36];
  const float* b2g  = (const float*)d_in[37];
  const float* b2b  = (const float*)d_in[38];
  const float* f3w  = (const float*)d_in[39];
  const float* f3b  = (const float*)d_in[40];

  const size_t P = (size_t)BB * NN;       // 32768 points
  float* ws = (float*)d_ws;
  float* h = ws;                          // P*64
  float* q = h + P * 64;
  float* k = q + P * 64;
  float* v = k + P * 64;
  int* idx = (int*)(v + P * 64);          // P*8 ints
  float* g = (float*)(idx + P * 8);       // B*128
  float4* ppg = (float4*)(g + BB * 128);  // P float4 (aligned: offset is 16B-multiple)
  float* t = q;                           // alias: safe (same-point read-then-write)

  zero_kernel<<<1, BB * 128, 0, stream>>>(g);
  embed_kernel<<<(int)(P / 4), 256, 0, stream>>>(x, ew1, eb1, ew2, eb2, h);
  knn_prep_kernel<<<(int)(P / 256), 256, 0, stream>>>(x, ppg);
  knn_kernel<<<BB * (NN / QPB), 1024, 0, stream>>>(ppg, idx);
  for (int l = 0; l < 2; l++) {
    qkv_kernel<<<QKV_GRID, 256, 0, stream>>>(h, wq + l * DD * DD, bq + l * DD,
                                             wk + l * DD * DD, bk + l * DD,
                                             wv + l * DD * DD, bv + l * DD, q, k, v);
    attn_kernel<<<ATTN_GRID, 256, 0, stream>>>(x, h, q, k, v, idx,
                                               pw1 + l * 3 * DD, pb1 + l * DD,
                                               pw2 + l * DD * DD, pb2 + l * DD,
                                               aw + l * DD, ab + l,
                                               ow + l * DD * DD, ob + l * DD,
                                               l1g + l * DD, l1b + l * DD, t);
    ffn_kernel<<<FFN_GRID, 256, 0, stream>>>(t, fw1 + l * DD * 2 * DD, fb1 + l * 2 * DD,
                                             fw2 + l * 2 * DD * DD, fb2 + l * DD,
                                             l2g + l * DD, l2b + l * DD, h);
  }
  cls_kernel<<<BB * 128, 256, 0, stream>>>(h, cw, cb, cg, cbeta, g);
  head_kernel<<<BB, 128, 0, stream>>>(g, f1w, f1b, b1g, b1b, f2w, f2b, b2g, b2b, f3w, f3b,
                                      (float*)d_out);
}

// Round 10
// 387.022 us; speedup vs baseline: 1.3743x; 1.0735x over previous
//
#include <hip/hip_runtime.h>
#include <cmath>

#define BB 8
#define NN 4096
#define DD 64
#define KK 8
#define NCLS 2

constexpr float LNEPS = 1e-5f;
constexpr float BNRS = 0.9999950000374994f;      // 1/sqrt(1+1e-5)
constexpr float INVSQRT2 = 0.70710678118654752440f;

constexpr int QKV_GRID = 512;
constexpr int FFN_GRID = 512;

// knn decomposition: 64 queries/block x 16 candidate-splits (one per wave)
#define QPB 64
#define SPLITS 16
#define SUBSET 64     // pass-1 subset per split (16*64 = 1024-point bound set)

__device__ __forceinline__ float wave_sum(float v) {
#pragma unroll
  for (int m = 32; m > 0; m >>= 1) v += __shfl_xor(v, m, 64);
  return v;
}

__device__ __forceinline__ float gelu_exact(float x) {
  return 0.5f * x * (1.0f + erff(x * INVSQRT2));
}

// identical in both knn passes -> bit-identical distances
__device__ __forceinline__ float dist2(float4 q, float4 p) {
  float dot = fmaf(q.x, p.x, fmaf(q.y, p.y, q.z * p.z));
  return fmaf(-2.0f, dot, q.w + p.w);
}

// ---------------------------------------------------------------- zero g
__global__ void zero_kernel(float* g) { g[threadIdx.x] = 0.0f; }

// ---------------------------------------------------------------- embed: h = relu(x@ew1+eb1)@ew2+eb2
// XCD-pinned: batch = blockIdx & 7 (all blocks of a batch on one XCD's L2)
__global__ __launch_bounds__(256) void embed_kernel(
    const float* __restrict__ x, const float* __restrict__ ew1, const float* __restrict__ eb1,
    const float* __restrict__ ew2, const float* __restrict__ eb2, float* __restrict__ h) {
  __shared__ float h1[4][DD];
  int w = threadIdx.x >> 6, c = threadIdx.x & 63;
  int pt = ((blockIdx.x & 7) << 12) + (blockIdx.x >> 3) * 4 + w;
  const float* xp = x + (size_t)pt * 3;
  float x0 = xp[0], x1 = xp[1], x2 = xp[2];
  float a = fmaf(x0, ew1[c], fmaf(x1, ew1[64 + c], fmaf(x2, ew1[128 + c], eb1[c])));
  h1[w][c] = fmaxf(a, 0.0f);
  float s = eb2[c];
#pragma unroll 8
  for (int d = 0; d < DD; d++) s = fmaf(h1[w][d], ew2[d * 64 + c], s);
  h[(size_t)pt * 64 + c] = s;
}

// ---------------------------------------------------------------- knn prep: ppg[b*N+j] = (x,y,z,|p|^2)
__global__ __launch_bounds__(256) void knn_prep_kernel(const float* __restrict__ x,
                                                       float4* __restrict__ ppg) {
  int i = ((blockIdx.x & 7) << 12) + (blockIdx.x >> 3) * 256 + threadIdx.x;
  float a0 = x[3 * i + 0], a1 = x[3 * i + 1], a2 = x[3 * i + 2];
  ppg[i] = make_float4(a0, a1, a2, a0 * a0 + a1 * a1 + a2 * a2);
}

// ---------------------------------------------------------------- knn: exact top-8 (stable ties), 2-pass
__global__ __launch_bounds__(1024) void knn_kernel(const float4* __restrict__ ppg,
                                                   int* __restrict__ idx) {
  __shared__ union {
    float v[SPLITS * 8][QPB];       // pass-1 value lists
    double k[SPLITS * 8][QPB];      // pass-2 key lists (64 KB)
  } mb;
  __shared__ float thrq[QPB];
  int b = blockIdx.x & 7;           // XCD-pinned batch
  int qbase = (blockIdx.x >> 3) * QPB;
  const float4* pb = ppg + (size_t)b * NN;
  int ql = threadIdx.x & 63;
  int sp = __builtin_amdgcn_readfirstlane(threadIdx.x >> 6);  // wave id = split id (SGPR)
  float4 qp = pb[qbase + ql];
  const float4* cp = pb + sp * (NN / SPLITS);                 // scalar base

  // ---- pass 1: branchless top-8 distances over SUBSET candidates
  float bd[8];
#pragma unroll
  for (int u = 0; u < 8; u++) bd[u] = INFINITY;
#pragma unroll 4
  for (int jj = 0; jj < SUBSET; ++jj) {
    float d2 = dist2(qp, cp[jj]);
#pragma unroll
    for (int u = 7; u > 0; --u) bd[u] = fminf(bd[u], fmaxf(bd[u - 1], d2));
    bd[0] = fminf(bd[0], d2);
  }
#pragma unroll
  for (int u = 0; u < 8; u++) mb.v[sp * 8 + u][ql] = bd[u];
  __syncthreads();

  // ---- U merge stage 1
  if (sp < 8) {
    float cd[8];
#pragma unroll
    for (int u = 0; u < 8; u++) cd[u] = INFINITY;
    int base = sp * 16;
#pragma unroll
    for (int e = 0; e < 16; e++) {
      float vv = mb.v[base + e][ql];
#pragma unroll
      for (int u = 7; u > 0; --u) cd[u] = fminf(cd[u], fmaxf(cd[u - 1], vv));
      cd[0] = fminf(cd[0], vv);
    }
#pragma unroll
    for (int u = 0; u < 8; u++) mb.v[base + u][ql] = cd[u];
  }
  __syncthreads();

  // ---- U merge stage 2
  if (sp == 0) {
    float cd[8];
#pragma unroll
    for (int u = 0; u < 8; u++) cd[u] = INFINITY;
    for (int m = 0; m < 8; m++) {
      for (int e = 0; e < 8; e++) {
        float vv = mb.v[m * 16 + e][ql];
        if (__all(vv >= cd[7])) break;
#pragma unroll
        for (int u = 7; u > 0; --u) cd[u] = fminf(cd[u], fmaxf(cd[u - 1], vv));
        cd[0] = fminf(cd[0], vv);
      }
    }
    thrq[ql] = cd[7];
  }
  __syncthreads();
  float U = thrq[ql];

  // ---- pass 2: exact per-split top-8 of hits (d2<=U), f64 keys in registers
  double kd[8];
#pragma unroll
  for (int u = 0; u < 8; u++) kd[u] = INFINITY;
#pragma unroll 4
  for (int jj = 0; jj < NN / SPLITS; ++jj) {
    float d2 = dist2(qp, cp[jj]);
    if (d2 <= U) {
      double key = __hiloint2double(__float_as_int(d2), sp * (NN / SPLITS) + jj);
      if (key < kd[7]) {
#pragma unroll
        for (int u = 7; u > 0; --u) kd[u] = fmin(kd[u], fmax(kd[u - 1], key));
        kd[0] = fmin(kd[0], key);
      }
    }
  }
#pragma unroll
  for (int u = 0; u < 8; u++) mb.k[sp * 8 + u][ql] = kd[u];
  __syncthreads();

  // ---- key merge stage 1
  if (sp < 8) {
    double cd[8];
#pragma unroll
    for (int u = 0; u < 8; u++) cd[u] = INFINITY;
    int base = sp * 16;
#pragma unroll
    for (int e = 0; e < 16; e++) {
      double key = mb.k[base + e][ql];
#pragma unroll
      for (int u = 7; u > 0; --u) cd[u] = fmin(cd[u], fmax(cd[u - 1], key));
      cd[0] = fmin(cd[0], key);
    }
#pragma unroll
    for (int u = 0; u < 8; u++) mb.k[base + u][ql] = cd[u];
  }
  __syncthreads();

  // ---- key merge stage 2 + write
  if (sp == 0) {
    double cd[8];
#pragma unroll
    for (int u = 0; u < 8; u++) cd[u] = INFINITY;
    for (int m = 0; m < 8; m++) {
      for (int e = 0; e < 8; e++) {
        double key = mb.k[m * 16 + e][ql];
        if (__all(key >= cd[7])) break;
#pragma unroll
        for (int u = 7; u > 0; --u) cd[u] = fmin(cd[u], fmax(cd[u - 1], key));
        cd[0] = fmin(cd[0], key);
      }
    }
    int* op = idx + ((size_t)b * NN + qbase + ql) * 8;
#pragma unroll
    for (int u = 0; u < 8; u++) op[u] = __double2loint(cd[u]);
  }
}

// ---------------------------------------------------------------- qkv projection (4 points per wave, XCD-pinned)
__global__ __launch_bounds__(256) void qkv_kernel(
    const float* __restrict__ h, const float* __restrict__ wq, const float* __restrict__ bq,
    const float* __restrict__ wk, const float* __restrict__ bk,
    const float* __restrict__ wv, const float* __restrict__ bv,
    float* __restrict__ q, float* __restrict__ k, float* __restrict__ v) {
  __shared__ float lwq[DD * DD], lwk[DD * DD], lwv[DD * DD];
  __shared__ float lbq[DD], lbk[DD], lbv[DD];
  __shared__ __attribute__((aligned(16))) float hb[4][DD][4];
  int tid = threadIdx.x;
  for (int i = tid; i < DD * DD; i += 256) { lwq[i] = wq[i]; lwk[i] = wk[i]; lwv[i] = wv[i]; }
  if (tid < DD) { lbq[tid] = bq[tid]; lbk[tid] = bk[tid]; lbv[tid] = bv[tid]; }
  __syncthreads();
  int w = tid >> 6, c = tid & 63;
  int batch = blockIdx.x & 7, pos = blockIdx.x >> 3;   // 64 block-positions per batch
  constexpr int ITERS = NN / ((QKV_GRID / 8) * 16);    // 4
  for (int it = 0; it < ITERS; ++it) {
    int p0 = (batch << 12) + ((it * 64 + pos) * 4 + w) * 4;
#pragma unroll
    for (int i = 0; i < 4; i++) hb[w][c][i] = h[(size_t)(p0 + i) * 64 + c];
    float aq[4], ak[4], av[4];
#pragma unroll
    for (int i = 0; i < 4; i++) { aq[i] = lbq[c]; ak[i] = lbk[c]; av[i] = lbv[c]; }
#pragma unroll 4
    for (int d = 0; d < DD; d++) {
      float wq_ = lwq[d * 64 + c], wk_ = lwk[d * 64 + c], wv_ = lwv[d * 64 + c];
      float4 hh = *(const float4*)&hb[w][d][0];
      aq[0] = fmaf(hh.x, wq_, aq[0]); aq[1] = fmaf(hh.y, wq_, aq[1]);
      aq[2] = fmaf(hh.z, wq_, aq[2]); aq[3] = fmaf(hh.w, wq_, aq[3]);
      ak[0] = fmaf(hh.x, wk_, ak[0]); ak[1] = fmaf(hh.y, wk_, ak[1]);
      ak[2] = fmaf(hh.z, wk_, ak[2]); ak[3] = fmaf(hh.w, wk_, ak[3]);
      av[0] = fmaf(hh.x, wv_, av[0]); av[1] = fmaf(hh.y, wv_, av[1]);
      av[2] = fmaf(hh.z, wv_, av[2]); av[3] = fmaf(hh.w, wv_, av[3]);
    }
#pragma unroll
    for (int i = 0; i < 4; i++) {
      q[(size_t)(p0 + i) * 64 + c] = aq[i];
      k[(size_t)(p0 + i) * 64 + c] = ak[i];
      v[(size_t)(p0 + i) * 64 + c] = av[i];
    }
  }
}

// ---------------------------------------------------------------- attention: 1-wave blocks, 2 points/wave
// All per-channel weights in registers; pw2/ow read from global (L1-hot, wave-broadcast);
// LDS only h1b (4KB) + outb (0.5KB) -> ~24-28 waves/CU resident.
// NOTE: t may alias q (same-point read-then-write only) -> no __restrict__ on q/t.
__global__ __launch_bounds__(64) void attn_kernel(
    const float* __restrict__ x, const float* __restrict__ h,
    const float* q, const float* __restrict__ kk, const float* __restrict__ vv,
    const int* __restrict__ idx,
    const float* __restrict__ pw1, const float* __restrict__ pb1,
    const float* __restrict__ pw2, const float* __restrict__ pb2,
    const float* __restrict__ aw, const float* __restrict__ ab,
    const float* __restrict__ ow, const float* __restrict__ ob,
    const float* __restrict__ l1g, const float* __restrict__ l1b,
    float* t) {
  __shared__ __attribute__((aligned(16))) float h1b[2][DD][8];   // 4KB
  __shared__ __attribute__((aligned(16))) float outb[2][DD];     // 0.5KB
  int c = threadIdx.x;
  int b = blockIdx.x & 7;                 // XCD-pinned batch
  int n0 = (blockIdx.x >> 3) * 2;         // 2048 positions per batch
  int p0 = (b << 12) + n0;
  const float* xb = x + (size_t)b * NN * 3;
  // per-lane weights in registers (L1-hot global reads)
  float w1c0 = pw1[c], w1c1 = pw1[64 + c], w1c2 = pw1[128 + c], b1c = pb1[c];
  float pb2c = pb2[c], lawc = aw[c], lobc = ob[c], g1c = l1g[c], bt1c = l1b[c];
  float lab = ab[0];
  float hs0 = h[(size_t)p0 * 64 + c], hs1 = h[(size_t)(p0 + 1) * 64 + c];
  float qs0 = q[(size_t)p0 * 64 + c], qs1 = q[(size_t)(p0 + 1) * 64 + c];
  int nb[2][8];
#pragma unroll
  for (int u = 0; u < 8; u++) {
    nb[0][u] = idx[(size_t)p0 * 8 + u];
    nb[1][u] = idx[(size_t)(p0 + 1) * 8 + u];
  }
  // ---- prefetch all k/v gather rows NOW; latency hides under pe1+pe2 compute
  float kv0[8], kv1[8], vg0[8], vg1[8];
#pragma unroll
  for (int u = 0; u < 8; u++) {
    kv0[u] = kk[((size_t)(b << 12) + nb[0][u]) * 64 + c];
    kv1[u] = kk[((size_t)(b << 12) + nb[1][u]) * 64 + c];
    vg0[u] = vv[((size_t)(b << 12) + nb[0][u]) * 64 + c];
    vg1[u] = vv[((size_t)(b << 12) + nb[1][u]) * 64 + c];
  }
#pragma unroll
  for (int pt = 0; pt < 2; ++pt) {
    int n = n0 + pt;
    float px0 = xb[n * 3 + 0], px1 = xb[n * 3 + 1], px2 = xb[n * 3 + 2];
    float h1v[8];
#pragma unroll
    for (int u = 0; u < 8; u++) {
      int m = nb[pt][u];
      float d0 = px0 - xb[m * 3 + 0], d1 = px1 - xb[m * 3 + 1], d2 = px2 - xb[m * 3 + 2];
      h1v[u] = fmaxf(fmaf(d0, w1c0, fmaf(d1, w1c1, fmaf(d2, w1c2, b1c))), 0.0f);
    }
    *(float4*)&h1b[pt][c][0] = make_float4(h1v[0], h1v[1], h1v[2], h1v[3]);
    *(float4*)&h1b[pt][c][4] = make_float4(h1v[4], h1v[5], h1v[6], h1v[7]);
  }
  float acc0[8], acc1[8];
#pragma unroll
  for (int u = 0; u < 8; u++) { acc0[u] = pb2c; acc1[u] = pb2c; }
#pragma unroll 2
  for (int d = 0; d < DD; d++) {
    float wv_ = pw2[d * 64 + c];
    float4 a0 = *(const float4*)&h1b[0][d][0];
    float4 b0 = *(const float4*)&h1b[0][d][4];
    float4 a1 = *(const float4*)&h1b[1][d][0];
    float4 b1 = *(const float4*)&h1b[1][d][4];
    acc0[0] = fmaf(a0.x, wv_, acc0[0]); acc0[1] = fmaf(a0.y, wv_, acc0[1]);
    acc0[2] = fmaf(a0.z, wv_, acc0[2]); acc0[3] = fmaf(a0.w, wv_, acc0[3]);
    acc0[4] = fmaf(b0.x, wv_, acc0[4]); acc0[5] = fmaf(b0.y, wv_, acc0[5]);
    acc0[6] = fmaf(b0.z, wv_, acc0[6]); acc0[7] = fmaf(b0.w, wv_, acc0[7]);
    acc1[0] = fmaf(a1.x, wv_, acc1[0]); acc1[1] = fmaf(a1.y, wv_, acc1[1]);
    acc1[2] = fmaf(a1.z, wv_, acc1[2]); acc1[3] = fmaf(a1.w, wv_, acc1[3]);
    acc1[4] = fmaf(b1.x, wv_, acc1[4]); acc1[5] = fmaf(b1.y, wv_, acc1[5]);
    acc1[6] = fmaf(b1.z, wv_, acc1[6]); acc1[7] = fmaf(b1.w, wv_, acc1[7]);
  }
  float lg0[8], lg1[8];
#pragma unroll
  for (int u = 0; u < 8; u++) {
    lg0[u] = wave_sum((qs0 - kv0[u] + acc0[u]) * lawc) + lab;
    lg1[u] = wave_sum((qs1 - kv1[u] + acc1[u]) * lawc) + lab;
  }
  float mx0 = lg0[0], mx1 = lg1[0];
#pragma unroll
  for (int u = 1; u < 8; u++) { mx0 = fmaxf(mx0, lg0[u]); mx1 = fmaxf(mx1, lg1[u]); }
  float s0 = 0.0f, s1 = 0.0f;
#pragma unroll
  for (int u = 0; u < 8; u++) {
    lg0[u] = expf(lg0[u] - mx0); s0 += lg0[u];
    lg1[u] = expf(lg1[u] - mx1); s1 += lg1[u];
  }
  float i0 = 1.0f / s0, i1 = 1.0f / s1;
  float out0 = 0.0f, out1 = 0.0f;
#pragma unroll
  for (int u = 0; u < 8; u++) {
    out0 = fmaf(lg0[u] * i0, vg0[u] + acc0[u], out0);
    out1 = fmaf(lg1[u] * i1, vg1[u] + acc1[u], out1);
  }
  outb[0][c] = out0; outb[1][c] = out1;
  float at0 = lobc, at1 = lobc;
#pragma unroll 4
  for (int d = 0; d < DD; d += 4) {
    float4 o0 = *(const float4*)&outb[0][d];
    float4 o1 = *(const float4*)&outb[1][d];
    float wa = ow[(d + 0) * 64 + c], wb = ow[(d + 1) * 64 + c];
    float wc = ow[(d + 2) * 64 + c], wd = ow[(d + 3) * 64 + c];
    at0 = fmaf(o0.x, wa, at0); at0 = fmaf(o0.y, wb, at0);
    at0 = fmaf(o0.z, wc, at0); at0 = fmaf(o0.w, wd, at0);
    at1 = fmaf(o1.x, wa, at1); at1 = fmaf(o1.y, wb, at1);
    at1 = fmaf(o1.z, wc, at1); at1 = fmaf(o1.w, wd, at1);
  }
  {
    float res = at0 + hs0;
    float mean = wave_sum(res) * (1.0f / 64.0f);
    float dv = res - mean;
    float var = wave_sum(dv * dv) * (1.0f / 64.0f);
    float ivr = 1.0f / sqrtf(var + LNEPS);
    t[(size_t)p0 * 64 + c] = fmaf(g1c, dv * ivr, bt1c);
  }
  {
    float res = at1 + hs1;
    float mean = wave_sum(res) * (1.0f / 64.0f);
    float dv = res - mean;
    float var = wave_sum(dv * dv) * (1.0f / 64.0f);
    float ivr = 1.0f / sqrtf(var + LNEPS);
    t[(size_t)(p0 + 1) * 64 + c] = fmaf(g1c, dv * ivr, bt1c);
  }
}

// ---------------------------------------------------------------- ffn (4 points per wave, XCD-pinned) -> h = ln2(t + ffn(t))
__global__ __launch_bounds__(256) void ffn_kernel(
    const float* __restrict__ t, const float* __restrict__ fw1, const float* __restrict__ fb1,
    const float* __restrict__ fw2, const float* __restrict__ fb2,
    const float* __restrict__ l2g, const float* __restrict__ l2b, float* __restrict__ h) {
  __shared__ float lf1[DD * 128];
  __shared__ float lf2[128 * DD];
  __shared__ float lb1[128], lb2[DD], lg2[DD], lbt2[DD];
  __shared__ __attribute__((aligned(16))) float yb[4][DD][4];
  __shared__ __attribute__((aligned(16))) float hb[4][128][4];
  int tid = threadIdx.x;
  for (int i = tid; i < DD * 128; i += 256) { lf1[i] = fw1[i]; lf2[i] = fw2[i]; }
  if (tid < 128) lb1[tid] = fb1[tid];
  if (tid < DD) { lb2[tid] = fb2[tid]; lg2[tid] = l2g[tid]; lbt2[tid] = l2b[tid]; }
  __syncthreads();
  int w = tid >> 6, c = tid & 63;
  int batch = blockIdx.x & 7, pos = blockIdx.x >> 3;
  constexpr int ITERS = NN / ((FFN_GRID / 8) * 16);   // 4
  for (int it = 0; it < ITERS; ++it) {
    int p0 = (batch << 12) + ((it * 64 + pos) * 4 + w) * 4;
    float y[4];
#pragma unroll
    for (int i = 0; i < 4; i++) { y[i] = t[(size_t)(p0 + i) * 64 + c]; yb[w][c][i] = y[i]; }
    float hA[4], hB[4];
#pragma unroll
    for (int i = 0; i < 4; i++) { hA[i] = lb1[c]; hB[i] = lb1[64 + c]; }
#pragma unroll 4
    for (int d = 0; d < DD; d++) {
      float w0 = lf1[d * 128 + c], w1 = lf1[d * 128 + 64 + c];
      float4 yv = *(const float4*)&yb[w][d][0];
      hA[0] = fmaf(yv.x, w0, hA[0]); hA[1] = fmaf(yv.y, w0, hA[1]);
      hA[2] = fmaf(yv.z, w0, hA[2]); hA[3] = fmaf(yv.w, w0, hA[3]);
      hB[0] = fmaf(yv.x, w1, hB[0]); hB[1] = fmaf(yv.y, w1, hB[1]);
      hB[2] = fmaf(yv.z, w1, hB[2]); hB[3] = fmaf(yv.w, w1, hB[3]);
    }
#pragma unroll
    for (int i = 0; i < 4; i++) {
      hA[i] = gelu_exact(hA[i]); hB[i] = gelu_exact(hB[i]);
      hb[w][c][i] = hA[i]; hb[w][64 + c][i] = hB[i];
    }
    float o[4];
#pragma unroll
    for (int i = 0; i < 4; i++) o[i] = lb2[c];
#pragma unroll 4
    for (int j = 0; j < 128; j++) {
      float wv_ = lf2[j * 64 + c];
      float4 hv = *(const float4*)&hb[w][j][0];
      o[0] = fmaf(hv.x, wv_, o[0]); o[1] = fmaf(hv.y, wv_, o[1]);
      o[2] = fmaf(hv.z, wv_, o[2]); o[3] = fmaf(hv.w, wv_, o[3]);
    }
#pragma unroll
    for (int i = 0; i < 4; i++) {
      float r = y[i] + o[i];
      float mean = wave_sum(r) * (1.0f / 64.0f);
      float dv = r - mean;
      float var = wave_sum(dv * dv) * (1.0f / 64.0f);
      float ivr = 1.0f / sqrtf(var + LNEPS);
      h[(size_t)(p0 + i) * 64 + c] = fmaf(lg2[c], dv * ivr, lbt2[c]);
    }
  }
}

// ---------------------------------------------------------------- classifier proj + blockwise max-pool (XCD-pinned)
__global__ __launch_bounds__(256) void cls_kernel(
    const float* __restrict__ h, const float* __restrict__ cw, const float* __restrict__ cb,
    const float* __restrict__ cg, const float* __restrict__ cbeta, float* __restrict__ g) {
  __shared__ float lcw[DD * 128];
  __shared__ float lcb[128], lcg[128], lcbt[128];
  __shared__ __attribute__((aligned(16))) float hb[4][DD][4];
  __shared__ float wmax[4][128];
  int tid = threadIdx.x;
  for (int i = tid; i < DD * 128; i += 256) lcw[i] = cw[i];
  if (tid < 128) { lcb[tid] = cb[tid]; lcg[tid] = cg[tid]; lcbt[tid] = cbeta[tid]; }
  __syncthreads();
  int w = tid >> 6, c = tid & 63;
  int b = blockIdx.x & 7;             // XCD-pinned batch
  int blk = blockIdx.x >> 3;          // 128 block-positions per batch
  int base = b * NN + blk * 32;
  float m0 = 0.0f, m1 = 0.0f;
  for (int it = 0; it < 2; ++it) {
    int p0 = base + (w * 2 + it) * 4;
#pragma unroll
    for (int i = 0; i < 4; i++) hb[w][c][i] = h[(size_t)(p0 + i) * 64 + c];
    float a0[4], a1[4];
#pragma unroll
    for (int i = 0; i < 4; i++) { a0[i] = lcb[c]; a1[i] = lcb[64 + c]; }
#pragma unroll 4
    for (int d = 0; d < DD; d++) {
      float w0 = lcw[d * 128 + c], w1 = lcw[d * 128 + 64 + c];
      float4 hv = *(const float4*)&hb[w][d][0];
      a0[0] = fmaf(hv.x, w0, a0[0]); a0[1] = fmaf(hv.y, w0, a0[1]);
      a0[2] = fmaf(hv.z, w0, a0[2]); a0[3] = fmaf(hv.w, w0, a0[3]);
      a1[0] = fmaf(hv.x, w1, a1[0]); a1[1] = fmaf(hv.y, w1, a1[1]);
      a1[2] = fmaf(hv.z, w1, a1[2]); a1[3] = fmaf(hv.w, w1, a1[3]);
    }
#pragma unroll
    for (int i = 0; i < 4; i++) {
      m0 = fmaxf(m0, fmaxf(0.0f, fmaf(lcg[c] * a0[i], BNRS, lcbt[c])));
      m1 = fmaxf(m1, fmaxf(0.0f, fmaf(lcg[64 + c] * a1[i], BNRS, lcbt[64 + c])));
    }
  }
  wmax[w][c] = m0; wmax[w][64 + c] = m1;
  __syncthreads();
  if (tid < 128) {
    float mm = fmaxf(fmaxf(wmax[0][tid], wmax[1][tid]), fmaxf(wmax[2][tid], wmax[3][tid]));
    atomicMax((int*)&g[b * 128 + tid], __float_as_int(mm));  // values >= 0
  }
}

// ---------------------------------------------------------------- final head (per batch)
__global__ __launch_bounds__(128) void head_kernel(
    const float* __restrict__ g,
    const float* __restrict__ f1w, const float* __restrict__ f1b,
    const float* __restrict__ b1g, const float* __restrict__ b1b,
    const float* __restrict__ f2w, const float* __restrict__ f2b,
    const float* __restrict__ b2g, const float* __restrict__ b2b,
    const float* __restrict__ f3w, const float* __restrict__ f3b,
    float* __restrict__ out) {
  __shared__ float gb[128], g1[128], g2[64];
  int b = blockIdx.x, t = threadIdx.x;
  gb[t] = g[b * 128 + t];
  __syncthreads();
  float a = f1b[t];
#pragma unroll 4
  for (int d = 0; d < 128; d++) a = fmaf(gb[d], f1w[d * 128 + t], a);
  g1[t] = fmaxf(0.0f, fmaf(b1g[t] * a, BNRS, b1b[t]));
  __syncthreads();
  if (t < 64) {
    float a2 = f2b[t];
#pragma unroll 4
    for (int j = 0; j < 128; j++) a2 = fmaf(g1[j], f2w[j * 64 + t], a2);
    g2[t] = fmaxf(0.0f, fmaf(b2g[t] * a2, BNRS, b2b[t]));
  }
  __syncthreads();
  if (t < NCLS) {
    float a3 = f3b[t];
#pragma unroll
    for (int d = 0; d < 64; d++) a3 = fmaf(g2[d], f3w[d * NCLS + t], a3);
    out[b * NCLS + t] = a3;
  }
}

extern "C" void kernel_launch(void* const* d_in, const int* in_sizes, int n_in,
                              void* d_out, int out_size, void* d_ws, size_t ws_size,
                              hipStream_t stream) {
  const float* x    = (const float*)d_in[0];
  const float* ew1  = (const float*)d_in[1];
  const float* eb1  = (const float*)d_in[2];
  const float* ew2  = (const float*)d_in[3];
  const float* eb2  = (const float*)d_in[4];
  const float* wq   = (const float*)d_in[5];
  const float* bq   = (const float*)d_in[6];
  const float* wk   = (const float*)d_in[7];
  const float* bk   = (const float*)d_in[8];
  const float* wv   = (const float*)d_in[9];
  const float* bv   = (const float*)d_in[10];
  const float* pw1  = (const float*)d_in[11];
  const float* pb1  = (const float*)d_in[12];
  const float* pw2  = (const float*)d_in[13];
  const float* pb2  = (const float*)d_in[14];
  const float* aw   = (const float*)d_in[15];
  const float* ab   = (const float*)d_in[16];
  const float* ow   = (const float*)d_in[17];
  const float* ob   = (const float*)d_in[18];
  const float* l1g  = (const float*)d_in[19];
  const float* l1b  = (const float*)d_in[20];
  const float* l2g  = (const float*)d_in[21];
  const float* l2b  = (const float*)d_in[22];
  const float* fw1  = (const float*)d_in[23];
  const float* fb1  = (const float*)d_in[24];
  const float* fw2  = (const float*)d_in[25];
  const float* fb2  = (const float*)d_in[26];
  const float* cw   = (const float*)d_in[27];
  const float* cb   = (const float*)d_in[28];
  const float* cg   = (const float*)d_in[29];
  const float* cbeta= (const float*)d_in[30];
  const float* f1w  = (const float*)d_in[31];
  const float* f1b  = (const float*)d_in[32];
  const float* b1g  = (const float*)d_in[33];
  const float* b1b  = (const float*)d_in[34];
  const float* f2w  = (const float*)d_in[35];
  const float* f2b  = (const float*)d_in[36];
  const float* b2g  = (const float*)d_in[37];
  const float* b2b  = (const float*)d_in[38];
  const float* f3w  = (const float*)d_in[39];
  const float* f3b  = (const float*)d_in[40];

  const size_t P = (size_t)BB * NN;       // 32768 points
  float* ws = (float*)d_ws;
  float* h = ws;                          // P*64
  float* q = h + P * 64;
  float* k = q + P * 64;
  float* v = k + P * 64;
  int* idx = (int*)(v + P * 64);          // P*8 ints
  float* g = (float*)(idx + P * 8);       // B*128
  float4* ppg = (float4*)(g + BB * 128);  // P float4 (aligned: offset is 16B-multiple)
  float* t = q;                           // alias: safe (same-point read-then-write)

  zero_kernel<<<1, BB * 128, 0, stream>>>(g);
  embed_kernel<<<(int)(P / 4), 256, 0, stream>>>(x, ew1, eb1, ew2, eb2, h);
  knn_prep_kernel<<<(int)(P / 256), 256, 0, stream>>>(x, ppg);
  knn_kernel<<<BB * (NN / QPB), 1024, 0, stream>>>(ppg, idx);
  for (int l = 0; l < 2; l++) {
    qkv_kernel<<<QKV_GRID, 256, 0, stream>>>(h, wq + l * DD * DD, bq + l * DD,
                                             wk + l * DD * DD, bk + l * DD,
                                             wv + l * DD * DD, bv + l * DD, q, k, v);
    attn_kernel<<<(int)(P / 2), 64, 0, stream>>>(x, h, q, k, v, idx,
                                                 pw1 + l * 3 * DD, pb1 + l * DD,
                                                 pw2 + l * DD * DD, pb2 + l * DD,
                                                 aw + l * DD, ab + l,
                                                 ow + l * DD * DD, ob + l * DD,
                                                 l1g + l * DD, l1b + l * DD, t);
    ffn_kernel<<<FFN_GRID, 256, 0, stream>>>(t, fw1 + l * DD * 2 * DD, fb1 + l * 2 * DD,
                                             fw2 + l * 2 * DD * DD, fb2 + l * DD,
                                             l2g + l * DD, l2b + l * DD, h);
  }
  cls_kernel<<<BB * 128, 256, 0, stream>>>(h, cw, cb, cg, cbeta, g);
  head_kernel<<<BB, 128, 0, stream>>>(g, f1w, f1b, b1g, b1b, f2w, f2b, b2g, b2b, f3w, f3b,
                                      (float*)d_out);
}

// Round 11
// 372.760 us; speedup vs baseline: 1.4269x; 1.0383x over previous
//
#include <hip/hip_runtime.h>
#include <cmath>

#define BB 8
#define NN 4096
#define DD 64
#define KK 8
#define NCLS 2

constexpr float LNEPS = 1e-5f;
constexpr float BNRS = 0.9999950000374994f;      // 1/sqrt(1+1e-5)
constexpr float INVSQRT2 = 0.70710678118654752440f;

// knn decomposition: 64 queries/block x 16 candidate-splits (one per wave)
#define QPB 64
#define SPLITS 16
#define SUBSET 64     // pass-1 subset per split (16*64 = 1024-point bound set)

__device__ __forceinline__ float wave_sum(float v) {
#pragma unroll
  for (int m = 32; m > 0; m >>= 1) v += __shfl_xor(v, m, 64);
  return v;
}

__device__ __forceinline__ float gelu_exact(float x) {
  return 0.5f * x * (1.0f + erff(x * INVSQRT2));
}

// identical in both knn passes -> bit-identical distances
__device__ __forceinline__ float dist2(float4 q, float4 p) {
  float dot = fmaf(q.x, p.x, fmaf(q.y, p.y, q.z * p.z));
  return fmaf(-2.0f, dot, q.w + p.w);
}

// ---------------------------------------------------------------- zero g
__global__ void zero_kernel(float* g) { g[threadIdx.x] = 0.0f; }

// ---------------------------------------------------------------- embed: h = relu(x@ew1+eb1)@ew2+eb2
// XCD-pinned: batch = blockIdx & 7 (all blocks of a batch on one XCD's L2)
__global__ __launch_bounds__(256) void embed_kernel(
    const float* __restrict__ x, const float* __restrict__ ew1, const float* __restrict__ eb1,
    const float* __restrict__ ew2, const float* __restrict__ eb2, float* __restrict__ h) {
  __shared__ float h1[4][DD];
  int w = threadIdx.x >> 6, c = threadIdx.x & 63;
  int pt = ((blockIdx.x & 7) << 12) + (blockIdx.x >> 3) * 4 + w;
  const float* xp = x + (size_t)pt * 3;
  float x0 = xp[0], x1 = xp[1], x2 = xp[2];
  float a = fmaf(x0, ew1[c], fmaf(x1, ew1[64 + c], fmaf(x2, ew1[128 + c], eb1[c])));
  h1[w][c] = fmaxf(a, 0.0f);
  float s = eb2[c];
#pragma unroll 8
  for (int d = 0; d < DD; d++) s = fmaf(h1[w][d], ew2[d * 64 + c], s);
  h[(size_t)pt * 64 + c] = s;
}

// ---------------------------------------------------------------- knn prep: ppg[b*N+j] = (x,y,z,|p|^2)
__global__ __launch_bounds__(256) void knn_prep_kernel(const float* __restrict__ x,
                                                       float4* __restrict__ ppg) {
  int i = ((blockIdx.x & 7) << 12) + (blockIdx.x >> 3) * 256 + threadIdx.x;
  float a0 = x[3 * i + 0], a1 = x[3 * i + 1], a2 = x[3 * i + 2];
  ppg[i] = make_float4(a0, a1, a2, a0 * a0 + a1 * a1 + a2 * a2);
}

// ---------------------------------------------------------------- knn: exact top-8 (stable ties), 2-pass
__global__ __launch_bounds__(1024) void knn_kernel(const float4* __restrict__ ppg,
                                                   int* __restrict__ idx) {
  __shared__ union {
    float v[SPLITS * 8][QPB];       // pass-1 value lists
    double k[SPLITS * 8][QPB];      // pass-2 key lists (64 KB)
  } mb;
  __shared__ float thrq[QPB];
  int b = blockIdx.x & 7;           // XCD-pinned batch
  int qbase = (blockIdx.x >> 3) * QPB;
  const float4* pb = ppg + (size_t)b * NN;
  int ql = threadIdx.x & 63;
  int sp = __builtin_amdgcn_readfirstlane(threadIdx.x >> 6);  // wave id = split id (SGPR)
  float4 qp = pb[qbase + ql];
  const float4* cp = pb + sp * (NN / SPLITS);                 // scalar base

  // ---- pass 1: branchless top-8 distances over SUBSET candidates
  float bd[8];
#pragma unroll
  for (int u = 0; u < 8; u++) bd[u] = INFINITY;
#pragma unroll 4
  for (int jj = 0; jj < SUBSET; ++jj) {
    float d2 = dist2(qp, cp[jj]);
#pragma unroll
    for (int u = 7; u > 0; --u) bd[u] = fminf(bd[u], fmaxf(bd[u - 1], d2));
    bd[0] = fminf(bd[0], d2);
  }
#pragma unroll
  for (int u = 0; u < 8; u++) mb.v[sp * 8 + u][ql] = bd[u];
  __syncthreads();

  // ---- U merge stage 1
  if (sp < 8) {
    float cd[8];
#pragma unroll
    for (int u = 0; u < 8; u++) cd[u] = INFINITY;
    int base = sp * 16;
#pragma unroll
    for (int e = 0; e < 16; e++) {
      float vv = mb.v[base + e][ql];
#pragma unroll
      for (int u = 7; u > 0; --u) cd[u] = fminf(cd[u], fmaxf(cd[u - 1], vv));
      cd[0] = fminf(cd[0], vv);
    }
#pragma unroll
    for (int u = 0; u < 8; u++) mb.v[base + u][ql] = cd[u];
  }
  __syncthreads();

  // ---- U merge stage 2
  if (sp == 0) {
    float cd[8];
#pragma unroll
    for (int u = 0; u < 8; u++) cd[u] = INFINITY;
    for (int m = 0; m < 8; m++) {
      for (int e = 0; e < 8; e++) {
        float vv = mb.v[m * 16 + e][ql];
        if (__all(vv >= cd[7])) break;
#pragma unroll
        for (int u = 7; u > 0; --u) cd[u] = fminf(cd[u], fmaxf(cd[u - 1], vv));
        cd[0] = fminf(cd[0], vv);
      }
    }
    thrq[ql] = cd[7];
  }
  __syncthreads();
  float U = thrq[ql];

  // ---- pass 2: exact per-split top-8 of hits (d2<=U), f64 keys in registers
  double kd[8];
#pragma unroll
  for (int u = 0; u < 8; u++) kd[u] = INFINITY;
#pragma unroll 4
  for (int jj = 0; jj < NN / SPLITS; ++jj) {
    float d2 = dist2(qp, cp[jj]);
    if (d2 <= U) {
      double key = __hiloint2double(__float_as_int(d2), sp * (NN / SPLITS) + jj);
      if (key < kd[7]) {
#pragma unroll
        for (int u = 7; u > 0; --u) kd[u] = fmin(kd[u], fmax(kd[u - 1], key));
        kd[0] = fmin(kd[0], key);
      }
    }
  }
#pragma unroll
  for (int u = 0; u < 8; u++) mb.k[sp * 8 + u][ql] = kd[u];
  __syncthreads();

  // ---- key merge stage 1
  if (sp < 8) {
    double cd[8];
#pragma unroll
    for (int u = 0; u < 8; u++) cd[u] = INFINITY;
    int base = sp * 16;
#pragma unroll
    for (int e = 0; e < 16; e++) {
      double key = mb.k[base + e][ql];
#pragma unroll
      for (int u = 7; u > 0; --u) cd[u] = fmin(cd[u], fmax(cd[u - 1], key));
      cd[0] = fmin(cd[0], key);
    }
#pragma unroll
    for (int u = 0; u < 8; u++) mb.k[base + u][ql] = cd[u];
  }
  __syncthreads();

  // ---- key merge stage 2 + write
  if (sp == 0) {
    double cd[8];
#pragma unroll
    for (int u = 0; u < 8; u++) cd[u] = INFINITY;
    for (int m = 0; m < 8; m++) {
      for (int e = 0; e < 8; e++) {
        double key = mb.k[m * 16 + e][ql];
        if (__all(key >= cd[7])) break;
#pragma unroll
        for (int u = 7; u > 0; --u) cd[u] = fmin(cd[u], fmax(cd[u - 1], key));
        cd[0] = fmin(cd[0], key);
      }
    }
    int* op = idx + ((size_t)b * NN + qbase + ql) * 8;
#pragma unroll
    for (int u = 0; u < 8; u++) op[u] = __double2loint(cd[u]);
  }
}

// ---------------------------------------------------------------- qkv projection: 1-wave blocks, 4 points/wave
// Weights from global (coalesced, L1/L2-hot, streamed once per wave); LDS only hb (1KB).
__global__ __launch_bounds__(64) void qkv_kernel(
    const float* __restrict__ h, const float* __restrict__ wq, const float* __restrict__ bq,
    const float* __restrict__ wk, const float* __restrict__ bk,
    const float* __restrict__ wv, const float* __restrict__ bv,
    float* __restrict__ q, float* __restrict__ k, float* __restrict__ v) {
  __shared__ __attribute__((aligned(16))) float hb[DD][4];
  int c = threadIdx.x;
  int b = blockIdx.x & 7, pos = blockIdx.x >> 3;   // 1024 positions per batch
  int p0 = (b << 12) + pos * 4;
#pragma unroll
  for (int i = 0; i < 4; i++) hb[c][i] = h[(size_t)(p0 + i) * 64 + c];
  float bqc = bq[c], bkc = bk[c], bvc = bv[c];
  float aq[4], ak[4], av[4];
#pragma unroll
  for (int i = 0; i < 4; i++) { aq[i] = bqc; ak[i] = bkc; av[i] = bvc; }
#pragma unroll 4
  for (int d = 0; d < DD; d++) {
    float wq_ = wq[d * 64 + c], wk_ = wk[d * 64 + c], wv_ = wv[d * 64 + c];
    float4 hh = *(const float4*)&hb[d][0];
    aq[0] = fmaf(hh.x, wq_, aq[0]); aq[1] = fmaf(hh.y, wq_, aq[1]);
    aq[2] = fmaf(hh.z, wq_, aq[2]); aq[3] = fmaf(hh.w, wq_, aq[3]);
    ak[0] = fmaf(hh.x, wk_, ak[0]); ak[1] = fmaf(hh.y, wk_, ak[1]);
    ak[2] = fmaf(hh.z, wk_, ak[2]); ak[3] = fmaf(hh.w, wk_, ak[3]);
    av[0] = fmaf(hh.x, wv_, av[0]); av[1] = fmaf(hh.y, wv_, av[1]);
    av[2] = fmaf(hh.z, wv_, av[2]); av[3] = fmaf(hh.w, wv_, av[3]);
  }
#pragma unroll
  for (int i = 0; i < 4; i++) {
    q[(size_t)(p0 + i) * 64 + c] = aq[i];
    k[(size_t)(p0 + i) * 64 + c] = ak[i];
    v[(size_t)(p0 + i) * 64 + c] = av[i];
  }
}

// ---------------------------------------------------------------- attention: 1-wave blocks, 2 points/wave
// All per-channel weights in registers; pw2/ow read from global (L1-hot, wave-broadcast);
// LDS only h1b (4KB) + outb (0.5KB) -> ~24-28 waves/CU resident.
// NOTE: t may alias q (same-point read-then-write only) -> no __restrict__ on q/t.
__global__ __launch_bounds__(64) void attn_kernel(
    const float* __restrict__ x, const float* __restrict__ h,
    const float* q, const float* __restrict__ kk, const float* __restrict__ vv,
    const int* __restrict__ idx,
    const float* __restrict__ pw1, const float* __restrict__ pb1,
    const float* __restrict__ pw2, const float* __restrict__ pb2,
    const float* __restrict__ aw, const float* __restrict__ ab,
    const float* __restrict__ ow, const float* __restrict__ ob,
    const float* __restrict__ l1g, const float* __restrict__ l1b,
    float* t) {
  __shared__ __attribute__((aligned(16))) float h1b[2][DD][8];   // 4KB
  __shared__ __attribute__((aligned(16))) float outb[2][DD];     // 0.5KB
  int c = threadIdx.x;
  int b = blockIdx.x & 7;                 // XCD-pinned batch
  int n0 = (blockIdx.x >> 3) * 2;         // 2048 positions per batch
  int p0 = (b << 12) + n0;
  const float* xb = x + (size_t)b * NN * 3;
  // per-lane weights in registers (L1-hot global reads)
  float w1c0 = pw1[c], w1c1 = pw1[64 + c], w1c2 = pw1[128 + c], b1c = pb1[c];
  float pb2c = pb2[c], lawc = aw[c], lobc = ob[c], g1c = l1g[c], bt1c = l1b[c];
  float lab = ab[0];
  float hs0 = h[(size_t)p0 * 64 + c], hs1 = h[(size_t)(p0 + 1) * 64 + c];
  float qs0 = q[(size_t)p0 * 64 + c], qs1 = q[(size_t)(p0 + 1) * 64 + c];
  int nb[2][8];
#pragma unroll
  for (int u = 0; u < 8; u++) {
    nb[0][u] = idx[(size_t)p0 * 8 + u];
    nb[1][u] = idx[(size_t)(p0 + 1) * 8 + u];
  }
  // ---- prefetch all k/v gather rows NOW; latency hides under pe1+pe2 compute
  float kv0[8], kv1[8], vg0[8], vg1[8];
#pragma unroll
  for (int u = 0; u < 8; u++) {
    kv0[u] = kk[((size_t)(b << 12) + nb[0][u]) * 64 + c];
    kv1[u] = kk[((size_t)(b << 12) + nb[1][u]) * 64 + c];
    vg0[u] = vv[((size_t)(b << 12) + nb[0][u]) * 64 + c];
    vg1[u] = vv[((size_t)(b << 12) + nb[1][u]) * 64 + c];
  }
#pragma unroll
  for (int pt = 0; pt < 2; ++pt) {
    int n = n0 + pt;
    float px0 = xb[n * 3 + 0], px1 = xb[n * 3 + 1], px2 = xb[n * 3 + 2];
    float h1v[8];
#pragma unroll
    for (int u = 0; u < 8; u++) {
      int m = nb[pt][u];
      float d0 = px0 - xb[m * 3 + 0], d1 = px1 - xb[m * 3 + 1], d2 = px2 - xb[m * 3 + 2];
      h1v[u] = fmaxf(fmaf(d0, w1c0, fmaf(d1, w1c1, fmaf(d2, w1c2, b1c))), 0.0f);
    }
    *(float4*)&h1b[pt][c][0] = make_float4(h1v[0], h1v[1], h1v[2], h1v[3]);
    *(float4*)&h1b[pt][c][4] = make_float4(h1v[4], h1v[5], h1v[6], h1v[7]);
  }
  float acc0[8], acc1[8];
#pragma unroll
  for (int u = 0; u < 8; u++) { acc0[u] = pb2c; acc1[u] = pb2c; }
#pragma unroll 2
  for (int d = 0; d < DD; d++) {
    float wv_ = pw2[d * 64 + c];
    float4 a0 = *(const float4*)&h1b[0][d][0];
    float4 b0 = *(const float4*)&h1b[0][d][4];
    float4 a1 = *(const float4*)&h1b[1][d][0];
    float4 b1 = *(const float4*)&h1b[1][d][4];
    acc0[0] = fmaf(a0.x, wv_, acc0[0]); acc0[1] = fmaf(a0.y, wv_, acc0[1]);
    acc0[2] = fmaf(a0.z, wv_, acc0[2]); acc0[3] = fmaf(a0.w, wv_, acc0[3]);
    acc0[4] = fmaf(b0.x, wv_, acc0[4]); acc0[5] = fmaf(b0.y, wv_, acc0[5]);
    acc0[6] = fmaf(b0.z, wv_, acc0[6]); acc0[7] = fmaf(b0.w, wv_, acc0[7]);
    acc1[0] = fmaf(a1.x, wv_, acc1[0]); acc1[1] = fmaf(a1.y, wv_, acc1[1]);
    acc1[2] = fmaf(a1.z, wv_, acc1[2]); acc1[3] = fmaf(a1.w, wv_, acc1[3]);
    acc1[4] = fmaf(b1.x, wv_, acc1[4]); acc1[5] = fmaf(b1.y, wv_, acc1[5]);
    acc1[6] = fmaf(b1.z, wv_, acc1[6]); acc1[7] = fmaf(b1.w, wv_, acc1[7]);
  }
  float lg0[8], lg1[8];
#pragma unroll
  for (int u = 0; u < 8; u++) {
    lg0[u] = wave_sum((qs0 - kv0[u] + acc0[u]) * lawc) + lab;
    lg1[u] = wave_sum((qs1 - kv1[u] + acc1[u]) * lawc) + lab;
  }
  float mx0 = lg0[0], mx1 = lg1[0];
#pragma unroll
  for (int u = 1; u < 8; u++) { mx0 = fmaxf(mx0, lg0[u]); mx1 = fmaxf(mx1, lg1[u]); }
  float s0 = 0.0f, s1 = 0.0f;
#pragma unroll
  for (int u = 0; u < 8; u++) {
    lg0[u] = expf(lg0[u] - mx0); s0 += lg0[u];
    lg1[u] = expf(lg1[u] - mx1); s1 += lg1[u];
  }
  float i0 = 1.0f / s0, i1 = 1.0f / s1;
  float out0 = 0.0f, out1 = 0.0f;
#pragma unroll
  for (int u = 0; u < 8; u++) {
    out0 = fmaf(lg0[u] * i0, vg0[u] + acc0[u], out0);
    out1 = fmaf(lg1[u] * i1, vg1[u] + acc1[u], out1);
  }
  outb[0][c] = out0; outb[1][c] = out1;
  float at0 = lobc, at1 = lobc;
#pragma unroll 4
  for (int d = 0; d < DD; d += 4) {
    float4 o0 = *(const float4*)&outb[0][d];
    float4 o1 = *(const float4*)&outb[1][d];
    float wa = ow[(d + 0) * 64 + c], wb = ow[(d + 1) * 64 + c];
    float wc = ow[(d + 2) * 64 + c], wd = ow[(d + 3) * 64 + c];
    at0 = fmaf(o0.x, wa, at0); at0 = fmaf(o0.y, wb, at0);
    at0 = fmaf(o0.z, wc, at0); at0 = fmaf(o0.w, wd, at0);
    at1 = fmaf(o1.x, wa, at1); at1 = fmaf(o1.y, wb, at1);
    at1 = fmaf(o1.z, wc, at1); at1 = fmaf(o1.w, wd, at1);
  }
  {
    float res = at0 + hs0;
    float mean = wave_sum(res) * (1.0f / 64.0f);
    float dv = res - mean;
    float var = wave_sum(dv * dv) * (1.0f / 64.0f);
    float ivr = 1.0f / sqrtf(var + LNEPS);
    t[(size_t)p0 * 64 + c] = fmaf(g1c, dv * ivr, bt1c);
  }
  {
    float res = at1 + hs1;
    float mean = wave_sum(res) * (1.0f / 64.0f);
    float dv = res - mean;
    float var = wave_sum(dv * dv) * (1.0f / 64.0f);
    float ivr = 1.0f / sqrtf(var + LNEPS);
    t[(size_t)(p0 + 1) * 64 + c] = fmaf(g1c, dv * ivr, bt1c);
  }
}

// ---------------------------------------------------------------- ffn: 1-wave blocks, 4 points/wave -> h = ln2(t + ffn(t))
// Weights from global (streamed once per wave, fw1 then fw2); LDS only yb+hb (3KB).
__global__ __launch_bounds__(64) void ffn_kernel(
    const float* __restrict__ t, const float* __restrict__ fw1, const float* __restrict__ fb1,
    const float* __restrict__ fw2, const float* __restrict__ fb2,
    const float* __restrict__ l2g, const float* __restrict__ l2b, float* __restrict__ h) {
  __shared__ __attribute__((aligned(16))) float yb[DD][4];
  __shared__ __attribute__((aligned(16))) float hb[128][4];
  int c = threadIdx.x;
  int b = blockIdx.x & 7, pos = blockIdx.x >> 3;   // 1024 positions per batch
  int p0 = (b << 12) + pos * 4;
  float y[4];
#pragma unroll
  for (int i = 0; i < 4; i++) { y[i] = t[(size_t)(p0 + i) * 64 + c]; yb[c][i] = y[i]; }
  float b1a = fb1[c], b1b = fb1[64 + c];
  float b2c = fb2[c], g2c = l2g[c], bt2c = l2b[c];
  float hA[4], hB[4];
#pragma unroll
  for (int i = 0; i < 4; i++) { hA[i] = b1a; hB[i] = b1b; }
#pragma unroll 4
  for (int d = 0; d < DD; d++) {
    float w0 = fw1[d * 128 + c], w1 = fw1[d * 128 + 64 + c];
    float4 yv = *(const float4*)&yb[d][0];
    hA[0] = fmaf(yv.x, w0, hA[0]); hA[1] = fmaf(yv.y, w0, hA[1]);
    hA[2] = fmaf(yv.z, w0, hA[2]); hA[3] = fmaf(yv.w, w0, hA[3]);
    hB[0] = fmaf(yv.x, w1, hB[0]); hB[1] = fmaf(yv.y, w1, hB[1]);
    hB[2] = fmaf(yv.z, w1, hB[2]); hB[3] = fmaf(yv.w, w1, hB[3]);
  }
#pragma unroll
  for (int i = 0; i < 4; i++) {
    hA[i] = gelu_exact(hA[i]); hB[i] = gelu_exact(hB[i]);
    hb[c][i] = hA[i]; hb[64 + c][i] = hB[i];
  }
  float o[4];
#pragma unroll
  for (int i = 0; i < 4; i++) o[i] = b2c;
#pragma unroll 4
  for (int j = 0; j < 128; j++) {
    float wv_ = fw2[j * 64 + c];
    float4 hv = *(const float4*)&hb[j][0];
    o[0] = fmaf(hv.x, wv_, o[0]); o[1] = fmaf(hv.y, wv_, o[1]);
    o[2] = fmaf(hv.z, wv_, o[2]); o[3] = fmaf(hv.w, wv_, o[3]);
  }
#pragma unroll
  for (int i = 0; i < 4; i++) {
    float r = y[i] + o[i];
    float mean = wave_sum(r) * (1.0f / 64.0f);
    float dv = r - mean;
    float var = wave_sum(dv * dv) * (1.0f / 64.0f);
    float ivr = 1.0f / sqrtf(var + LNEPS);
    h[(size_t)(p0 + i) * 64 + c] = fmaf(g2c, dv * ivr, bt2c);
  }
}

// ---------------------------------------------------------------- classifier proj + blockwise max-pool (XCD-pinned)
__global__ __launch_bounds__(256) void cls_kernel(
    const float* __restrict__ h, const float* __restrict__ cw, const float* __restrict__ cb,
    const float* __restrict__ cg, const float* __restrict__ cbeta, float* __restrict__ g) {
  __shared__ float lcw[DD * 128];
  __shared__ float lcb[128], lcg[128], lcbt[128];
  __shared__ __attribute__((aligned(16))) float hb[4][DD][4];
  __shared__ float wmax[4][128];
  int tid = threadIdx.x;
  for (int i = tid; i < DD * 128; i += 256) lcw[i] = cw[i];
  if (tid < 128) { lcb[tid] = cb[tid]; lcg[tid] = cg[tid]; lcbt[tid] = cbeta[tid]; }
  __syncthreads();
  int w = tid >> 6, c = tid & 63;
  int b = blockIdx.x & 7;             // XCD-pinned batch
  int blk = blockIdx.x >> 3;          // 128 block-positions per batch
  int base = b * NN + blk * 32;
  float m0 = 0.0f, m1 = 0.0f;
  for (int it = 0; it < 2; ++it) {
    int p0 = base + (w * 2 + it) * 4;
#pragma unroll
    for (int i = 0; i < 4; i++) hb[w][c][i] = h[(size_t)(p0 + i) * 64 + c];
    float a0[4], a1[4];
#pragma unroll
    for (int i = 0; i < 4; i++) { a0[i] = lcb[c]; a1[i] = lcb[64 + c]; }
#pragma unroll 4
    for (int d = 0; d < DD; d++) {
      float w0 = lcw[d * 128 + c], w1 = lcw[d * 128 + 64 + c];
      float4 hv = *(const float4*)&hb[w][d][0];
      a0[0] = fmaf(hv.x, w0, a0[0]); a0[1] = fmaf(hv.y, w0, a0[1]);
      a0[2] = fmaf(hv.z, w0, a0[2]); a0[3] = fmaf(hv.w, w0, a0[3]);
      a1[0] = fmaf(hv.x, w1, a1[0]); a1[1] = fmaf(hv.y, w1, a1[1]);
      a1[2] = fmaf(hv.z, w1, a1[2]); a1[3] = fmaf(hv.w, w1, a1[3]);
    }
#pragma unroll
    for (int i = 0; i < 4; i++) {
      m0 = fmaxf(m0, fmaxf(0.0f, fmaf(lcg[c] * a0[i], BNRS, lcbt[c])));
      m1 = fmaxf(m1, fmaxf(0.0f, fmaf(lcg[64 + c] * a1[i], BNRS, lcbt[64 + c])));
    }
  }
  wmax[w][c] = m0; wmax[w][64 + c] = m1;
  __syncthreads();
  if (tid < 128) {
    float mm = fmaxf(fmaxf(wmax[0][tid], wmax[1][tid]), fmaxf(wmax[2][tid], wmax[3][tid]));
    atomicMax((int*)&g[b * 128 + tid], __float_as_int(mm));  // values >= 0
  }
}

// ---------------------------------------------------------------- final head (per batch)
__global__ __launch_bounds__(128) void head_kernel(
    const float* __restrict__ g,
    const float* __restrict__ f1w, const float* __restrict__ f1b,
    const float* __restrict__ b1g, const float* __restrict__ b1b,
    const float* __restrict__ f2w, const float* __restrict__ f2b,
    const float* __restrict__ b2g, const float* __restrict__ b2b,
    const float* __restrict__ f3w, const float* __restrict__ f3b,
    float* __restrict__ out) {
  __shared__ float gb[128], g1[128], g2[64];
  int b = blockIdx.x, t = threadIdx.x;
  gb[t] = g[b * 128 + t];
  __syncthreads();
  float a = f1b[t];
#pragma unroll 4
  for (int d = 0; d < 128; d++) a = fmaf(gb[d], f1w[d * 128 + t], a);
  g1[t] = fmaxf(0.0f, fmaf(b1g[t] * a, BNRS, b1b[t]));
  __syncthreads();
  if (t < 64) {
    float a2 = f2b[t];
#pragma unroll 4
    for (int j = 0; j < 128; j++) a2 = fmaf(g1[j], f2w[j * 64 + t], a2);
    g2[t] = fmaxf(0.0f, fmaf(b2g[t] * a2, BNRS, b2b[t]));
  }
  __syncthreads();
  if (t < NCLS) {
    float a3 = f3b[t];
#pragma unroll
    for (int d = 0; d < 64; d++) a3 = fmaf(g2[d], f3w[d * NCLS + t], a3);
    out[b * NCLS + t] = a3;
  }
}

extern "C" void kernel_launch(void* const* d_in, const int* in_sizes, int n_in,
                              void* d_out, int out_size, void* d_ws, size_t ws_size,
                              hipStream_t stream) {
  const float* x    = (const float*)d_in[0];
  const float* ew1  = (const float*)d_in[1];
  const float* eb1  = (const float*)d_in[2];
  const float* ew2  = (const float*)d_in[3];
  const float* eb2  = (const float*)d_in[4];
  const float* wq   = (const float*)d_in[5];
  const float* bq   = (const float*)d_in[6];
  const float* wk   = (const float*)d_in[7];
  const float* bk   = (const float*)d_in[8];
  const float* wv   = (const float*)d_in[9];
  const float* bv   = (const float*)d_in[10];
  const float* pw1  = (const float*)d_in[11];
  const float* pb1  = (const float*)d_in[12];
  const float* pw2  = (const float*)d_in[13];
  const float* pb2  = (const float*)d_in[14];
  const float* aw   = (const float*)d_in[15];
  const float* ab   = (const float*)d_in[16];
  const float* ow   = (const float*)d_in[17];
  const float* ob   = (const float*)d_in[18];
  const float* l1g  = (const float*)d_in[19];
  const float* l1b  = (const float*)d_in[20];
  const float* l2g  = (const float*)d_in[21];
  const float* l2b  = (const float*)d_in[22];
  const float* fw1  = (const float*)d_in[23];
  const float* fb1  = (const float*)d_in[24];
  const float* fw2  = (const float*)d_in[25];
  const float* fb2  = (const float*)d_in[26];
  const float* cw   = (const float*)d_in[27];
  const float* cb   = (const float*)d_in[28];
  const float* cg   = (const float*)d_in[29];
  const float* cbeta= (const float*)d_in[30];
  const float* f1w  = (const float*)d_in[31];
  const float* f1b  = (const float*)d_in[32];
  const float* b1g  = (const float*)d_in[33];
  const float* b1b  = (const float*)d_in[34];
  const float* f2w  = (const float*)d_in[35];
  const float* f2b  = (const float*)d_in[36];
  const float* b2g  = (const float*)d_in[37];
  const float* b2b  = (const float*)d_in[38];
  const float* f3w  = (const float*)d_in[39];
  const float* f3b  = (const float*)d_in[40];

  const size_t P = (size_t)BB * NN;       // 32768 points
  float* ws = (float*)d_ws;
  float* h = ws;                          // P*64
  float* q = h + P * 64;
  float* k = q + P * 64;
  float* v = k + P * 64;
  int* idx = (int*)(v + P * 64);          // P*8 ints
  float* g = (float*)(idx + P * 8);       // B*128
  float4* ppg = (float4*)(g + BB * 128);  // P float4 (aligned: offset is 16B-multiple)
  float* t = q;                           // alias: safe (same-point read-then-write)

  zero_kernel<<<1, BB * 128, 0, stream>>>(g);
  embed_kernel<<<(int)(P / 4), 256, 0, stream>>>(x, ew1, eb1, ew2, eb2, h);
  knn_prep_kernel<<<(int)(P / 256), 256, 0, stream>>>(x, ppg);
  knn_kernel<<<BB * (NN / QPB), 1024, 0, stream>>>(ppg, idx);
  for (int l = 0; l < 2; l++) {
    qkv_kernel<<<(int)(P / 4), 64, 0, stream>>>(h, wq + l * DD * DD, bq + l * DD,
                                                wk + l * DD * DD, bk + l * DD,
                                                wv + l * DD * DD, bv + l * DD, q, k, v);
    attn_kernel<<<(int)(P / 2), 64, 0, stream>>>(x, h, q, k, v, idx,
                                                 pw1 + l * 3 * DD, pb1 + l * DD,
                                                 pw2 + l * DD * DD, pb2 + l * DD,
                                                 aw + l * DD, ab + l,
                                                 ow + l * DD * DD, ob + l * DD,
                                                 l1g + l * DD, l1b + l * DD, t);
    ffn_kernel<<<(int)(P / 4), 64, 0, stream>>>(t, fw1 + l * DD * 2 * DD, fb1 + l * 2 * DD,
                                                fw2 + l * 2 * DD * DD, fb2 + l * DD,
                                                l2g + l * DD, l2b + l * DD, h);
  }
  cls_kernel<<<BB * 128, 256, 0, stream>>>(h, cw, cb, cg, cbeta, g);
  head_kernel<<<BB, 128, 0, stream>>>(g, f1w, f1b, b1g, b1b, f2w, f2b, b2g, b2b, f3w, f3b,
                                      (float*)d_out);
}

// Round 12
// 366.233 us; speedup vs baseline: 1.4523x; 1.0178x over previous
//
#include <hip/hip_runtime.h>
#include <cmath>

#define BB 8
#define NN 4096
#define DD 64
#define KK 8
#define NCLS 2

constexpr float LNEPS = 1e-5f;
constexpr float BNRS = 0.9999950000374994f;      // 1/sqrt(1+1e-5)
constexpr float INVSQRT2 = 0.70710678118654752440f;

// knn decomposition: 64 queries/block x 16 candidate-splits (one per wave)
#define QPB 64
#define SPLITS 16
#define SUBSET 64     // pass-1 subset per split (16*64 = 1024-point bound set)

__device__ __forceinline__ float wave_sum(float v) {
#pragma unroll
  for (int m = 32; m > 0; m >>= 1) v += __shfl_xor(v, m, 64);
  return v;
}

__device__ __forceinline__ float gelu_exact(float x) {
  return 0.5f * x * (1.0f + erff(x * INVSQRT2));
}

// identical in both knn passes -> bit-identical distances
__device__ __forceinline__ float dist2(float4 q, float4 p) {
  float dot = fmaf(q.x, p.x, fmaf(q.y, p.y, q.z * p.z));
  return fmaf(-2.0f, dot, q.w + p.w);
}

// ---------------------------------------------------------------- zero g
__global__ void zero_kernel(float* g) { g[threadIdx.x] = 0.0f; }

// ---------------------------------------------------------------- embed: h = relu(x@ew1+eb1)@ew2+eb2
__global__ __launch_bounds__(256) void embed_kernel(
    const float* __restrict__ x, const float* __restrict__ ew1, const float* __restrict__ eb1,
    const float* __restrict__ ew2, const float* __restrict__ eb2, float* __restrict__ h) {
  __shared__ float h1[4][DD];
  int w = threadIdx.x >> 6, c = threadIdx.x & 63;
  int pt = ((blockIdx.x & 7) << 12) + (blockIdx.x >> 3) * 4 + w;
  const float* xp = x + (size_t)pt * 3;
  float x0 = xp[0], x1 = xp[1], x2 = xp[2];
  float a = fmaf(x0, ew1[c], fmaf(x1, ew1[64 + c], fmaf(x2, ew1[128 + c], eb1[c])));
  h1[w][c] = fmaxf(a, 0.0f);
  float s = eb2[c];
#pragma unroll 8
  for (int d = 0; d < DD; d++) s = fmaf(h1[w][d], ew2[d * 64 + c], s);
  h[(size_t)pt * 64 + c] = s;
}

// ---------------------------------------------------------------- knn prep: ppg[b*N+j] = (x,y,z,|p|^2)
__global__ __launch_bounds__(256) void knn_prep_kernel(const float* __restrict__ x,
                                                       float4* __restrict__ ppg) {
  int i = ((blockIdx.x & 7) << 12) + (blockIdx.x >> 3) * 256 + threadIdx.x;
  float a0 = x[3 * i + 0], a1 = x[3 * i + 1], a2 = x[3 * i + 2];
  ppg[i] = make_float4(a0, a1, a2, a0 * a0 + a1 * a1 + a2 * a2);
}

// ---------------------------------------------------------------- knn: exact top-8 (stable ties), 2-pass
// Pass-2 hit path: FIFO append to LDS (7 slots/hit vs 34 for sorted-insert).
// Overflow (>8 hits per split, P~2e-4): replace-max-if-smaller keeps the 8
// smallest hits of the split -> provably exact (a true top-8 member has <=7
// smaller keys globally, hence <=7 smaller hits within its split).
__global__ __launch_bounds__(1024) void knn_kernel(const float4* __restrict__ ppg,
                                                   int* __restrict__ idx) {
  __shared__ union {
    float v[SPLITS * 8][QPB];       // pass-1 value lists
    double k[SPLITS * 8][QPB];      // pass-2 key lists (64 KB)
  } mb;
  __shared__ float thrq[QPB];
  int b = blockIdx.x & 7;           // XCD-pinned batch
  int qbase = (blockIdx.x >> 3) * QPB;
  const float4* pb = ppg + (size_t)b * NN;
  int ql = threadIdx.x & 63;
  int sp = __builtin_amdgcn_readfirstlane(threadIdx.x >> 6);  // wave id = split id (SGPR)
  float4 qp = pb[qbase + ql];
  const float4* cp = pb + sp * (NN / SPLITS);                 // scalar base

  // ---- pass 1: branchless top-8 distances over SUBSET candidates
  float bd[8];
#pragma unroll
  for (int u = 0; u < 8; u++) bd[u] = INFINITY;
#pragma unroll 4
  for (int jj = 0; jj < SUBSET; ++jj) {
    float d2 = dist2(qp, cp[jj]);
#pragma unroll
    for (int u = 7; u > 0; --u) bd[u] = fminf(bd[u], fmaxf(bd[u - 1], d2));
    bd[0] = fminf(bd[0], d2);
  }
#pragma unroll
  for (int u = 0; u < 8; u++) mb.v[sp * 8 + u][ql] = bd[u];
  __syncthreads();

  // ---- U merge stage 1
  if (sp < 8) {
    float cd[8];
#pragma unroll
    for (int u = 0; u < 8; u++) cd[u] = INFINITY;
    int base = sp * 16;
#pragma unroll
    for (int e = 0; e < 16; e++) {
      float vv = mb.v[base + e][ql];
#pragma unroll
      for (int u = 7; u > 0; --u) cd[u] = fminf(cd[u], fmaxf(cd[u - 1], vv));
      cd[0] = fminf(cd[0], vv);
    }
#pragma unroll
    for (int u = 0; u < 8; u++) mb.v[base + u][ql] = cd[u];
  }
  __syncthreads();

  // ---- U merge stage 2
  if (sp == 0) {
    float cd[8];
#pragma unroll
    for (int u = 0; u < 8; u++) cd[u] = INFINITY;
    for (int m = 0; m < 8; m++) {
      for (int e = 0; e < 8; e++) {
        float vv = mb.v[m * 16 + e][ql];
        if (__all(vv >= cd[7])) break;
#pragma unroll
        for (int u = 7; u > 0; --u) cd[u] = fminf(cd[u], fmaxf(cd[u - 1], vv));
        cd[0] = fminf(cd[0], vv);
      }
    }
    thrq[ql] = cd[7];
  }
  __syncthreads();
  float U = thrq[ql];

  // ---- init key slots (after barrier: mb.v reads all complete)
#pragma unroll
  for (int u = 0; u < 8; u++) mb.k[sp * 8 + u][ql] = INFINITY;

  // ---- pass 2: FIFO-collect hits (d2<=U) per split; overflow -> replace-max
  int cnt = 0;
#pragma unroll 4
  for (int jj = 0; jj < NN / SPLITS; ++jj) {
    float d2 = dist2(qp, cp[jj]);
    if (d2 <= U) {
      double key = __hiloint2double(__float_as_int(d2), sp * (NN / SPLITS) + jj);
      if (cnt < 8) {
        mb.k[sp * 8 + cnt][ql] = key;
        cnt++;
      } else {
        double mx = mb.k[sp * 8 + 0][ql];
        int mi = 0;
#pragma unroll
        for (int u = 1; u < 8; u++) {
          double tv = mb.k[sp * 8 + u][ql];
          if (tv > mx) { mx = tv; mi = u; }
        }
        if (key < mx) mb.k[sp * 8 + mi][ql] = key;
      }
    }
  }
  __syncthreads();

  // ---- key merge stage 1 (network accepts unsorted input; output sorted)
  if (sp < 8) {
    double cd[8];
#pragma unroll
    for (int u = 0; u < 8; u++) cd[u] = INFINITY;
    int base = sp * 16;
#pragma unroll
    for (int e = 0; e < 16; e++) {
      double key = mb.k[base + e][ql];
#pragma unroll
      for (int u = 7; u > 0; --u) cd[u] = fmin(cd[u], fmax(cd[u - 1], key));
      cd[0] = fmin(cd[0], key);
    }
#pragma unroll
    for (int u = 0; u < 8; u++) mb.k[base + u][ql] = cd[u];
  }
  __syncthreads();

  // ---- key merge stage 2 + write (stage-1 outputs are sorted -> __all-break ok)
  if (sp == 0) {
    double cd[8];
#pragma unroll
    for (int u = 0; u < 8; u++) cd[u] = INFINITY;
    for (int m = 0; m < 8; m++) {
      for (int e = 0; e < 8; e++) {
        double key = mb.k[m * 16 + e][ql];
        if (__all(key >= cd[7])) break;
#pragma unroll
        for (int u = 7; u > 0; --u) cd[u] = fmin(cd[u], fmax(cd[u - 1], key));
        cd[0] = fmin(cd[0], key);
      }
    }
    int* op = idx + ((size_t)b * NN + qbase + ql) * 8;
#pragma unroll
    for (int u = 0; u < 8; u++) op[u] = __double2loint(cd[u]);
  }
}

// ---------------------------------------------------------------- qkv projection: 1-wave blocks, 4 points/wave
__global__ __launch_bounds__(64) void qkv_kernel(
    const float* __restrict__ h, const float* __restrict__ wq, const float* __restrict__ bq,
    const float* __restrict__ wk, const float* __restrict__ bk,
    const float* __restrict__ wv, const float* __restrict__ bv,
    float* __restrict__ q, float* __restrict__ k, float* __restrict__ v) {
  __shared__ __attribute__((aligned(16))) float hb[DD][4];
  int c = threadIdx.x;
  int b = blockIdx.x & 7, pos = blockIdx.x >> 3;   // 1024 positions per batch
  int p0 = (b << 12) + pos * 4;
#pragma unroll
  for (int i = 0; i < 4; i++) hb[c][i] = h[(size_t)(p0 + i) * 64 + c];
  float bqc = bq[c], bkc = bk[c], bvc = bv[c];
  float aq[4], ak[4], av[4];
#pragma unroll
  for (int i = 0; i < 4; i++) { aq[i] = bqc; ak[i] = bkc; av[i] = bvc; }
#pragma unroll 4
  for (int d = 0; d < DD; d++) {
    float wq_ = wq[d * 64 + c], wk_ = wk[d * 64 + c], wv_ = wv[d * 64 + c];
    float4 hh = *(const float4*)&hb[d][0];
    aq[0] = fmaf(hh.x, wq_, aq[0]); aq[1] = fmaf(hh.y, wq_, aq[1]);
    aq[2] = fmaf(hh.z, wq_, aq[2]); aq[3] = fmaf(hh.w, wq_, aq[3]);
    ak[0] = fmaf(hh.x, wk_, ak[0]); ak[1] = fmaf(hh.y, wk_, ak[1]);
    ak[2] = fmaf(hh.z, wk_, ak[2]); ak[3] = fmaf(hh.w, wk_, ak[3]);
    av[0] = fmaf(hh.x, wv_, av[0]); av[1] = fmaf(hh.y, wv_, av[1]);
    av[2] = fmaf(hh.z, wv_, av[2]); av[3] = fmaf(hh.w, wv_, av[3]);
  }
#pragma unroll
  for (int i = 0; i < 4; i++) {
    q[(size_t)(p0 + i) * 64 + c] = aq[i];
    k[(size_t)(p0 + i) * 64 + c] = ak[i];
    v[(size_t)(p0 + i) * 64 + c] = av[i];
  }
}

// ---------------------------------------------------------------- fused attention+ffn: 1-wave blocks, 2 points/wave
// attn -> t (registers) -> ffn -> h, all point-local after the k/v gathers.
// h is read (residual) and written for the SAME points only -> no cross-wave hazard.
__global__ __launch_bounds__(64) void attn_ffn_kernel(
    const float* __restrict__ x, float* h,
    const float* __restrict__ q, const float* __restrict__ kk, const float* __restrict__ vv,
    const int* __restrict__ idx,
    const float* __restrict__ pw1, const float* __restrict__ pb1,
    const float* __restrict__ pw2, const float* __restrict__ pb2,
    const float* __restrict__ aw, const float* __restrict__ ab,
    const float* __restrict__ ow, const float* __restrict__ ob,
    const float* __restrict__ l1g, const float* __restrict__ l1b,
    const float* __restrict__ fw1, const float* __restrict__ fb1,
    const float* __restrict__ fw2, const float* __restrict__ fb2,
    const float* __restrict__ l2g, const float* __restrict__ l2b) {
  __shared__ __attribute__((aligned(16))) float h1b[2][DD][8];   // 4KB
  __shared__ __attribute__((aligned(16))) float outb[2][DD];     // 0.5KB
  __shared__ __attribute__((aligned(8)))  float tb[DD][2];       // 0.5KB
  __shared__ __attribute__((aligned(8)))  float hb2[128][2];     // 1KB
  int c = threadIdx.x;
  int b = blockIdx.x & 7;                 // XCD-pinned batch
  int n0 = (blockIdx.x >> 3) * 2;         // 2048 positions per batch
  int p0 = (b << 12) + n0;
  const float* xb = x + (size_t)b * NN * 3;
  float w1c0 = pw1[c], w1c1 = pw1[64 + c], w1c2 = pw1[128 + c], b1c = pb1[c];
  float pb2c = pb2[c], lawc = aw[c], lobc = ob[c], g1c = l1g[c], bt1c = l1b[c];
  float lab = ab[0];
  float hs0 = h[(size_t)p0 * 64 + c], hs1 = h[(size_t)(p0 + 1) * 64 + c];
  float qs0 = q[(size_t)p0 * 64 + c], qs1 = q[(size_t)(p0 + 1) * 64 + c];
  int nb[2][8];
#pragma unroll
  for (int u = 0; u < 8; u++) {
    nb[0][u] = idx[(size_t)p0 * 8 + u];
    nb[1][u] = idx[(size_t)(p0 + 1) * 8 + u];
  }
  // ---- prefetch all k/v gather rows NOW; latency hides under pe1+pe2 compute
  float kv0[8], kv1[8], vg0[8], vg1[8];
#pragma unroll
  for (int u = 0; u < 8; u++) {
    kv0[u] = kk[((size_t)(b << 12) + nb[0][u]) * 64 + c];
    kv1[u] = kk[((size_t)(b << 12) + nb[1][u]) * 64 + c];
    vg0[u] = vv[((size_t)(b << 12) + nb[0][u]) * 64 + c];
    vg1[u] = vv[((size_t)(b << 12) + nb[1][u]) * 64 + c];
  }
#pragma unroll
  for (int pt = 0; pt < 2; ++pt) {
    int n = n0 + pt;
    float px0 = xb[n * 3 + 0], px1 = xb[n * 3 + 1], px2 = xb[n * 3 + 2];
    float h1v[8];
#pragma unroll
    for (int u = 0; u < 8; u++) {
      int m = nb[pt][u];
      float d0 = px0 - xb[m * 3 + 0], d1 = px1 - xb[m * 3 + 1], d2 = px2 - xb[m * 3 + 2];
      h1v[u] = fmaxf(fmaf(d0, w1c0, fmaf(d1, w1c1, fmaf(d2, w1c2, b1c))), 0.0f);
    }
    *(float4*)&h1b[pt][c][0] = make_float4(h1v[0], h1v[1], h1v[2], h1v[3]);
    *(float4*)&h1b[pt][c][4] = make_float4(h1v[4], h1v[5], h1v[6], h1v[7]);
  }
  float acc0[8], acc1[8];
#pragma unroll
  for (int u = 0; u < 8; u++) { acc0[u] = pb2c; acc1[u] = pb2c; }
#pragma unroll 2
  for (int d = 0; d < DD; d++) {
    float wv_ = pw2[d * 64 + c];
    float4 a0 = *(const float4*)&h1b[0][d][0];
    float4 b0 = *(const float4*)&h1b[0][d][4];
    float4 a1 = *(const float4*)&h1b[1][d][0];
    float4 b1 = *(const float4*)&h1b[1][d][4];
    acc0[0] = fmaf(a0.x, wv_, acc0[0]); acc0[1] = fmaf(a0.y, wv_, acc0[1]);
    acc0[2] = fmaf(a0.z, wv_, acc0[2]); acc0[3] = fmaf(a0.w, wv_, acc0[3]);
    acc0[4] = fmaf(b0.x, wv_, acc0[4]); acc0[5] = fmaf(b0.y, wv_, acc0[5]);
    acc0[6] = fmaf(b0.z, wv_, acc0[6]); acc0[7] = fmaf(b0.w, wv_, acc0[7]);
    acc1[0] = fmaf(a1.x, wv_, acc1[0]); acc1[1] = fmaf(a1.y, wv_, acc1[1]);
    acc1[2] = fmaf(a1.z, wv_, acc1[2]); acc1[3] = fmaf(a1.w, wv_, acc1[3]);
    acc1[4] = fmaf(b1.x, wv_, acc1[4]); acc1[5] = fmaf(b1.y, wv_, acc1[5]);
    acc1[6] = fmaf(b1.z, wv_, acc1[6]); acc1[7] = fmaf(b1.w, wv_, acc1[7]);
  }
  float lg0[8], lg1[8];
#pragma unroll
  for (int u = 0; u < 8; u++) {
    lg0[u] = wave_sum((qs0 - kv0[u] + acc0[u]) * lawc) + lab;
    lg1[u] = wave_sum((qs1 - kv1[u] + acc1[u]) * lawc) + lab;
  }
  float mx0 = lg0[0], mx1 = lg1[0];
#pragma unroll
  for (int u = 1; u < 8; u++) { mx0 = fmaxf(mx0, lg0[u]); mx1 = fmaxf(mx1, lg1[u]); }
  float s0 = 0.0f, s1 = 0.0f;
#pragma unroll
  for (int u = 0; u < 8; u++) {
    lg0[u] = expf(lg0[u] - mx0); s0 += lg0[u];
    lg1[u] = expf(lg1[u] - mx1); s1 += lg1[u];
  }
  float i0 = 1.0f / s0, i1 = 1.0f / s1;
  float out0 = 0.0f, out1 = 0.0f;
#pragma unroll
  for (int u = 0; u < 8; u++) {
    out0 = fmaf(lg0[u] * i0, vg0[u] + acc0[u], out0);
    out1 = fmaf(lg1[u] * i1, vg1[u] + acc1[u], out1);
  }
  outb[0][c] = out0; outb[1][c] = out1;
  float at0 = lobc, at1 = lobc;
#pragma unroll 4
  for (int d = 0; d < DD; d += 4) {
    float4 o0 = *(const float4*)&outb[0][d];
    float4 o1 = *(const float4*)&outb[1][d];
    float wa = ow[(d + 0) * 64 + c], wb = ow[(d + 1) * 64 + c];
    float wc = ow[(d + 2) * 64 + c], wd = ow[(d + 3) * 64 + c];
    at0 = fmaf(o0.x, wa, at0); at0 = fmaf(o0.y, wb, at0);
    at0 = fmaf(o0.z, wc, at0); at0 = fmaf(o0.w, wd, at0);
    at1 = fmaf(o1.x, wa, at1); at1 = fmaf(o1.y, wb, at1);
    at1 = fmaf(o1.z, wc, at1); at1 = fmaf(o1.w, wd, at1);
  }
  float t0v, t1v;
  {
    float res = at0 + hs0;
    float mean = wave_sum(res) * (1.0f / 64.0f);
    float dv = res - mean;
    float var = wave_sum(dv * dv) * (1.0f / 64.0f);
    float ivr = 1.0f / sqrtf(var + LNEPS);
    t0v = fmaf(g1c, dv * ivr, bt1c);
  }
  {
    float res = at1 + hs1;
    float mean = wave_sum(res) * (1.0f / 64.0f);
    float dv = res - mean;
    float var = wave_sum(dv * dv) * (1.0f / 64.0f);
    float ivr = 1.0f / sqrtf(var + LNEPS);
    t1v = fmaf(g1c, dv * ivr, bt1c);
  }
  // ================ ffn (fused, point-local; math identical to old ffn_kernel)
  tb[c][0] = t0v; tb[c][1] = t1v;
  float fb1a = fb1[c], fb1b = fb1[64 + c];
  float hA0 = fb1a, hA1 = fb1a, hB0 = fb1b, hB1 = fb1b;
#pragma unroll 4
  for (int d = 0; d < DD; d++) {
    float w0 = fw1[d * 128 + c], w1 = fw1[d * 128 + 64 + c];
    float2 yv = *(const float2*)&tb[d][0];
    hA0 = fmaf(yv.x, w0, hA0); hA1 = fmaf(yv.y, w0, hA1);
    hB0 = fmaf(yv.x, w1, hB0); hB1 = fmaf(yv.y, w1, hB1);
  }
  hA0 = gelu_exact(hA0); hA1 = gelu_exact(hA1);
  hB0 = gelu_exact(hB0); hB1 = gelu_exact(hB1);
  hb2[c][0] = hA0; hb2[c][1] = hA1;
  hb2[64 + c][0] = hB0; hb2[64 + c][1] = hB1;
  float fb2c = fb2[c], g2c = l2g[c], bt2c = l2b[c];
  float o0 = fb2c, o1 = fb2c;
#pragma unroll 4
  for (int j = 0; j < 128; j++) {
    float wv_ = fw2[j * 64 + c];
    float2 hv = *(const float2*)&hb2[j][0];
    o0 = fmaf(hv.x, wv_, o0); o1 = fmaf(hv.y, wv_, o1);
  }
  {
    float r = t0v + o0;
    float mean = wave_sum(r) * (1.0f / 64.0f);
    float dv = r - mean;
    float var = wave_sum(dv * dv) * (1.0f / 64.0f);
    float ivr = 1.0f / sqrtf(var + LNEPS);
    h[(size_t)p0 * 64 + c] = fmaf(g2c, dv * ivr, bt2c);
  }
  {
    float r = t1v + o1;
    float mean = wave_sum(r) * (1.0f / 64.0f);
    float dv = r - mean;
    float var = wave_sum(dv * dv) * (1.0f / 64.0f);
    float ivr = 1.0f / sqrtf(var + LNEPS);
    h[(size_t)(p0 + 1) * 64 + c] = fmaf(g2c, dv * ivr, bt2c);
  }
}

// ---------------------------------------------------------------- classifier proj + blockwise max-pool (XCD-pinned)
__global__ __launch_bounds__(256) void cls_kernel(
    const float* __restrict__ h, const float* __restrict__ cw, const float* __restrict__ cb,
    const float* __restrict__ cg, const float* __restrict__ cbeta, float* __restrict__ g) {
  __shared__ float lcw[DD * 128];
  __shared__ float lcb[128], lcg[128], lcbt[128];
  __shared__ __attribute__((aligned(16))) float hb[4][DD][4];
  __shared__ float wmax[4][128];
  int tid = threadIdx.x;
  for (int i = tid; i < DD * 128; i += 256) lcw[i] = cw[i];
  if (tid < 128) { lcb[tid] = cb[tid]; lcg[tid] = cg[tid]; lcbt[tid] = cbeta[tid]; }
  __syncthreads();
  int w = tid >> 6, c = tid & 63;
  int b = blockIdx.x & 7;             // XCD-pinned batch
  int blk = blockIdx.x >> 3;          // 128 block-positions per batch
  int base = b * NN + blk * 32;
  float m0 = 0.0f, m1 = 0.0f;
  for (int it = 0; it < 2; ++it) {
    int p0 = base + (w * 2 + it) * 4;
#pragma unroll
    for (int i = 0; i < 4; i++) hb[w][c][i] = h[(size_t)(p0 + i) * 64 + c];
    float a0[4], a1[4];
#pragma unroll
    for (int i = 0; i < 4; i++) { a0[i] = lcb[c]; a1[i] = lcb[64 + c]; }
#pragma unroll 4
    for (int d = 0; d < DD; d++) {
      float w0 = lcw[d * 128 + c], w1 = lcw[d * 128 + 64 + c];
      float4 hv = *(const float4*)&hb[w][d][0];
      a0[0] = fmaf(hv.x, w0, a0[0]); a0[1] = fmaf(hv.y, w0, a0[1]);
      a0[2] = fmaf(hv.z, w0, a0[2]); a0[3] = fmaf(hv.w, w0, a0[3]);
      a1[0] = fmaf(hv.x, w1, a1[0]); a1[1] = fmaf(hv.y, w1, a1[1]);
      a1[2] = fmaf(hv.z, w1, a1[2]); a1[3] = fmaf(hv.w, w1, a1[3]);
    }
#pragma unroll
    for (int i = 0; i < 4; i++) {
      m0 = fmaxf(m0, fmaxf(0.0f, fmaf(lcg[c] * a0[i], BNRS, lcbt[c])));
      m1 = fmaxf(m1, fmaxf(0.0f, fmaf(lcg[64 + c] * a1[i], BNRS, lcbt[64 + c])));
    }
  }
  wmax[w][c] = m0; wmax[w][64 + c] = m1;
  __syncthreads();
  if (tid < 128) {
    float mm = fmaxf(fmaxf(wmax[0][tid], wmax[1][tid]), fmaxf(wmax[2][tid], wmax[3][tid]));
    atomicMax((int*)&g[b * 128 + tid], __float_as_int(mm));  // values >= 0
  }
}

// ---------------------------------------------------------------- final head (per batch)
__global__ __launch_bounds__(128) void head_kernel(
    const float* __restrict__ g,
    const float* __restrict__ f1w, const float* __restrict__ f1b,
    const float* __restrict__ b1g, const float* __restrict__ b1b,
    const float* __restrict__ f2w, const float* __restrict__ f2b,
    const float* __restrict__ b2g, const float* __restrict__ b2b,
    const float* __restrict__ f3w, const float* __restrict__ f3b,
    float* __restrict__ out) {
  __shared__ float gb[128], g1[128], g2[64];
  int b = blockIdx.x, t = threadIdx.x;
  gb[t] = g[b * 128 + t];
  __syncthreads();
  float a = f1b[t];
#pragma unroll 4
  for (int d = 0; d < 128; d++) a = fmaf(gb[d], f1w[d * 128 + t], a);
  g1[t] = fmaxf(0.0f, fmaf(b1g[t] * a, BNRS, b1b[t]));
  __syncthreads();
  if (t < 64) {
    float a2 = f2b[t];
#pragma unroll 4
    for (int j = 0; j < 128; j++) a2 = fmaf(g1[j], f2w[j * 64 + t], a2);
    g2[t] = fmaxf(0.0f, fmaf(b2g[t] * a2, BNRS, b2b[t]));
  }
  __syncthreads();
  if (t < NCLS) {
    float a3 = f3b[t];
#pragma unroll
    for (int d = 0; d < 64; d++) a3 = fmaf(g2[d], f3w[d * NCLS + t], a3);
    out[b * NCLS + t] = a3;
  }
}

extern "C" void kernel_launch(void* const* d_in, const int* in_sizes, int n_in,
                              void* d_out, int out_size, void* d_ws, size_t ws_size,
                              hipStream_t stream) {
  const float* x    = (const float*)d_in[0];
  const float* ew1  = (const float*)d_in[1];
  const float* eb1  = (const float*)d_in[2];
  const float* ew2  = (const float*)d_in[3];
  const float* eb2  = (const float*)d_in[4];
  const float* wq   = (const float*)d_in[5];
  const float* bq   = (const float*)d_in[6];
  const float* wk   = (const float*)d_in[7];
  const float* bk   = (const float*)d_in[8];
  const float* wv   = (const float*)d_in[9];
  const float* bv   = (const float*)d_in[10];
  const float* pw1  = (const float*)d_in[11];
  const float* pb1  = (const float*)d_in[12];
  const float* pw2  = (const float*)d_in[13];
  const float* pb2  = (const float*)d_in[14];
  const float* aw   = (const float*)d_in[15];
  const float* ab   = (const float*)d_in[16];
  const float* ow   = (const float*)d_in[17];
  const float* ob   = (const float*)d_in[18];
  const float* l1g  = (const float*)d_in[19];
  const float* l1b  = (const float*)d_in[20];
  const float* l2g  = (const float*)d_in[21];
  const float* l2b  = (const float*)d_in[22];
  const float* fw1  = (const float*)d_in[23];
  const float* fb1  = (const float*)d_in[24];
  const float* fw2  = (const float*)d_in[25];
  const float* fb2  = (const float*)d_in[26];
  const float* cw   = (const float*)d_in[27];
  const float* cb   = (const float*)d_in[28];
  const float* cg   = (const float*)d_in[29];
  const float* cbeta= (const float*)d_in[30];
  const float* f1w  = (const float*)d_in[31];
  const float* f1b  = (const float*)d_in[32];
  const float* b1g  = (const float*)d_in[33];
  const float* b1b  = (const float*)d_in[34];
  const float* f2w  = (const float*)d_in[35];
  const float* f2b  = (const float*)d_in[36];
  const float* b2g  = (const float*)d_in[37];
  const float* b2b  = (const float*)d_in[38];
  const float* f3w  = (const float*)d_in[39];
  const float* f3b  = (const float*)d_in[40];

  const size_t P = (size_t)BB * NN;       // 32768 points
  float* ws = (float*)d_ws;
  float* h = ws;                          // P*64
  float* q = h + P * 64;
  float* k = q + P * 64;
  float* v = k + P * 64;
  int* idx = (int*)(v + P * 64);          // P*8 ints
  float* g = (float*)(idx + P * 8);       // B*128
  float4* ppg = (float4*)(g + BB * 128);  // P float4 (aligned: offset is 16B-multiple)

  zero_kernel<<<1, BB * 128, 0, stream>>>(g);
  embed_kernel<<<(int)(P / 4), 256, 0, stream>>>(x, ew1, eb1, ew2, eb2, h);
  knn_prep_kernel<<<(int)(P / 256), 256, 0, stream>>>(x, ppg);
  knn_kernel<<<BB * (NN / QPB), 1024, 0, stream>>>(ppg, idx);
  for (int l = 0; l < 2; l++) {
    qkv_kernel<<<(int)(P / 4), 64, 0, stream>>>(h, wq + l * DD * DD, bq + l * DD,
                                                wk + l * DD * DD, bk + l * DD,
                                                wv + l * DD * DD, bv + l * DD, q, k, v);
    attn_ffn_kernel<<<(int)(P / 2), 64, 0, stream>>>(
        x, h, q, k, v, idx,
        pw1 + l * 3 * DD, pb1 + l * DD, pw2 + l * DD * DD, pb2 + l * DD,
        aw + l * DD, ab + l, ow + l * DD * DD, ob + l * DD,
        l1g + l * DD, l1b + l * DD,
        fw1 + l * DD * 2 * DD, fb1 + l * 2 * DD, fw2 + l * 2 * DD * DD, fb2 + l * DD,
        l2g + l * DD, l2b + l * DD);
  }
  cls_kernel<<<BB * 128, 256, 0, stream>>>(h, cw, cb, cg, cbeta, g);
  head_kernel<<<BB, 128, 0, stream>>>(g, f1w, f1b, b1g, b1b, f2w, f2b, b2g, b2b, f3w, f3b,
                                      (float*)d_out);
}